// Round 9
// baseline (2815.899 us; speedup 1.0000x reference)
//
#include <hip/hip_runtime.h>
#include <hip/hip_bf16.h>

typedef __hip_bfloat16 hbf16;
using bf16x8 = __attribute__((ext_vector_type(8))) __bf16;
using f32x4 = __attribute__((ext_vector_type(4))) float;

// GPT-2 small: L=12 H=12 D=768 V=50257 T=1024 B=2, HD=64
constexpr int Lc = 12, Hc = 12, Dc = 768, Vc = 50257, Tc = 1024, Bc = 2, HDc = 64;
constexpr int Mc = Bc * Tc;  // 2048 rows
constexpr int Vpad = 50304;  // 393*128, zero-padded vocab

// transposed-weight slot sizes (elements)
constexpr size_t SZ_Q = (size_t)3 * Dc * Dc;   // [2304][768]
constexpr size_t SZ_P = (size_t)Dc * Dc;       // [768][768]
constexpr size_t SZ_F = (size_t)4 * Dc * Dc;   // [3072][768]
constexpr size_t SZ_FP = (size_t)4 * Dc * Dc;  // [768][3072]
constexpr size_t SZL = SZ_Q + SZ_P + SZ_F + SZ_FP;

#define GLD16(gp, lp)                                               \
    __builtin_amdgcn_global_load_lds(                               \
        (__attribute__((address_space(1))) void*)(void*)(gp),       \
        (__attribute__((address_space(3))) void*)(void*)(lp), 16, 0, 0)

// ---------------- embedding: h = wte[x] + wpe[t] (f32) ----------------
__global__ void embed_kernel(const int* __restrict__ x, const float* __restrict__ wte,
                             const float* __restrict__ wpe, float* __restrict__ h) {
    int i = blockIdx.x * blockDim.x + threadIdx.x;
    if (i >= Mc * Dc) return;
    int m = i / Dc, d = i - m * Dc;
    int t = m % Tc;
    int tok = x[m];
    h[i] = wte[(size_t)tok * Dc + d] + wpe[(size_t)t * Dc + d];
}

// ---------------- layernorm: one wave per row, shuffle reduce, f32 in -> bf16 out --
__global__ __launch_bounds__(256) void ln_kernel(const float* __restrict__ x,
                                                 const float* __restrict__ w,
                                                 const float* __restrict__ b,
                                                 hbf16* __restrict__ out) {
    int wv = threadIdx.x >> 6, lane = threadIdx.x & 63;
    int row = blockIdx.x * 4 + wv;
    const float4* xr = (const float4*)(x + (size_t)row * Dc);
    float4 v[3];
    float s = 0.f, sq = 0.f;
#pragma unroll
    for (int i = 0; i < 3; i++) {
        v[i] = xr[i * 64 + lane];
        s += v[i].x + v[i].y + v[i].z + v[i].w;
        sq += v[i].x * v[i].x + v[i].y * v[i].y + v[i].z * v[i].z + v[i].w * v[i].w;
    }
#pragma unroll
    for (int o = 32; o > 0; o >>= 1) {
        s += __shfl_xor(s, o, 64);
        sq += __shfl_xor(sq, o, 64);
    }
    float mean = s * (1.f / Dc);
    float var = sq * (1.f / Dc) - mean * mean;
    float rstd = rsqrtf(var + 1e-5f);
#pragma unroll
    for (int i = 0; i < 3; i++) {
        int c = (i * 64 + lane) * 4;
        float4 wv4 = *(const float4*)(w + c);
        float4 bv4 = *(const float4*)(b + c);
        float r0 = (v[i].x - mean) * rstd * wv4.x + bv4.x;
        float r1 = (v[i].y - mean) * rstd * wv4.y + bv4.y;
        float r2 = (v[i].z - mean) * rstd * wv4.z + bv4.z;
        float r3 = (v[i].w - mean) * rstd * wv4.w + bv4.w;
        __bf16 q0 = (__bf16)r0, q1 = (__bf16)r1, q2 = (__bf16)r2, q3 = (__bf16)r3;
        ushort4 u;
        u.x = *(unsigned short*)&q0; u.y = *(unsigned short*)&q1;
        u.z = *(unsigned short*)&q2; u.w = *(unsigned short*)&q3;
        *(ushort4*)(out + (size_t)row * Dc + c) = u;
    }
}

// ---------------- weight transpose, grid (6912, nlayers) ----------------
__global__ __launch_bounds__(256) void transpose4_kernel(
    const float* __restrict__ s0, const float* __restrict__ s1,
    const float* __restrict__ s2, const float* __restrict__ s3,
    hbf16* __restrict__ d0, hbf16* __restrict__ d1,
    hbf16* __restrict__ d2, hbf16* __restrict__ d3) {
    int id = blockIdx.x;
    size_t lz = blockIdx.y;
    int bx, by, K, N;
    const float* W;
    hbf16* Wt;
    if (id < 1728)      { int t = id;        bx = t % 72; by = t / 72; K = 768;  N = 2304; W = s0 + lz * SZ_Q;  Wt = d0 + lz * SZL; }
    else if (id < 2304) { int t = id - 1728; bx = t % 24; by = t / 24; K = 768;  N = 768;  W = s1 + lz * SZ_P;  Wt = d1 + lz * SZL; }
    else if (id < 4608) { int t = id - 2304; bx = t % 96; by = t / 96; K = 768;  N = 3072; W = s2 + lz * SZ_F;  Wt = d2 + lz * SZL; }
    else                { int t = id - 4608; bx = t % 24; by = t / 24; K = 3072; N = 768;  W = s3 + lz * SZ_FP; Wt = d3 + lz * SZL; }

    __shared__ float tile[32][33];
    int n0 = bx * 32, k0 = by * 32;
    int tx = threadIdx.x & 31, ty = threadIdx.x >> 5;  // 32x8
#pragma unroll
    for (int i = 0; i < 4; i++) {
        int r = ty + i * 8;
        tile[r][tx] = W[(size_t)(k0 + r) * N + n0 + tx];
    }
    __syncthreads();
#pragma unroll
    for (int i = 0; i < 4; i++) {
        int r = ty + i * 8;
        Wt[(size_t)(n0 + r) * K + k0 + tx] = __float2bfloat16(tile[tx][r]);
    }
}

// ---------------- wte f32 [V][D] -> bf16 [Vpad][D] (zero pad) ----------------
__global__ void convert_wte(const float* __restrict__ wte, hbf16* __restrict__ out) {
    size_t i4 = ((size_t)blockIdx.x * 256 + threadIdx.x) * 4;
    if (i4 >= (size_t)Vpad * Dc) return;
    if (i4 < (size_t)Vc * Dc) {
#pragma unroll
        for (int j = 0; j < 4; j++) out[i4 + j] = __float2bfloat16(wte[i4 + j]);
    } else {
#pragma unroll
        for (int j = 0; j < 4; j++) out[i4 + j] = __float2bfloat16(0.f);
    }
}

// ---------------- MFMA GEMM 128xBN, single-buffer (reverted): C = A@Bt^T + epi ----
// EPI: 0 = +bias, 1 = +bias +f32 residual, 2 = +bias + tanh-GELU
template <int EPI, bool OUTBF, int BN>
__global__ __launch_bounds__(256) void mm_kernel(const hbf16* __restrict__ A,
                                                 const hbf16* __restrict__ Bt,
                                                 const float* __restrict__ bias,
                                                 const float* __restrict__ resid,
                                                 void* __restrict__ Cout,
                                                 int M, int N, int K) {
    constexpr int NF = BN / 32;  // n-frags per wave
    __shared__ __bf16 As[128 * 32];
    __shared__ __bf16 Bs[BN * 32];
    int tid = threadIdx.x;
    int l = tid & 63, w = tid >> 6;
    int wr = w >> 1, wc = w & 1;

    // XCD swizzle: hw dispatch order is x-fastest; chunk per XCD, m fastest.
    int gx = gridDim.x, gy = gridDim.y;
    int nwg = gx * gy;  // divisible by 8 for all our launches
    int hwlin = blockIdx.y * gx + blockIdx.x;
    int wk = (hwlin & 7) * (nwg >> 3) + (hwlin >> 3);
    int m0 = (wk % gy) * 128;
    int n0 = (wk / gy) * BN;

    int sr = tid >> 2, sc = tid & 3;
    int scs = (sc ^ (sr & 3)) * 8;
    const hbf16* pA0 = A + (size_t)(m0 + sr) * K + scs;
    const hbf16* pA1 = A + (size_t)(m0 + 64 + sr) * K + scs;
    const hbf16* pB0 = Bt + (size_t)(n0 + sr) * K + scs;
    const hbf16* pB1 = (BN == 128) ? Bt + (size_t)(n0 + 64 + sr) * K + scs : pB0;
    __bf16* lA0 = As + tid * 8;
    __bf16* lA1 = As + 2048 + tid * 8;
    __bf16* lB0 = Bs + tid * 8;
    __bf16* lB1 = Bs + 2048 + tid * 8;

    int lr = l & 15, lg = l >> 4;
    int ksl = (lg ^ (lr & 3)) * 8;
    int aoff[4], boff[NF];
#pragma unroll
    for (int m = 0; m < 4; m++) aoff[m] = (wr * 64 + m * 16 + lr) * 32 + ksl;
#pragma unroll
    for (int n = 0; n < NF; n++) boff[n] = (wc * (BN / 2) + n * 16 + lr) * 32 + ksl;

    f32x4 acc[4][NF] = {};

    for (int k0 = 0; k0 < K; k0 += 32) {
        GLD16(pA0, lA0);
        GLD16(pA1, lA1);
        GLD16(pB0, lB0);
        if constexpr (BN == 128) GLD16(pB1, lB1);
        pA0 += 32; pA1 += 32; pB0 += 32;
        if constexpr (BN == 128) pB1 += 32;
        __syncthreads();
        bf16x8 af[4], bfr[NF];
#pragma unroll
        for (int m = 0; m < 4; m++) af[m] = *(const bf16x8*)&As[aoff[m]];
#pragma unroll
        for (int n = 0; n < NF; n++) bfr[n] = *(const bf16x8*)&Bs[boff[n]];
#pragma unroll
        for (int m = 0; m < 4; m++)
#pragma unroll
            for (int n = 0; n < NF; n++)
                acc[m][n] = __builtin_amdgcn_mfma_f32_16x16x32_bf16(af[m], bfr[n], acc[m][n], 0, 0, 0);
        __syncthreads();
    }

#pragma unroll
    for (int n = 0; n < NF; n++) {
        int col = n0 + wc * (BN / 2) + n * 16 + lr;
        bool cok = col < N;
        float bv = (bias && cok) ? bias[col] : 0.f;
#pragma unroll
        for (int m = 0; m < 4; m++) {
#pragma unroll
            for (int r = 0; r < 4; r++) {
                int row = m0 + wr * 64 + m * 16 + lg * 4 + r;
                if (!cok) continue;
                float v = acc[m][n][r] + bv;
                if (EPI == 1) v += resid[(size_t)row * N + col];
                if (EPI == 2) {
                    float x3 = v * v * v;
                    v = 0.5f * v * (1.f + tanhf(0.7978845608028654f * (v + 0.044715f * x3)));
                }
                if (OUTBF)
                    ((hbf16*)Cout)[(size_t)row * N + col] = __float2bfloat16(v);
                else
                    ((float*)Cout)[(size_t)row * N + col] = v;
            }
        }
    }
}

// ---------------- MFMA GEMM 256x128, 512 threads, single-buffer (lm_head) ---------
__global__ __launch_bounds__(512) void mm2_kernel(const hbf16* __restrict__ A,
                                                  const hbf16* __restrict__ Bt,
                                                  float* __restrict__ Cout,
                                                  int M, int N, int K) {
    __shared__ __bf16 As[256 * 32];  // 16 KB
    __shared__ __bf16 Bs[128 * 32];  // 8 KB
    int tid = threadIdx.x;
    int l = tid & 63, w = tid >> 6;
    int wr = w >> 1, wc = w & 1;

    int gx = gridDim.x, gy = gridDim.y;  // gy = 8
    int nwg = gx * gy;
    int hwlin = blockIdx.y * gx + blockIdx.x;
    int wk = (hwlin & 7) * (nwg >> 3) + (hwlin >> 3);
    int m0 = (wk & 7) * 256;
    int n0 = (wk >> 3) * 128;

    int sr = tid >> 2, sc = tid & 3;
    int scs = (sc ^ (sr & 3)) * 8;
    const hbf16* pA0 = A + (size_t)(m0 + sr) * K + scs;
    const hbf16* pA1 = A + (size_t)(m0 + 128 + sr) * K + scs;
    const hbf16* pB = Bt + (size_t)(n0 + sr) * K + scs;
    __bf16* lA0 = As + tid * 8;
    __bf16* lA1 = As + 4096 + tid * 8;
    __bf16* lB = Bs + tid * 8;

    int lr = l & 15, lg = l >> 4;
    int ksl = (lg ^ (lr & 3)) * 8;
    int aoff[4], boff[4];
#pragma unroll
    for (int m = 0; m < 4; m++) aoff[m] = (wr * 64 + m * 16 + lr) * 32 + ksl;
#pragma unroll
    for (int n = 0; n < 4; n++) boff[n] = (wc * 64 + n * 16 + lr) * 32 + ksl;

    f32x4 acc[4][4] = {};

    for (int k0 = 0; k0 < K; k0 += 32) {
        GLD16(pA0, lA0);
        GLD16(pA1, lA1);
        GLD16(pB, lB);
        pA0 += 32; pA1 += 32; pB += 32;
        __syncthreads();
        bf16x8 af[4], bfr[4];
#pragma unroll
        for (int m = 0; m < 4; m++) af[m] = *(const bf16x8*)&As[aoff[m]];
#pragma unroll
        for (int n = 0; n < 4; n++) bfr[n] = *(const bf16x8*)&Bs[boff[n]];
#pragma unroll
        for (int m = 0; m < 4; m++)
#pragma unroll
            for (int n = 0; n < 4; n++)
                acc[m][n] = __builtin_amdgcn_mfma_f32_16x16x32_bf16(af[m], bfr[n], acc[m][n], 0, 0, 0);
        __syncthreads();
    }

#pragma unroll
    for (int n = 0; n < 4; n++) {
        int col = n0 + wc * 64 + n * 16 + lr;
        if (col >= N) continue;
#pragma unroll
        for (int m = 0; m < 4; m++) {
#pragma unroll
            for (int r = 0; r < 4; r++) {
                int row = m0 + wr * 64 + m * 16 + lg * 4 + r;
                Cout[(size_t)row * N + col] = acc[m][n][r];
            }
        }
    }
}

// ---------------- MFMA flash attention (exp2 + defer-max + paired V-stage) --------
__global__ __launch_bounds__(256) void fattn_kernel(const hbf16* __restrict__ qkv,
                                                    hbf16* __restrict__ y) {
    int qt = gridDim.x - 1 - blockIdx.x;  // heavy tiles first
    int h = blockIdx.y, b = blockIdx.z;
    int q0 = qt * 64;
    int tid = threadIdx.x;
    int l = tid & 63, w = tid >> 6;
    int li = l & 15, lg = l >> 4;
    constexpr int RS = 3 * Dc;
    constexpr int PST = 72;
    constexpr int VST = 72;
    constexpr float SCL = 0.125f * 1.44269504f;  // fold 1/sqrt(64) and log2(e)
    constexpr float THR = 11.5f;                 // defer-max threshold (log2 domain)

    __shared__ __bf16 P_lds[4][16 * PST];
    __shared__ __bf16 Vt[64 * VST];

    bf16x8 qf[2];
    {
        const hbf16* qp = qkv + (size_t)(b * Tc + q0 + w * 16 + li) * RS + h * HDc + lg * 8;
        qf[0] = *(const bf16x8*)qp;
        qf[1] = *(const bf16x8*)(qp + 32);
    }

    f32x4 acc_o[4] = {};
    float m_run[4], l_run[4];
#pragma unroll
    for (int r = 0; r < 4; r++) { m_run[r] = -1e30f; l_run[r] = 0.f; }

    // V-stage mapping: thread handles rows (jp, jp+1), d-chunk db..db+7
    int jp = (tid >> 3) * 2;
    int db = (tid & 7) * 8;

    for (int jt = 0; jt <= qt; jt++) {
        int j0 = jt * 64;
        // ---- stage V^T: paired rows -> 8 x ds_write_b32, conflict-free ----
        {
            const hbf16* vp0 = qkv + (size_t)(b * Tc + j0 + jp) * RS + 2 * Dc + h * HDc + db;
            bf16x8 v0 = *(const bf16x8*)vp0;
            bf16x8 v1 = *(const bf16x8*)(vp0 + RS);
#pragma unroll
            for (int i = 0; i < 8; i++) {
                __bf16 a0 = v0[i], a1 = v1[i];
                unsigned u = (unsigned)*(unsigned short*)&a0 |
                             ((unsigned)*(unsigned short*)&a1 << 16);
                *(unsigned*)&Vt[(db + i) * VST + jp] = u;
            }
        }

        // ---- S = Q K^T ----
        f32x4 s[4] = {};
        __builtin_amdgcn_s_setprio(1);
#pragma unroll
        for (int ks = 0; ks < 2; ks++) {
#pragma unroll
            for (int n = 0; n < 4; n++) {
                const hbf16* kp = qkv + (size_t)(b * Tc + j0 + n * 16 + li) * RS + Dc + h * HDc + ks * 32 + lg * 8;
                bf16x8 kf = *(const bf16x8*)kp;
                s[n] = __builtin_amdgcn_mfma_f32_16x16x32_bf16(qf[ks], kf, s[n], 0, 0, 0);
            }
        }
        __builtin_amdgcn_s_setprio(0);
#pragma unroll
        for (int n = 0; n < 4; n++)
#pragma unroll
            for (int r = 0; r < 4; r++) s[n][r] *= SCL;

        if (jt == qt) {  // diagonal: mask j > q
            int qloc = w * 16 + lg * 4;
#pragma unroll
            for (int n = 0; n < 4; n++) {
                int jloc = n * 16 + li;
#pragma unroll
                for (int r = 0; r < 4; r++)
                    if (jloc > qloc + r) s[n][r] = -1e30f;
            }
        }

        // ---- online softmax (log2 domain), defer-max ----
        float mx4[4];
#pragma unroll
        for (int r = 0; r < 4; r++) {
            float mx = fmaxf(fmaxf(s[0][r], s[1][r]), fmaxf(s[2][r], s[3][r]));
#pragma unroll
            for (int msk = 1; msk <= 8; msk <<= 1) mx = fmaxf(mx, __shfl_xor(mx, msk, 64));
            mx4[r] = mx;
        }
        bool dfr = (mx4[0] - m_run[0] <= THR) && (mx4[1] - m_run[1] <= THR) &&
                   (mx4[2] - m_run[2] <= THR) && (mx4[3] - m_run[3] <= THR);
        dfr = __all(dfr);
        float scl[4] = {1.f, 1.f, 1.f, 1.f};
        if (!dfr) {
#pragma unroll
            for (int r = 0; r < 4; r++) {
                float mnew = fmaxf(m_run[r], mx4[r]);
                scl[r] = exp2f(m_run[r] - mnew);
                m_run[r] = mnew;
            }
        }
        float rs[4] = {0.f, 0.f, 0.f, 0.f};
#pragma unroll
        for (int n = 0; n < 4; n++)
#pragma unroll
            for (int r = 0; r < 4; r++) {
                float p = exp2f(s[n][r] - m_run[r]);
                s[n][r] = p;
                rs[r] += p;
            }
#pragma unroll
        for (int r = 0; r < 4; r++) {
#pragma unroll
            for (int msk = 1; msk <= 8; msk <<= 1) rs[r] += __shfl_xor(rs[r], msk, 64);
            l_run[r] = (dfr ? l_run[r] : l_run[r] * scl[r]) + rs[r];
        }

        // ---- P -> LDS (bf16), re-read as A-frags (wave-local) ----
#pragma unroll
        for (int n = 0; n < 4; n++)
#pragma unroll
            for (int r = 0; r < 4; r++) {
                hbf16 t = __float2bfloat16(s[n][r]);
                P_lds[w][(lg * 4 + r) * PST + n * 16 + li] = *(__bf16*)&t;
            }
        bf16x8 pa0 = *(const bf16x8*)&P_lds[w][li * PST + lg * 8];
        bf16x8 pa1 = *(const bf16x8*)&P_lds[w][li * PST + 32 + lg * 8];

        if (!dfr) {
#pragma unroll
            for (int n2 = 0; n2 < 4; n2++)
#pragma unroll
                for (int r = 0; r < 4; r++) acc_o[n2][r] *= scl[r];
        }

        __syncthreads();  // Vt writes visible
        __builtin_amdgcn_s_setprio(1);
#pragma unroll
        for (int n2 = 0; n2 < 4; n2++) {
            bf16x8 vf0 = *(const bf16x8*)&Vt[(n2 * 16 + li) * VST + lg * 8];
            bf16x8 vf1 = *(const bf16x8*)&Vt[(n2 * 16 + li) * VST + 32 + lg * 8];
            acc_o[n2] = __builtin_amdgcn_mfma_f32_16x16x32_bf16(pa0, vf0, acc_o[n2], 0, 0, 0);
            acc_o[n2] = __builtin_amdgcn_mfma_f32_16x16x32_bf16(pa1, vf1, acc_o[n2], 0, 0, 0);
        }
        __builtin_amdgcn_s_setprio(0);
        __syncthreads();  // PV reads done before next stage overwrites Vt
    }

#pragma unroll
    for (int r = 0; r < 4; r++) {
        float rcp = 1.f / l_run[r];
        int row = q0 + w * 16 + lg * 4 + r;
#pragma unroll
        for (int n2 = 0; n2 < 4; n2++)
            y[(size_t)(b * Tc + row) * Dc + h * HDc + n2 * 16 + li] =
                __float2bfloat16(acc_o[n2][r] * rcp);
    }
}

extern "C" void kernel_launch(void* const* d_in, const int* in_sizes, int n_in,
                              void* d_out, int out_size, void* d_ws, size_t ws_size,
                              hipStream_t stream) {
    const int* x = (const int*)d_in[0];
    const float* wte = (const float*)d_in[1];
    const float* wpe = (const float*)d_in[2];
    const float* ln1w = (const float*)d_in[3];
    const float* ln1b = (const float*)d_in[4];
    const float* qkvw = (const float*)d_in[5];
    const float* qkvb = (const float*)d_in[6];
    const float* projw = (const float*)d_in[7];
    const float* projb = (const float*)d_in[8];
    const float* ln2w = (const float*)d_in[9];
    const float* ln2b = (const float*)d_in[10];
    const float* fcw = (const float*)d_in[11];
    const float* fcb = (const float*)d_in[12];
    const float* fcpw = (const float*)d_in[13];
    const float* fcpb = (const float*)d_in[14];
    const float* lnfw = (const float*)d_in[15];
    const float* lnfb = (const float*)d_in[16];

    char* p = (char*)d_ws;
    float* h = (float*)p;     p += (size_t)Mc * Dc * 4;      // f32 [M][D]
    hbf16* qkv = (hbf16*)p;   p += (size_t)Mc * 3 * Dc * 2;  // bf16 [M][3D]
    hbf16* a = (hbf16*)p;     p += (size_t)Mc * Dc * 2;      // bf16 [M][D]
    hbf16* y = (hbf16*)p;     p += (size_t)Mc * Dc * 2;      // bf16 [M][D]
    hbf16* mlp = (hbf16*)p;   p += (size_t)Mc * 4 * Dc * 2;  // bf16 [M][4D]
    hbf16* wte_b = (hbf16*)p; p += (size_t)Vpad * Dc * 2;    // [50304][768]
    hbf16* wtr = (hbf16*)p;                                  // transposed weights
    size_t used = (size_t)((char*)wtr - (char*)d_ws);
    bool all_mode = (ws_size - used) >= (size_t)Lc * SZL * 2;

    embed_kernel<<<(Mc * Dc + 255) / 256, 256, 0, stream>>>(x, wte, wpe, h);
    convert_wte<<<((size_t)Vpad * Dc / 4 + 255) / 256, 256, 0, stream>>>(wte, wte_b);

    if (all_mode) {
        transpose4_kernel<<<dim3(6912, Lc), 256, 0, stream>>>(
            qkvw, projw, fcw, fcpw,
            wtr, wtr + SZ_Q, wtr + SZ_Q + SZ_P, wtr + SZ_Q + SZ_P + SZ_F);
    }

    for (int l = 0; l < Lc; l++) {
        hbf16* base = wtr + (all_mode ? (size_t)l * SZL : 0);
        hbf16* wq_t = base;
        hbf16* wp_t = base + SZ_Q;
        hbf16* wf_t = base + SZ_Q + SZ_P;
        hbf16* wfp_t = base + SZ_Q + SZ_P + SZ_F;
        if (!all_mode) {
            transpose4_kernel<<<dim3(6912, 1), 256, 0, stream>>>(
                qkvw + (size_t)l * SZ_Q, projw + (size_t)l * SZ_P,
                fcw + (size_t)l * SZ_F, fcpw + (size_t)l * SZ_FP,
                wq_t, wp_t, wf_t, wfp_t);
        }

        ln_kernel<<<Mc / 4, 256, 0, stream>>>(h, ln1w + (size_t)l * Dc, ln1b + (size_t)l * Dc, a);
        mm_kernel<0, true, 128><<<dim3(3 * Dc / 128, Mc / 128), 256, 0, stream>>>(
            a, wq_t, qkvb + (size_t)l * 3 * Dc, nullptr, qkv, Mc, 3 * Dc, Dc);
        fattn_kernel<<<dim3(Tc / 64, Hc, Bc), 256, 0, stream>>>(qkv, y);
        mm_kernel<1, false, 64><<<dim3(Dc / 64, Mc / 128), 256, 0, stream>>>(
            y, wp_t, projb + (size_t)l * Dc, h, h, Mc, Dc, Dc);
        ln_kernel<<<Mc / 4, 256, 0, stream>>>(h, ln2w + (size_t)l * Dc, ln2b + (size_t)l * Dc, a);
        mm_kernel<2, true, 128><<<dim3(4 * Dc / 128, Mc / 128), 256, 0, stream>>>(
            a, wf_t, fcb + (size_t)l * 4 * Dc, nullptr, mlp, Mc, 4 * Dc, Dc);
        mm_kernel<1, false, 64><<<dim3(Dc / 64, Mc / 128), 256, 0, stream>>>(
            mlp, wfp_t, fcpb + (size_t)l * Dc, h, h, Mc, Dc, 4 * Dc);
    }

    ln_kernel<<<Mc / 4, 256, 0, stream>>>(h, lnfw, lnfb, a);
    mm2_kernel<<<dim3(Vpad / 128, Mc / 256), 512, 0, stream>>>(
        a, wte_b, (float*)d_out, Mc, Vc, Dc);
}

// Round 10
// 2796.367 us; speedup vs baseline: 1.0070x; 1.0070x over previous
//
#include <hip/hip_runtime.h>
#include <hip/hip_bf16.h>

typedef __hip_bfloat16 hbf16;
using bf16x8 = __attribute__((ext_vector_type(8))) __bf16;
using f32x4 = __attribute__((ext_vector_type(4))) float;

// GPT-2 small: L=12 H=12 D=768 V=50257 T=1024 B=2, HD=64
constexpr int Lc = 12, Hc = 12, Dc = 768, Vc = 50257, Tc = 1024, Bc = 2, HDc = 64;
constexpr int Mc = Bc * Tc;  // 2048 rows
constexpr int Vpad = 50304;  // 393*128, zero-padded vocab

// transposed-weight slot sizes (elements)
constexpr size_t SZ_Q = (size_t)3 * Dc * Dc;   // [2304][768]
constexpr size_t SZ_P = (size_t)Dc * Dc;       // [768][768]
constexpr size_t SZ_F = (size_t)4 * Dc * Dc;   // [3072][768]
constexpr size_t SZ_FP = (size_t)4 * Dc * Dc;  // [768][3072]
constexpr size_t SZL = SZ_Q + SZ_P + SZ_F + SZ_FP;

#define GLD16(gp, lp)                                               \
    __builtin_amdgcn_global_load_lds(                               \
        (__attribute__((address_space(1))) void*)(void*)(gp),       \
        (__attribute__((address_space(3))) void*)(void*)(lp), 16, 0, 0)

// ---------------- embedding: h = wte[x] + wpe[t] (f32) ----------------
__global__ void embed_kernel(const int* __restrict__ x, const float* __restrict__ wte,
                             const float* __restrict__ wpe, float* __restrict__ h) {
    int i = blockIdx.x * blockDim.x + threadIdx.x;
    if (i >= Mc * Dc) return;
    int m = i / Dc, d = i - m * Dc;
    int t = m % Tc;
    int tok = x[m];
    h[i] = wte[(size_t)tok * Dc + d] + wpe[(size_t)t * Dc + d];
}

// ---------------- layernorm: one wave per row, shuffle reduce, f32 in -> bf16 out --
__global__ __launch_bounds__(256) void ln_kernel(const float* __restrict__ x,
                                                 const float* __restrict__ w,
                                                 const float* __restrict__ b,
                                                 hbf16* __restrict__ out) {
    int wv = threadIdx.x >> 6, lane = threadIdx.x & 63;
    int row = blockIdx.x * 4 + wv;
    const float4* xr = (const float4*)(x + (size_t)row * Dc);
    float4 v[3];
    float s = 0.f, sq = 0.f;
#pragma unroll
    for (int i = 0; i < 3; i++) {
        v[i] = xr[i * 64 + lane];
        s += v[i].x + v[i].y + v[i].z + v[i].w;
        sq += v[i].x * v[i].x + v[i].y * v[i].y + v[i].z * v[i].z + v[i].w * v[i].w;
    }
#pragma unroll
    for (int o = 32; o > 0; o >>= 1) {
        s += __shfl_xor(s, o, 64);
        sq += __shfl_xor(sq, o, 64);
    }
    float mean = s * (1.f / Dc);
    float var = sq * (1.f / Dc) - mean * mean;
    float rstd = rsqrtf(var + 1e-5f);
#pragma unroll
    for (int i = 0; i < 3; i++) {
        int c = (i * 64 + lane) * 4;
        float4 wv4 = *(const float4*)(w + c);
        float4 bv4 = *(const float4*)(b + c);
        float r0 = (v[i].x - mean) * rstd * wv4.x + bv4.x;
        float r1 = (v[i].y - mean) * rstd * wv4.y + bv4.y;
        float r2 = (v[i].z - mean) * rstd * wv4.z + bv4.z;
        float r3 = (v[i].w - mean) * rstd * wv4.w + bv4.w;
        __bf16 q0 = (__bf16)r0, q1 = (__bf16)r1, q2 = (__bf16)r2, q3 = (__bf16)r3;
        ushort4 u;
        u.x = *(unsigned short*)&q0; u.y = *(unsigned short*)&q1;
        u.z = *(unsigned short*)&q2; u.w = *(unsigned short*)&q3;
        *(ushort4*)(out + (size_t)row * Dc + c) = u;
    }
}

// ---------------- weight transpose, grid (6912, nlayers) ----------------
__global__ __launch_bounds__(256) void transpose4_kernel(
    const float* __restrict__ s0, const float* __restrict__ s1,
    const float* __restrict__ s2, const float* __restrict__ s3,
    hbf16* __restrict__ d0, hbf16* __restrict__ d1,
    hbf16* __restrict__ d2, hbf16* __restrict__ d3) {
    int id = blockIdx.x;
    size_t lz = blockIdx.y;
    int bx, by, K, N;
    const float* W;
    hbf16* Wt;
    if (id < 1728)      { int t = id;        bx = t % 72; by = t / 72; K = 768;  N = 2304; W = s0 + lz * SZ_Q;  Wt = d0 + lz * SZL; }
    else if (id < 2304) { int t = id - 1728; bx = t % 24; by = t / 24; K = 768;  N = 768;  W = s1 + lz * SZ_P;  Wt = d1 + lz * SZL; }
    else if (id < 4608) { int t = id - 2304; bx = t % 96; by = t / 96; K = 768;  N = 3072; W = s2 + lz * SZ_F;  Wt = d2 + lz * SZL; }
    else                { int t = id - 4608; bx = t % 24; by = t / 24; K = 3072; N = 768;  W = s3 + lz * SZ_FP; Wt = d3 + lz * SZL; }

    __shared__ float tile[32][33];
    int n0 = bx * 32, k0 = by * 32;
    int tx = threadIdx.x & 31, ty = threadIdx.x >> 5;  // 32x8
#pragma unroll
    for (int i = 0; i < 4; i++) {
        int r = ty + i * 8;
        tile[r][tx] = W[(size_t)(k0 + r) * N + n0 + tx];
    }
    __syncthreads();
#pragma unroll
    for (int i = 0; i < 4; i++) {
        int r = ty + i * 8;
        Wt[(size_t)(n0 + r) * K + k0 + tx] = __float2bfloat16(tile[tx][r]);
    }
}

// ---------------- wte f32 [V][D] -> bf16 [Vpad][D] (zero pad) ----------------
__global__ void convert_wte(const float* __restrict__ wte, hbf16* __restrict__ out) {
    size_t i4 = ((size_t)blockIdx.x * 256 + threadIdx.x) * 4;
    if (i4 >= (size_t)Vpad * Dc) return;
    if (i4 < (size_t)Vc * Dc) {
#pragma unroll
        for (int j = 0; j < 4; j++) out[i4 + j] = __float2bfloat16(wte[i4 + j]);
    } else {
#pragma unroll
        for (int j = 0; j < 4; j++) out[i4 + j] = __float2bfloat16(0.f);
    }
}

// ---------------- MFMA GEMM 64x64, ONE WAVE per block, dbuf + counted vmcnt -------
// No __syncthreads(): single wave => no barrier => counted vmcnt pipeline survives.
// EPI: 0 = +bias, 1 = +bias +f32 residual, 2 = +bias + tanh-GELU
template <int EPI, bool OUTBF>
__global__ __launch_bounds__(64) void mm64_kernel(const hbf16* __restrict__ A,
                                                  const hbf16* __restrict__ Bt,
                                                  const float* __restrict__ bias,
                                                  const float* __restrict__ resid,
                                                  void* __restrict__ Cout,
                                                  int M, int N, int K) {
    __shared__ __bf16 As[2][64 * 32];  // 2 x 4 KB
    __shared__ __bf16 Bs[2][64 * 32];  // 2 x 4 KB
    int l = threadIdx.x;

    // XCD swizzle on hw dispatch order (x fastest); m fastest within chunk.
    int gx = gridDim.x, gy = gridDim.y;
    int nwg = gx * gy;  // divisible by 8 for all launches here
    int hwlin = blockIdx.y * gx + blockIdx.x;
    int wk = (hwlin & 7) * (nwg >> 3) + (hwlin >> 3);
    int m0 = (wk % gy) * 64;
    int n0 = (wk / gy) * 64;

    // staging: issue j covers rows j*16 + (l>>2); slot swizzle s' = s ^ (row&3)
    int sr4 = l >> 2, sc = l & 3;
    int scs = (sc ^ (sr4 & 3)) * 8;
    const hbf16* pA = A + (size_t)(m0 + sr4) * K + scs;
    const hbf16* pB = Bt + (size_t)(n0 + sr4) * K + scs;
    size_t rstep = (size_t)16 * K;

    int lr = l & 15, lg = l >> 4;
    int ksl = (lg ^ (lr & 3)) * 8;  // swizzled k-slot for frag reads
    int aoff[4], boff[4];
#pragma unroll
    for (int m = 0; m < 4; m++) aoff[m] = (m * 16 + lr) * 32 + ksl;
#pragma unroll
    for (int n = 0; n < 4; n++) boff[n] = (n * 16 + lr) * 32 + ksl;

    f32x4 acc[4][4] = {};
    int nk = K / 32;

    // prologue: stage tile 0 (8 outstanding loads)
#pragma unroll
    for (int j = 0; j < 4; j++) {
        GLD16(pA + j * rstep, &As[0][j * 512 + l * 8]);
        GLD16(pB + j * rstep, &Bs[0][j * 512 + l * 8]);
    }

    for (int t = 0; t < nk; ++t) {
        int cur = t & 1;
        if (t + 1 < nk) {
            int ko = (t + 1) * 32;
#pragma unroll
            for (int j = 0; j < 4; j++) {
                GLD16(pA + ko + j * rstep, &As[cur ^ 1][j * 512 + l * 8]);
                GLD16(pB + ko + j * rstep, &Bs[cur ^ 1][j * 512 + l * 8]);
            }
            asm volatile("s_waitcnt vmcnt(8)" ::: "memory");  // cur's 8 done; next 8 fly
        } else {
            asm volatile("s_waitcnt vmcnt(0)" ::: "memory");
        }
        __builtin_amdgcn_sched_barrier(0);
        bf16x8 af[4], bfr[4];
#pragma unroll
        for (int m = 0; m < 4; m++) af[m] = *(const bf16x8*)&As[cur][aoff[m]];
#pragma unroll
        for (int n = 0; n < 4; n++) bfr[n] = *(const bf16x8*)&Bs[cur][boff[n]];
#pragma unroll
        for (int m = 0; m < 4; m++)
#pragma unroll
            for (int n = 0; n < 4; n++)
                acc[m][n] = __builtin_amdgcn_mfma_f32_16x16x32_bf16(af[m], bfr[n], acc[m][n], 0, 0, 0);
    }

#pragma unroll
    for (int n = 0; n < 4; n++) {
        int col = n0 + n * 16 + lr;
        float bv = bias ? bias[col] : 0.f;
#pragma unroll
        for (int m = 0; m < 4; m++) {
#pragma unroll
            for (int r = 0; r < 4; r++) {
                int row = m0 + m * 16 + lg * 4 + r;
                float v = acc[m][n][r] + bv;
                if (EPI == 1) v += resid[(size_t)row * N + col];
                if (EPI == 2) {
                    float x3 = v * v * v;
                    v = 0.5f * v * (1.f + tanhf(0.7978845608028654f * (v + 0.044715f * x3)));
                }
                if (OUTBF)
                    ((hbf16*)Cout)[(size_t)row * N + col] = __float2bfloat16(v);
                else
                    ((float*)Cout)[(size_t)row * N + col] = v;
            }
        }
    }
}

// ---------------- MFMA GEMM 256x128, 512 threads, 2-phase dbuf (lm_head) ----------
__global__ __launch_bounds__(512) void mm2_kernel(const hbf16* __restrict__ A,
                                                  const hbf16* __restrict__ Bt,
                                                  float* __restrict__ Cout,
                                                  int M, int N, int K) {
    __shared__ __bf16 As[2][256 * 32];  // 2 x 16 KB
    __shared__ __bf16 Bs[2][128 * 32];  // 2 x 8 KB
    int tid = threadIdx.x;
    int l = tid & 63, w = tid >> 6;
    int wr = w >> 1, wc = w & 1;

    int gx = gridDim.x, gy = gridDim.y;  // gy = 8
    int nwg = gx * gy;
    int hwlin = blockIdx.y * gx + blockIdx.x;
    int wk = (hwlin & 7) * (nwg >> 3) + (hwlin >> 3);
    int m0 = (wk & 7) * 256;
    int n0 = (wk >> 3) * 128;

    int sr = tid >> 2, sc = tid & 3;
    int scs = (sc ^ (sr & 3)) * 8;
    const hbf16* gA0 = A + (size_t)(m0 + sr) * K + scs;
    const hbf16* gA1 = A + (size_t)(m0 + 128 + sr) * K + scs;
    const hbf16* gB = Bt + (size_t)(n0 + sr) * K + scs;

    auto stage = [&](int bi, int ko) {
        GLD16(gA0 + ko, &As[bi][tid * 8]);
        GLD16(gA1 + ko, &As[bi][4096 + tid * 8]);
        GLD16(gB + ko, &Bs[bi][tid * 8]);
    };

    int lr = l & 15, lg = l >> 4;
    int ksl = (lg ^ (lr & 3)) * 8;
    int aoff[4], boff[4];
#pragma unroll
    for (int m = 0; m < 4; m++) aoff[m] = (wr * 64 + m * 16 + lr) * 32 + ksl;
#pragma unroll
    for (int n = 0; n < 4; n++) boff[n] = (wc * 64 + n * 16 + lr) * 32 + ksl;

    f32x4 acc[4][4] = {};
    int nk = K / 32;

    stage(0, 0);
    __syncthreads();
    for (int t = 0; t < nk; ++t) {
        int cur = t & 1;
        if (t + 1 < nk) stage(cur ^ 1, (t + 1) * 32);
        bf16x8 af[4], bfr[4];
#pragma unroll
        for (int m = 0; m < 4; m++) af[m] = *(const bf16x8*)&As[cur][aoff[m]];
#pragma unroll
        for (int n = 0; n < 4; n++) bfr[n] = *(const bf16x8*)&Bs[cur][boff[n]];
#pragma unroll
        for (int m = 0; m < 4; m++)
#pragma unroll
            for (int n = 0; n < 4; n++)
                acc[m][n] = __builtin_amdgcn_mfma_f32_16x16x32_bf16(af[m], bfr[n], acc[m][n], 0, 0, 0);
        __syncthreads();
    }

#pragma unroll
    for (int n = 0; n < 4; n++) {
        int col = n0 + wc * 64 + n * 16 + lr;
        if (col >= N) continue;
#pragma unroll
        for (int m = 0; m < 4; m++) {
#pragma unroll
            for (int r = 0; r < 4; r++) {
                int row = m0 + wr * 64 + m * 16 + lg * 4 + r;
                Cout[(size_t)row * N + col] = acc[m][n][r];
            }
        }
    }
}

// ---------------- MFMA flash attention (exp2 + defer-max + paired V-stage) --------
__global__ __launch_bounds__(256) void fattn_kernel(const hbf16* __restrict__ qkv,
                                                    hbf16* __restrict__ y) {
    int qt = gridDim.x - 1 - blockIdx.x;  // heavy tiles first
    int h = blockIdx.y, b = blockIdx.z;
    int q0 = qt * 64;
    int tid = threadIdx.x;
    int l = tid & 63, w = tid >> 6;
    int li = l & 15, lg = l >> 4;
    constexpr int RS = 3 * Dc;
    constexpr int PST = 72;
    constexpr int VST = 72;
    constexpr float SCL = 0.125f * 1.44269504f;  // fold 1/sqrt(64) and log2(e)
    constexpr float THR = 11.5f;                 // defer-max threshold (log2 domain)

    __shared__ __bf16 P_lds[4][16 * PST];
    __shared__ __bf16 Vt[64 * VST];

    bf16x8 qf[2];
    {
        const hbf16* qp = qkv + (size_t)(b * Tc + q0 + w * 16 + li) * RS + h * HDc + lg * 8;
        qf[0] = *(const bf16x8*)qp;
        qf[1] = *(const bf16x8*)(qp + 32);
    }

    f32x4 acc_o[4] = {};
    float m_run[4], l_run[4];
#pragma unroll
    for (int r = 0; r < 4; r++) { m_run[r] = -1e30f; l_run[r] = 0.f; }

    int jp = (tid >> 3) * 2;
    int db = (tid & 7) * 8;

    for (int jt = 0; jt <= qt; jt++) {
        int j0 = jt * 64;
        // ---- stage V^T: paired rows -> 8 x ds_write_b32 ----
        {
            const hbf16* vp0 = qkv + (size_t)(b * Tc + j0 + jp) * RS + 2 * Dc + h * HDc + db;
            bf16x8 v0 = *(const bf16x8*)vp0;
            bf16x8 v1 = *(const bf16x8*)(vp0 + RS);
#pragma unroll
            for (int i = 0; i < 8; i++) {
                __bf16 a0 = v0[i], a1 = v1[i];
                unsigned u = (unsigned)*(unsigned short*)&a0 |
                             ((unsigned)*(unsigned short*)&a1 << 16);
                *(unsigned*)&Vt[(db + i) * VST + jp] = u;
            }
        }

        // ---- S = Q K^T ----
        f32x4 s[4] = {};
#pragma unroll
        for (int ks = 0; ks < 2; ks++) {
#pragma unroll
            for (int n = 0; n < 4; n++) {
                const hbf16* kp = qkv + (size_t)(b * Tc + j0 + n * 16 + li) * RS + Dc + h * HDc + ks * 32 + lg * 8;
                bf16x8 kf = *(const bf16x8*)kp;
                s[n] = __builtin_amdgcn_mfma_f32_16x16x32_bf16(qf[ks], kf, s[n], 0, 0, 0);
            }
        }
#pragma unroll
        for (int n = 0; n < 4; n++)
#pragma unroll
            for (int r = 0; r < 4; r++) s[n][r] *= SCL;

        if (jt == qt) {  // diagonal: mask j > q
            int qloc = w * 16 + lg * 4;
#pragma unroll
            for (int n = 0; n < 4; n++) {
                int jloc = n * 16 + li;
#pragma unroll
                for (int r = 0; r < 4; r++)
                    if (jloc > qloc + r) s[n][r] = -1e30f;
            }
        }

        // ---- online softmax (log2 domain), defer-max ----
        float mx4[4];
#pragma unroll
        for (int r = 0; r < 4; r++) {
            float mx = fmaxf(fmaxf(s[0][r], s[1][r]), fmaxf(s[2][r], s[3][r]));
#pragma unroll
            for (int msk = 1; msk <= 8; msk <<= 1) mx = fmaxf(mx, __shfl_xor(mx, msk, 64));
            mx4[r] = mx;
        }
        bool dfr = (mx4[0] - m_run[0] <= THR) && (mx4[1] - m_run[1] <= THR) &&
                   (mx4[2] - m_run[2] <= THR) && (mx4[3] - m_run[3] <= THR);
        dfr = __all(dfr);
        float scl[4] = {1.f, 1.f, 1.f, 1.f};
        if (!dfr) {
#pragma unroll
            for (int r = 0; r < 4; r++) {
                float mnew = fmaxf(m_run[r], mx4[r]);
                scl[r] = exp2f(m_run[r] - mnew);
                m_run[r] = mnew;
            }
        }
        float rs[4] = {0.f, 0.f, 0.f, 0.f};
#pragma unroll
        for (int n = 0; n < 4; n++)
#pragma unroll
            for (int r = 0; r < 4; r++) {
                float p = exp2f(s[n][r] - m_run[r]);
                s[n][r] = p;
                rs[r] += p;
            }
#pragma unroll
        for (int r = 0; r < 4; r++) {
#pragma unroll
            for (int msk = 1; msk <= 8; msk <<= 1) rs[r] += __shfl_xor(rs[r], msk, 64);
            l_run[r] = (dfr ? l_run[r] : l_run[r] * scl[r]) + rs[r];
        }

        // ---- P -> LDS (bf16), re-read as A-frags (wave-local) ----
#pragma unroll
        for (int n = 0; n < 4; n++)
#pragma unroll
            for (int r = 0; r < 4; r++) {
                hbf16 t = __float2bfloat16(s[n][r]);
                P_lds[w][(lg * 4 + r) * PST + n * 16 + li] = *(__bf16*)&t;
            }
        bf16x8 pa0 = *(const bf16x8*)&P_lds[w][li * PST + lg * 8];
        bf16x8 pa1 = *(const bf16x8*)&P_lds[w][li * PST + 32 + lg * 8];

        if (!dfr) {
#pragma unroll
            for (int n2 = 0; n2 < 4; n2++)
#pragma unroll
                for (int r = 0; r < 4; r++) acc_o[n2][r] *= scl[r];
        }

        __syncthreads();  // Vt writes visible
#pragma unroll
        for (int n2 = 0; n2 < 4; n2++) {
            bf16x8 vf0 = *(const bf16x8*)&Vt[(n2 * 16 + li) * VST + lg * 8];
            bf16x8 vf1 = *(const bf16x8*)&Vt[(n2 * 16 + li) * VST + 32 + lg * 8];
            acc_o[n2] = __builtin_amdgcn_mfma_f32_16x16x32_bf16(pa0, vf0, acc_o[n2], 0, 0, 0);
            acc_o[n2] = __builtin_amdgcn_mfma_f32_16x16x32_bf16(pa1, vf1, acc_o[n2], 0, 0, 0);
        }
        __syncthreads();  // PV reads done before next stage overwrites Vt
    }

#pragma unroll
    for (int r = 0; r < 4; r++) {
        float rcp = 1.f / l_run[r];
        int row = q0 + w * 16 + lg * 4 + r;
#pragma unroll
        for (int n2 = 0; n2 < 4; n2++)
            y[(size_t)(b * Tc + row) * Dc + h * HDc + n2 * 16 + li] =
                __float2bfloat16(acc_o[n2][r] * rcp);
    }
}

extern "C" void kernel_launch(void* const* d_in, const int* in_sizes, int n_in,
                              void* d_out, int out_size, void* d_ws, size_t ws_size,
                              hipStream_t stream) {
    const int* x = (const int*)d_in[0];
    const float* wte = (const float*)d_in[1];
    const float* wpe = (const float*)d_in[2];
    const float* ln1w = (const float*)d_in[3];
    const float* ln1b = (const float*)d_in[4];
    const float* qkvw = (const float*)d_in[5];
    const float* qkvb = (const float*)d_in[6];
    const float* projw = (const float*)d_in[7];
    const float* projb = (const float*)d_in[8];
    const float* ln2w = (const float*)d_in[9];
    const float* ln2b = (const float*)d_in[10];
    const float* fcw = (const float*)d_in[11];
    const float* fcb = (const float*)d_in[12];
    const float* fcpw = (const float*)d_in[13];
    const float* fcpb = (const float*)d_in[14];
    const float* lnfw = (const float*)d_in[15];
    const float* lnfb = (const float*)d_in[16];

    char* p = (char*)d_ws;
    float* h = (float*)p;     p += (size_t)Mc * Dc * 4;      // f32 [M][D]
    hbf16* qkv = (hbf16*)p;   p += (size_t)Mc * 3 * Dc * 2;  // bf16 [M][3D]
    hbf16* a = (hbf16*)p;     p += (size_t)Mc * Dc * 2;      // bf16 [M][D]
    hbf16* y = (hbf16*)p;     p += (size_t)Mc * Dc * 2;      // bf16 [M][D]
    hbf16* mlp = (hbf16*)p;   p += (size_t)Mc * 4 * Dc * 2;  // bf16 [M][4D]
    hbf16* wte_b = (hbf16*)p; p += (size_t)Vpad * Dc * 2;    // [50304][768]
    hbf16* wtr = (hbf16*)p;                                  // transposed weights
    size_t used = (size_t)((char*)wtr - (char*)d_ws);
    bool all_mode = (ws_size - used) >= (size_t)Lc * SZL * 2;

    embed_kernel<<<(Mc * Dc + 255) / 256, 256, 0, stream>>>(x, wte, wpe, h);
    convert_wte<<<((size_t)Vpad * Dc / 4 + 255) / 256, 256, 0, stream>>>(wte, wte_b);

    if (all_mode) {
        transpose4_kernel<<<dim3(6912, Lc), 256, 0, stream>>>(
            qkvw, projw, fcw, fcpw,
            wtr, wtr + SZ_Q, wtr + SZ_Q + SZ_P, wtr + SZ_Q + SZ_P + SZ_F);
    }

    for (int l = 0; l < Lc; l++) {
        hbf16* base = wtr + (all_mode ? (size_t)l * SZL : 0);
        hbf16* wq_t = base;
        hbf16* wp_t = base + SZ_Q;
        hbf16* wf_t = base + SZ_Q + SZ_P;
        hbf16* wfp_t = base + SZ_Q + SZ_P + SZ_F;
        if (!all_mode) {
            transpose4_kernel<<<dim3(6912, 1), 256, 0, stream>>>(
                qkvw + (size_t)l * SZ_Q, projw + (size_t)l * SZ_P,
                fcw + (size_t)l * SZ_F, fcpw + (size_t)l * SZ_FP,
                wq_t, wp_t, wf_t, wfp_t);
        }

        ln_kernel<<<Mc / 4, 256, 0, stream>>>(h, ln1w + (size_t)l * Dc, ln1b + (size_t)l * Dc, a);
        mm64_kernel<0, true><<<dim3(3 * Dc / 64, Mc / 64), 64, 0, stream>>>(
            a, wq_t, qkvb + (size_t)l * 3 * Dc, nullptr, qkv, Mc, 3 * Dc, Dc);
        fattn_kernel<<<dim3(Tc / 64, Hc, Bc), 256, 0, stream>>>(qkv, y);
        mm64_kernel<1, false><<<dim3(Dc / 64, Mc / 64), 64, 0, stream>>>(
            y, wp_t, projb + (size_t)l * Dc, h, h, Mc, Dc, Dc);
        ln_kernel<<<Mc / 4, 256, 0, stream>>>(h, ln2w + (size_t)l * Dc, ln2b + (size_t)l * Dc, a);
        mm64_kernel<2, true><<<dim3(4 * Dc / 64, Mc / 64), 64, 0, stream>>>(
            a, wf_t, fcb + (size_t)l * 4 * Dc, nullptr, mlp, Mc, 4 * Dc, Dc);
        mm64_kernel<1, false><<<dim3(Dc / 64, Mc / 64), 64, 0, stream>>>(
            mlp, wfp_t, fcpb + (size_t)l * Dc, h, h, Mc, Dc, 4 * Dc);
    }

    ln_kernel<<<Mc / 4, 256, 0, stream>>>(h, lnfw, lnfb, a);
    mm2_kernel<<<dim3(Vpad / 128, Mc / 256), 512, 0, stream>>>(
        a, wte_b, (float*)d_out, Mc, Vc, Dc);
}

// Round 11
// 2719.457 us; speedup vs baseline: 1.0355x; 1.0283x over previous
//
#include <hip/hip_runtime.h>
#include <hip/hip_bf16.h>

typedef __hip_bfloat16 hbf16;
using bf16x8 = __attribute__((ext_vector_type(8))) __bf16;
using f32x4 = __attribute__((ext_vector_type(4))) float;

// GPT-2 small: L=12 H=12 D=768 V=50257 T=1024 B=2, HD=64
constexpr int Lc = 12, Hc = 12, Dc = 768, Vc = 50257, Tc = 1024, Bc = 2, HDc = 64;
constexpr int Mc = Bc * Tc;  // 2048 rows
constexpr int Vpad = 50304;  // 393*128, zero-padded vocab

// transposed-weight slot sizes (elements)
constexpr size_t SZ_Q = (size_t)3 * Dc * Dc;   // [2304][768]
constexpr size_t SZ_P = (size_t)Dc * Dc;       // [768][768]
constexpr size_t SZ_F = (size_t)4 * Dc * Dc;   // [3072][768]
constexpr size_t SZ_FP = (size_t)4 * Dc * Dc;  // [768][3072]
constexpr size_t SZL = SZ_Q + SZ_P + SZ_F + SZ_FP;

#define GLD16(gp, lp)                                               \
    __builtin_amdgcn_global_load_lds(                               \
        (__attribute__((address_space(1))) void*)(void*)(gp),       \
        (__attribute__((address_space(3))) void*)(void*)(lp), 16, 0, 0)

// ---------------- embedding: h = wte[x] + wpe[t] (f32) ----------------
__global__ void embed_kernel(const int* __restrict__ x, const float* __restrict__ wte,
                             const float* __restrict__ wpe, float* __restrict__ h) {
    int i = blockIdx.x * blockDim.x + threadIdx.x;
    if (i >= Mc * Dc) return;
    int m = i / Dc, d = i - m * Dc;
    int t = m % Tc;
    int tok = x[m];
    h[i] = wte[(size_t)tok * Dc + d] + wpe[(size_t)t * Dc + d];
}

// ---------------- layernorm: one wave per row, shuffle reduce, f32 in -> bf16 out --
__global__ __launch_bounds__(256) void ln_kernel(const float* __restrict__ x,
                                                 const float* __restrict__ w,
                                                 const float* __restrict__ b,
                                                 hbf16* __restrict__ out) {
    int wv = threadIdx.x >> 6, lane = threadIdx.x & 63;
    int row = blockIdx.x * 4 + wv;
    const float4* xr = (const float4*)(x + (size_t)row * Dc);
    float4 v[3];
    float s = 0.f, sq = 0.f;
#pragma unroll
    for (int i = 0; i < 3; i++) {
        v[i] = xr[i * 64 + lane];
        s += v[i].x + v[i].y + v[i].z + v[i].w;
        sq += v[i].x * v[i].x + v[i].y * v[i].y + v[i].z * v[i].z + v[i].w * v[i].w;
    }
#pragma unroll
    for (int o = 32; o > 0; o >>= 1) {
        s += __shfl_xor(s, o, 64);
        sq += __shfl_xor(sq, o, 64);
    }
    float mean = s * (1.f / Dc);
    float var = sq * (1.f / Dc) - mean * mean;
    float rstd = rsqrtf(var + 1e-5f);
#pragma unroll
    for (int i = 0; i < 3; i++) {
        int c = (i * 64 + lane) * 4;
        float4 wv4 = *(const float4*)(w + c);
        float4 bv4 = *(const float4*)(b + c);
        float r0 = (v[i].x - mean) * rstd * wv4.x + bv4.x;
        float r1 = (v[i].y - mean) * rstd * wv4.y + bv4.y;
        float r2 = (v[i].z - mean) * rstd * wv4.z + bv4.z;
        float r3 = (v[i].w - mean) * rstd * wv4.w + bv4.w;
        __bf16 q0 = (__bf16)r0, q1 = (__bf16)r1, q2 = (__bf16)r2, q3 = (__bf16)r3;
        ushort4 u;
        u.x = *(unsigned short*)&q0; u.y = *(unsigned short*)&q1;
        u.z = *(unsigned short*)&q2; u.w = *(unsigned short*)&q3;
        *(ushort4*)(out + (size_t)row * Dc + c) = u;
    }
}

// ---------------- weight transpose, grid (6912, nlayers) ----------------
__global__ __launch_bounds__(256) void transpose4_kernel(
    const float* __restrict__ s0, const float* __restrict__ s1,
    const float* __restrict__ s2, const float* __restrict__ s3,
    hbf16* __restrict__ d0, hbf16* __restrict__ d1,
    hbf16* __restrict__ d2, hbf16* __restrict__ d3) {
    int id = blockIdx.x;
    size_t lz = blockIdx.y;
    int bx, by, K, N;
    const float* W;
    hbf16* Wt;
    if (id < 1728)      { int t = id;        bx = t % 72; by = t / 72; K = 768;  N = 2304; W = s0 + lz * SZ_Q;  Wt = d0 + lz * SZL; }
    else if (id < 2304) { int t = id - 1728; bx = t % 24; by = t / 24; K = 768;  N = 768;  W = s1 + lz * SZ_P;  Wt = d1 + lz * SZL; }
    else if (id < 4608) { int t = id - 2304; bx = t % 96; by = t / 96; K = 768;  N = 3072; W = s2 + lz * SZ_F;  Wt = d2 + lz * SZL; }
    else                { int t = id - 4608; bx = t % 24; by = t / 24; K = 3072; N = 768;  W = s3 + lz * SZ_FP; Wt = d3 + lz * SZL; }

    __shared__ float tile[32][33];
    int n0 = bx * 32, k0 = by * 32;
    int tx = threadIdx.x & 31, ty = threadIdx.x >> 5;  // 32x8
#pragma unroll
    for (int i = 0; i < 4; i++) {
        int r = ty + i * 8;
        tile[r][tx] = W[(size_t)(k0 + r) * N + n0 + tx];
    }
    __syncthreads();
#pragma unroll
    for (int i = 0; i < 4; i++) {
        int r = ty + i * 8;
        Wt[(size_t)(n0 + r) * K + k0 + tx] = __float2bfloat16(tile[tx][r]);
    }
}

// ---------------- wte f32 [V][D] -> bf16 [Vpad][D] (zero pad) ----------------
__global__ void convert_wte(const float* __restrict__ wte, hbf16* __restrict__ out) {
    size_t i4 = ((size_t)blockIdx.x * 256 + threadIdx.x) * 4;
    if (i4 >= (size_t)Vpad * Dc) return;
    if (i4 < (size_t)Vc * Dc) {
#pragma unroll
        for (int j = 0; j < 4; j++) out[i4 + j] = __float2bfloat16(wte[i4 + j]);
    } else {
#pragma unroll
        for (int j = 0; j < 4; j++) out[i4 + j] = __float2bfloat16(0.f);
    }
}

// ---------------- MFMA GEMM 128xBN, single-buffer (R7 config): C = A@Bt^T + epi ---
// EPI: 0 = +bias, 1 = +bias +f32 residual, 2 = +bias + tanh-GELU
template <int EPI, bool OUTBF, int BN>
__global__ __launch_bounds__(256) void mm_kernel(const hbf16* __restrict__ A,
                                                 const hbf16* __restrict__ Bt,
                                                 const float* __restrict__ bias,
                                                 const float* __restrict__ resid,
                                                 void* __restrict__ Cout,
                                                 int M, int N, int K) {
    constexpr int NF = BN / 32;  // n-frags per wave
    __shared__ __bf16 As[128 * 32];
    __shared__ __bf16 Bs[BN * 32];
    int tid = threadIdx.x;
    int l = tid & 63, w = tid >> 6;
    int wr = w >> 1, wc = w & 1;

    int gx = gridDim.x, gy = gridDim.y;
    int nwg = gx * gy;
    int hwlin = blockIdx.y * gx + blockIdx.x;
    int wk = (hwlin & 7) * (nwg >> 3) + (hwlin >> 3);
    int m0 = (wk % gy) * 128;
    int n0 = (wk / gy) * BN;

    int sr = tid >> 2, sc = tid & 3;
    int scs = (sc ^ (sr & 3)) * 8;
    const hbf16* pA0 = A + (size_t)(m0 + sr) * K + scs;
    const hbf16* pA1 = A + (size_t)(m0 + 64 + sr) * K + scs;
    const hbf16* pB0 = Bt + (size_t)(n0 + sr) * K + scs;
    const hbf16* pB1 = (BN == 128) ? Bt + (size_t)(n0 + 64 + sr) * K + scs : pB0;
    __bf16* lA0 = As + tid * 8;
    __bf16* lA1 = As + 2048 + tid * 8;
    __bf16* lB0 = Bs + tid * 8;
    __bf16* lB1 = Bs + 2048 + tid * 8;

    int lr = l & 15, lg = l >> 4;
    int ksl = (lg ^ (lr & 3)) * 8;
    int aoff[4], boff[NF];
#pragma unroll
    for (int m = 0; m < 4; m++) aoff[m] = (wr * 64 + m * 16 + lr) * 32 + ksl;
#pragma unroll
    for (int n = 0; n < NF; n++) boff[n] = (wc * (BN / 2) + n * 16 + lr) * 32 + ksl;

    f32x4 acc[4][NF] = {};

    for (int k0 = 0; k0 < K; k0 += 32) {
        GLD16(pA0, lA0);
        GLD16(pA1, lA1);
        GLD16(pB0, lB0);
        if constexpr (BN == 128) GLD16(pB1, lB1);
        pA0 += 32; pA1 += 32; pB0 += 32;
        if constexpr (BN == 128) pB1 += 32;
        __syncthreads();
        bf16x8 af[4], bfr[NF];
#pragma unroll
        for (int m = 0; m < 4; m++) af[m] = *(const bf16x8*)&As[aoff[m]];
#pragma unroll
        for (int n = 0; n < NF; n++) bfr[n] = *(const bf16x8*)&Bs[boff[n]];
#pragma unroll
        for (int m = 0; m < 4; m++)
#pragma unroll
            for (int n = 0; n < NF; n++)
                acc[m][n] = __builtin_amdgcn_mfma_f32_16x16x32_bf16(af[m], bfr[n], acc[m][n], 0, 0, 0);
        __syncthreads();
    }

#pragma unroll
    for (int n = 0; n < NF; n++) {
        int col = n0 + wc * (BN / 2) + n * 16 + lr;
        bool cok = col < N;
        float bv = (bias && cok) ? bias[col] : 0.f;
#pragma unroll
        for (int m = 0; m < 4; m++) {
#pragma unroll
            for (int r = 0; r < 4; r++) {
                int row = m0 + wr * 64 + m * 16 + lg * 4 + r;
                if (!cok) continue;
                float v = acc[m][n][r] + bv;
                if (EPI == 1) v += resid[(size_t)row * N + col];
                if (EPI == 2) {
                    float x3 = v * v * v;
                    v = 0.5f * v * (1.f + tanhf(0.7978845608028654f * (v + 0.044715f * x3)));
                }
                if (OUTBF)
                    ((hbf16*)Cout)[(size_t)row * N + col] = __float2bfloat16(v);
                else
                    ((float*)Cout)[(size_t)row * N + col] = v;
            }
        }
    }
}

// ---------------- MFMA GEMM 256x128, 512 threads, 2-phase dbuf (lm_head) ----------
__global__ __launch_bounds__(512) void mm2_kernel(const hbf16* __restrict__ A,
                                                  const hbf16* __restrict__ Bt,
                                                  float* __restrict__ Cout,
                                                  int M, int N, int K) {
    __shared__ __bf16 As[2][256 * 32];  // 2 x 16 KB
    __shared__ __bf16 Bs[2][128 * 32];  // 2 x 8 KB
    int tid = threadIdx.x;
    int l = tid & 63, w = tid >> 6;
    int wr = w >> 1, wc = w & 1;

    int gx = gridDim.x, gy = gridDim.y;  // gy = 8
    int nwg = gx * gy;
    int hwlin = blockIdx.y * gx + blockIdx.x;
    int wk = (hwlin & 7) * (nwg >> 3) + (hwlin >> 3);
    int m0 = (wk & 7) * 256;
    int n0 = (wk >> 3) * 128;

    int sr = tid >> 2, sc = tid & 3;
    int scs = (sc ^ (sr & 3)) * 8;
    const hbf16* gA0 = A + (size_t)(m0 + sr) * K + scs;
    const hbf16* gA1 = A + (size_t)(m0 + 128 + sr) * K + scs;
    const hbf16* gB = Bt + (size_t)(n0 + sr) * K + scs;

    auto stage = [&](int bi, int ko) {
        GLD16(gA0 + ko, &As[bi][tid * 8]);
        GLD16(gA1 + ko, &As[bi][4096 + tid * 8]);
        GLD16(gB + ko, &Bs[bi][tid * 8]);
    };

    int lr = l & 15, lg = l >> 4;
    int ksl = (lg ^ (lr & 3)) * 8;
    int aoff[4], boff[4];
#pragma unroll
    for (int m = 0; m < 4; m++) aoff[m] = (wr * 64 + m * 16 + lr) * 32 + ksl;
#pragma unroll
    for (int n = 0; n < 4; n++) boff[n] = (wc * 64 + n * 16 + lr) * 32 + ksl;

    f32x4 acc[4][4] = {};
    int nk = K / 32;

    stage(0, 0);
    __syncthreads();
    for (int t = 0; t < nk; ++t) {
        int cur = t & 1;
        if (t + 1 < nk) stage(cur ^ 1, (t + 1) * 32);
        bf16x8 af[4], bfr[4];
#pragma unroll
        for (int m = 0; m < 4; m++) af[m] = *(const bf16x8*)&As[cur][aoff[m]];
#pragma unroll
        for (int n = 0; n < 4; n++) bfr[n] = *(const bf16x8*)&Bs[cur][boff[n]];
#pragma unroll
        for (int m = 0; m < 4; m++)
#pragma unroll
            for (int n = 0; n < 4; n++)
                acc[m][n] = __builtin_amdgcn_mfma_f32_16x16x32_bf16(af[m], bfr[n], acc[m][n], 0, 0, 0);
        __syncthreads();
    }

#pragma unroll
    for (int n = 0; n < 4; n++) {
        int col = n0 + wc * 64 + n * 16 + lr;
        if (col >= N) continue;
#pragma unroll
        for (int m = 0; m < 4; m++) {
#pragma unroll
            for (int r = 0; r < 4; r++) {
                int row = m0 + wr * 64 + m * 16 + lg * 4 + r;
                Cout[(size_t)row * N + col] = acc[m][n][r];
            }
        }
    }
}

// ---------------- MFMA flash attention, pipelined ----------------
// K double-buffered in LDS via global_load_lds (slot-swizzled source, rule #21).
// V reg-prefetched one tile ahead (T14), double-buffered Vt.
// One raw barrier per tile (lgkmcnt(0) + s_barrier) — no vmcnt(0) drain in loop.
__global__ __launch_bounds__(256) void fattn_kernel(const hbf16* __restrict__ qkv,
                                                    hbf16* __restrict__ y) {
    int qt = gridDim.x - 1 - blockIdx.x;  // heavy tiles first
    int h = blockIdx.y, b = blockIdx.z;
    int q0 = qt * 64;
    int tid = threadIdx.x;
    int l = tid & 63, w = tid >> 6;
    int li = l & 15, lg = l >> 4;
    constexpr int RS = 3 * Dc;
    constexpr int PST = 72;
    constexpr int VST = 72;
    constexpr float SCL = 0.125f * 1.44269504f;  // 1/sqrt(64) * log2(e)
    constexpr float THR = 11.5f;                 // defer-max threshold (log2 domain)

    __shared__ __bf16 K_lds[2][64 * 64];   // 2 x 8 KB, swizzled 16B slots
    __shared__ __bf16 Vt[2][64 * VST];     // 2 x 9 KB
    __shared__ __bf16 P_lds[4][16 * PST];  // 9 KB

    bf16x8 qf[2];
    {
        const hbf16* qp = qkv + (size_t)(b * Tc + q0 + w * 16 + li) * RS + h * HDc + lg * 8;
        qf[0] = *(const bf16x8*)qp;
        qf[1] = *(const bf16x8*)(qp + 32);
    }

    // K staging: 2 issues; chunk id = tid + i*256; row = id>>3, slot s = id&7;
    // global col = (s ^ (row&7))*8 so LDS[row][s] = G[row][s^(row&7)]
    int krow0 = tid >> 3, krow1 = 32 + (tid >> 3);
    int ks8 = tid & 7;
    int kc0 = (ks8 ^ (krow0 & 7)) * 8;
    int kc1 = (ks8 ^ (krow1 & 7)) * 8;
    const hbf16* kbase = qkv + (size_t)(b * Tc) * RS + Dc + h * HDc;

    // V prefetch mapping: thread handles rows (jp, jp+1), d-chunk db..db+7
    int jp = (tid >> 3) * 2;
    int db = (tid & 7) * 8;
    const hbf16* vbase = qkv + (size_t)(b * Tc) * RS + 2 * Dc + h * HDc;

    // K frag read offsets: want G[n*16+li][(ks*4+lg)*8..+8] -> LDS slot (ks*4+lg)^(li&7)
    int koff[2][4];
#pragma unroll
    for (int ks = 0; ks < 2; ks++)
#pragma unroll
        for (int n = 0; n < 4; n++)
            koff[ks][n] = (n * 16 + li) * 64 + (((ks * 4 + lg) ^ (li & 7)) * 8);

    f32x4 acc_o[4] = {};
    float m_run[4], l_run[4];
#pragma unroll
    for (int r = 0; r < 4; r++) { m_run[r] = -1e30f; l_run[r] = 0.f; }

    // ---- prologue: load V(0) regs (oldest), issue K(0) GLD, write V(0) -> Vt[0] ----
    bf16x8 vr0, vr1;
    {
        const hbf16* vp = vbase + (size_t)jp * RS + db;
        vr0 = *(const bf16x8*)vp;
        vr1 = *(const bf16x8*)(vp + RS);
        GLD16(kbase + (size_t)krow0 * RS + kc0, &K_lds[0][tid * 8]);
        GLD16(kbase + (size_t)krow1 * RS + kc1, &K_lds[0][2048 + tid * 8]);
    }
#pragma unroll
    for (int i = 0; i < 8; i++) {  // compiler inserts vmcnt wait for vr use (K keeps flying)
        __bf16 a0 = vr0[i], a1 = vr1[i];
        unsigned u = (unsigned)*(unsigned short*)&a0 | ((unsigned)*(unsigned short*)&a1 << 16);
        *(unsigned*)&Vt[0][(db + i) * VST + jp] = u;
    }

    int cur = 0;
    for (int jt = 0; jt <= qt; jt++) {
        int j0 = jt * 64;
        int jn0 = (jt < qt) ? (jt + 1) * 64 : 0;  // dummy wrap keeps vmcnt invariant

        // barrier: Vt[cur] (written last tile) + K_lds visible; prior PV reads done
        asm volatile("s_waitcnt lgkmcnt(0)" ::: "memory");
        __builtin_amdgcn_s_barrier();

        // issue next-tile V regs (older) then K GLD (younger)
        {
            const hbf16* vp = vbase + (size_t)(jn0 + jp) * RS + db;
            vr0 = *(const bf16x8*)vp;
            vr1 = *(const bf16x8*)(vp + RS);
            GLD16(kbase + (size_t)(jn0 + krow0) * RS + kc0, &K_lds[cur ^ 1][tid * 8]);
            GLD16(kbase + (size_t)(jn0 + krow1) * RS + kc1, &K_lds[cur ^ 1][2048 + tid * 8]);
        }

        // wait K(jt) landed (leaves V(jt+1)+K(jt+1) = 4 in flight)
        asm volatile("s_waitcnt vmcnt(4)" ::: "memory");
        __builtin_amdgcn_sched_barrier(0);

        // ---- S = Q K^T from K_lds[cur] ----
        f32x4 s[4] = {};
#pragma unroll
        for (int ks = 0; ks < 2; ks++)
#pragma unroll
            for (int n = 0; n < 4; n++) {
                bf16x8 kf = *(const bf16x8*)&K_lds[cur][koff[ks][n]];
                s[n] = __builtin_amdgcn_mfma_f32_16x16x32_bf16(qf[ks], kf, s[n], 0, 0, 0);
            }
#pragma unroll
        for (int n = 0; n < 4; n++)
#pragma unroll
            for (int r = 0; r < 4; r++) s[n][r] *= SCL;

        if (jt == qt) {  // diagonal: mask j > q
            int qloc = w * 16 + lg * 4;
#pragma unroll
            for (int n = 0; n < 4; n++) {
                int jloc = n * 16 + li;
#pragma unroll
                for (int r = 0; r < 4; r++)
                    if (jloc > qloc + r) s[n][r] = -1e30f;
            }
        }

        // ---- online softmax (log2 domain), defer-max ----
        float mx4[4];
#pragma unroll
        for (int r = 0; r < 4; r++) {
            float mx = fmaxf(fmaxf(s[0][r], s[1][r]), fmaxf(s[2][r], s[3][r]));
#pragma unroll
            for (int msk = 1; msk <= 8; msk <<= 1) mx = fmaxf(mx, __shfl_xor(mx, msk, 64));
            mx4[r] = mx;
        }
        bool dfr = (mx4[0] - m_run[0] <= THR) && (mx4[1] - m_run[1] <= THR) &&
                   (mx4[2] - m_run[2] <= THR) && (mx4[3] - m_run[3] <= THR);
        dfr = __all(dfr);
        float scl[4] = {1.f, 1.f, 1.f, 1.f};
        if (!dfr) {
#pragma unroll
            for (int r = 0; r < 4; r++) {
                float mnew = fmaxf(m_run[r], mx4[r]);
                scl[r] = exp2f(m_run[r] - mnew);
                m_run[r] = mnew;
            }
        }
        float rs[4] = {0.f, 0.f, 0.f, 0.f};
#pragma unroll
        for (int n = 0; n < 4; n++)
#pragma unroll
            for (int r = 0; r < 4; r++) {
                float p = exp2f(s[n][r] - m_run[r]);
                s[n][r] = p;
                rs[r] += p;
            }
#pragma unroll
        for (int r = 0; r < 4; r++) {
#pragma unroll
            for (int msk = 1; msk <= 8; msk <<= 1) rs[r] += __shfl_xor(rs[r], msk, 64);
            l_run[r] = (dfr ? l_run[r] : l_run[r] * scl[r]) + rs[r];
        }

        // ---- P -> LDS (bf16), re-read as A-frags (wave-local, no barrier) ----
#pragma unroll
        for (int n = 0; n < 4; n++)
#pragma unroll
            for (int r = 0; r < 4; r++) {
                hbf16 t = __float2bfloat16(s[n][r]);
                P_lds[w][(lg * 4 + r) * PST + n * 16 + li] = *(__bf16*)&t;
            }
        bf16x8 pa0 = *(const bf16x8*)&P_lds[w][li * PST + lg * 8];
        bf16x8 pa1 = *(const bf16x8*)&P_lds[w][li * PST + 32 + lg * 8];

        if (!dfr) {
#pragma unroll
            for (int n2 = 0; n2 < 4; n2++)
#pragma unroll
                for (int r = 0; r < 4; r++) acc_o[n2][r] *= scl[r];
        }

        // ---- PV from Vt[cur] (written last tile, synced by this tile's barrier) ----
#pragma unroll
        for (int n2 = 0; n2 < 4; n2++) {
            bf16x8 vf0 = *(const bf16x8*)&Vt[cur][(n2 * 16 + li) * VST + lg * 8];
            bf16x8 vf1 = *(const bf16x8*)&Vt[cur][(n2 * 16 + li) * VST + 32 + lg * 8];
            acc_o[n2] = __builtin_amdgcn_mfma_f32_16x16x32_bf16(pa0, vf0, acc_o[n2], 0, 0, 0);
            acc_o[n2] = __builtin_amdgcn_mfma_f32_16x16x32_bf16(pa1, vf1, acc_o[n2], 0, 0, 0);
        }

        // ---- write V(jt+1) regs -> Vt[cur^1] (other buffer; visible after next barrier)
#pragma unroll
        for (int i = 0; i < 8; i++) {
            __bf16 a0 = vr0[i], a1 = vr1[i];
            unsigned u = (unsigned)*(unsigned short*)&a0 | ((unsigned)*(unsigned short*)&a1 << 16);
            *(unsigned*)&Vt[cur ^ 1][(db + i) * VST + jp] = u;
        }
        cur ^= 1;
    }

#pragma unroll
    for (int r = 0; r < 4; r++) {
        float rcp = 1.f / l_run[r];
        int row = q0 + w * 16 + lg * 4 + r;
#pragma unroll
        for (int n2 = 0; n2 < 4; n2++)
            y[(size_t)(b * Tc + row) * Dc + h * HDc + n2 * 16 + li] =
                __float2bfloat16(acc_o[n2][r] * rcp);
    }
}

extern "C" void kernel_launch(void* const* d_in, const int* in_sizes, int n_in,
                              void* d_out, int out_size, void* d_ws, size_t ws_size,
                              hipStream_t stream) {
    const int* x = (const int*)d_in[0];
    const float* wte = (const float*)d_in[1];
    const float* wpe = (const float*)d_in[2];
    const float* ln1w = (const float*)d_in[3];
    const float* ln1b = (const float*)d_in[4];
    const float* qkvw = (const float*)d_in[5];
    const float* qkvb = (const float*)d_in[6];
    const float* projw = (const float*)d_in[7];
    const float* projb = (const float*)d_in[8];
    const float* ln2w = (const float*)d_in[9];
    const float* ln2b = (const float*)d_in[10];
    const float* fcw = (const float*)d_in[11];
    const float* fcb = (const float*)d_in[12];
    const float* fcpw = (const float*)d_in[13];
    const float* fcpb = (const float*)d_in[14];
    const float* lnfw = (const float*)d_in[15];
    const float* lnfb = (const float*)d_in[16];

    char* p = (char*)d_ws;
    float* h = (float*)p;     p += (size_t)Mc * Dc * 4;      // f32 [M][D]
    hbf16* qkv = (hbf16*)p;   p += (size_t)Mc * 3 * Dc * 2;  // bf16 [M][3D]
    hbf16* a = (hbf16*)p;     p += (size_t)Mc * Dc * 2;      // bf16 [M][D]
    hbf16* y = (hbf16*)p;     p += (size_t)Mc * Dc * 2;      // bf16 [M][D]
    hbf16* mlp = (hbf16*)p;   p += (size_t)Mc * 4 * Dc * 2;  // bf16 [M][4D]
    hbf16* wte_b = (hbf16*)p; p += (size_t)Vpad * Dc * 2;    // [50304][768]
    hbf16* wtr = (hbf16*)p;                                  // transposed weights
    size_t used = (size_t)((char*)wtr - (char*)d_ws);
    bool all_mode = (ws_size - used) >= (size_t)Lc * SZL * 2;

    embed_kernel<<<(Mc * Dc + 255) / 256, 256, 0, stream>>>(x, wte, wpe, h);
    convert_wte<<<((size_t)Vpad * Dc / 4 + 255) / 256, 256, 0, stream>>>(wte, wte_b);

    if (all_mode) {
        transpose4_kernel<<<dim3(6912, Lc), 256, 0, stream>>>(
            qkvw, projw, fcw, fcpw,
            wtr, wtr + SZ_Q, wtr + SZ_Q + SZ_P, wtr + SZ_Q + SZ_P + SZ_F);
    }

    for (int l = 0; l < Lc; l++) {
        hbf16* base = wtr + (all_mode ? (size_t)l * SZL : 0);
        hbf16* wq_t = base;
        hbf16* wp_t = base + SZ_Q;
        hbf16* wf_t = base + SZ_Q + SZ_P;
        hbf16* wfp_t = base + SZ_Q + SZ_P + SZ_F;
        if (!all_mode) {
            transpose4_kernel<<<dim3(6912, 1), 256, 0, stream>>>(
                qkvw + (size_t)l * SZ_Q, projw + (size_t)l * SZ_P,
                fcw + (size_t)l * SZ_F, fcpw + (size_t)l * SZ_FP,
                wq_t, wp_t, wf_t, wfp_t);
        }

        ln_kernel<<<Mc / 4, 256, 0, stream>>>(h, ln1w + (size_t)l * Dc, ln1b + (size_t)l * Dc, a);
        mm_kernel<0, true, 128><<<dim3(3 * Dc / 128, Mc / 128), 256, 0, stream>>>(
            a, wq_t, qkvb + (size_t)l * 3 * Dc, nullptr, qkv, Mc, 3 * Dc, Dc);
        fattn_kernel<<<dim3(Tc / 64, Hc, Bc), 256, 0, stream>>>(qkv, y);
        mm_kernel<1, false, 64><<<dim3(Dc / 64, Mc / 128), 256, 0, stream>>>(
            y, wp_t, projb + (size_t)l * Dc, h, h, Mc, Dc, Dc);
        ln_kernel<<<Mc / 4, 256, 0, stream>>>(h, ln2w + (size_t)l * Dc, ln2b + (size_t)l * Dc, a);
        mm_kernel<2, true, 128><<<dim3(4 * Dc / 128, Mc / 128), 256, 0, stream>>>(
            a, wf_t, fcb + (size_t)l * 4 * Dc, nullptr, mlp, Mc, 4 * Dc, Dc);
        mm_kernel<1, false, 64><<<dim3(Dc / 64, Mc / 128), 256, 0, stream>>>(
            mlp, wfp_t, fcpb + (size_t)l * Dc, h, h, Mc, Dc, 4 * Dc);
    }

    ln_kernel<<<Mc / 4, 256, 0, stream>>>(h, lnfw, lnfb, a);
    mm2_kernel<<<dim3(Vpad / 128, Mc / 256), 512, 0, stream>>>(
        a, wte_b, (float*)d_out, Mc, Vc, Dc);
}

// Round 12
// 2578.768 us; speedup vs baseline: 1.0920x; 1.0546x over previous
//
#include <hip/hip_runtime.h>
#include <hip/hip_bf16.h>

typedef __hip_bfloat16 hbf16;
using bf16x8 = __attribute__((ext_vector_type(8))) __bf16;
using f32x4 = __attribute__((ext_vector_type(4))) float;

// GPT-2 small: L=12 H=12 D=768 V=50257 T=1024 B=2, HD=64
constexpr int Lc = 12, Hc = 12, Dc = 768, Vc = 50257, Tc = 1024, Bc = 2, HDc = 64;
constexpr int Mc = Bc * Tc;  // 2048 rows
constexpr int Vpad = 50304;  // 393*128, zero-padded vocab

// transposed-weight slot sizes (elements)
constexpr size_t SZ_Q = (size_t)3 * Dc * Dc;   // [2304][768]
constexpr size_t SZ_P = (size_t)Dc * Dc;       // [768][768]
constexpr size_t SZ_F = (size_t)4 * Dc * Dc;   // [3072][768]
constexpr size_t SZ_FP = (size_t)4 * Dc * Dc;  // [768][3072]
constexpr size_t SZL = SZ_Q + SZ_P + SZ_F + SZ_FP;

#define GLD16(gp, lp)                                               \
    __builtin_amdgcn_global_load_lds(                               \
        (__attribute__((address_space(1))) void*)(void*)(gp),       \
        (__attribute__((address_space(3))) void*)(void*)(lp), 16, 0, 0)

// ---------------- embedding: h = wte[x] + wpe[t] (f32) ----------------
__global__ void embed_kernel(const int* __restrict__ x, const float* __restrict__ wte,
                             const float* __restrict__ wpe, float* __restrict__ h) {
    int i = blockIdx.x * blockDim.x + threadIdx.x;
    if (i >= Mc * Dc) return;
    int m = i / Dc, d = i - m * Dc;
    int t = m % Tc;
    int tok = x[m];
    h[i] = wte[(size_t)tok * Dc + d] + wpe[(size_t)t * Dc + d];
}

// ---------------- layernorm: one wave per row, shuffle reduce, f32 in -> bf16 out --
__global__ __launch_bounds__(256) void ln_kernel(const float* __restrict__ x,
                                                 const float* __restrict__ w,
                                                 const float* __restrict__ b,
                                                 hbf16* __restrict__ out) {
    int wv = threadIdx.x >> 6, lane = threadIdx.x & 63;
    int row = blockIdx.x * 4 + wv;
    const float4* xr = (const float4*)(x + (size_t)row * Dc);
    float4 v[3];
    float s = 0.f, sq = 0.f;
#pragma unroll
    for (int i = 0; i < 3; i++) {
        v[i] = xr[i * 64 + lane];
        s += v[i].x + v[i].y + v[i].z + v[i].w;
        sq += v[i].x * v[i].x + v[i].y * v[i].y + v[i].z * v[i].z + v[i].w * v[i].w;
    }
#pragma unroll
    for (int o = 32; o > 0; o >>= 1) {
        s += __shfl_xor(s, o, 64);
        sq += __shfl_xor(sq, o, 64);
    }
    float mean = s * (1.f / Dc);
    float var = sq * (1.f / Dc) - mean * mean;
    float rstd = rsqrtf(var + 1e-5f);
#pragma unroll
    for (int i = 0; i < 3; i++) {
        int c = (i * 64 + lane) * 4;
        float4 wv4 = *(const float4*)(w + c);
        float4 bv4 = *(const float4*)(b + c);
        float r0 = (v[i].x - mean) * rstd * wv4.x + bv4.x;
        float r1 = (v[i].y - mean) * rstd * wv4.y + bv4.y;
        float r2 = (v[i].z - mean) * rstd * wv4.z + bv4.z;
        float r3 = (v[i].w - mean) * rstd * wv4.w + bv4.w;
        __bf16 q0 = (__bf16)r0, q1 = (__bf16)r1, q2 = (__bf16)r2, q3 = (__bf16)r3;
        ushort4 u;
        u.x = *(unsigned short*)&q0; u.y = *(unsigned short*)&q1;
        u.z = *(unsigned short*)&q2; u.w = *(unsigned short*)&q3;
        *(ushort4*)(out + (size_t)row * Dc + c) = u;
    }
}

// ---------------- weight transpose, grid (6912, nlayers) ----------------
__global__ __launch_bounds__(256) void transpose4_kernel(
    const float* __restrict__ s0, const float* __restrict__ s1,
    const float* __restrict__ s2, const float* __restrict__ s3,
    hbf16* __restrict__ d0, hbf16* __restrict__ d1,
    hbf16* __restrict__ d2, hbf16* __restrict__ d3) {
    int id = blockIdx.x;
    size_t lz = blockIdx.y;
    int bx, by, K, N;
    const float* W;
    hbf16* Wt;
    if (id < 1728)      { int t = id;        bx = t % 72; by = t / 72; K = 768;  N = 2304; W = s0 + lz * SZ_Q;  Wt = d0 + lz * SZL; }
    else if (id < 2304) { int t = id - 1728; bx = t % 24; by = t / 24; K = 768;  N = 768;  W = s1 + lz * SZ_P;  Wt = d1 + lz * SZL; }
    else if (id < 4608) { int t = id - 2304; bx = t % 96; by = t / 96; K = 768;  N = 3072; W = s2 + lz * SZ_F;  Wt = d2 + lz * SZL; }
    else                { int t = id - 4608; bx = t % 24; by = t / 24; K = 3072; N = 768;  W = s3 + lz * SZ_FP; Wt = d3 + lz * SZL; }

    __shared__ float tile[32][33];
    int n0 = bx * 32, k0 = by * 32;
    int tx = threadIdx.x & 31, ty = threadIdx.x >> 5;  // 32x8
#pragma unroll
    for (int i = 0; i < 4; i++) {
        int r = ty + i * 8;
        tile[r][tx] = W[(size_t)(k0 + r) * N + n0 + tx];
    }
    __syncthreads();
#pragma unroll
    for (int i = 0; i < 4; i++) {
        int r = ty + i * 8;
        Wt[(size_t)(n0 + r) * K + k0 + tx] = __float2bfloat16(tile[tx][r]);
    }
}

// ---------------- wte f32 [V][D] -> bf16 [Vpad][D] (zero pad) ----------------
__global__ void convert_wte(const float* __restrict__ wte, hbf16* __restrict__ out) {
    size_t i4 = ((size_t)blockIdx.x * 256 + threadIdx.x) * 4;
    if (i4 >= (size_t)Vpad * Dc) return;
    if (i4 < (size_t)Vc * Dc) {
#pragma unroll
        for (int j = 0; j < 4; j++) out[i4 + j] = __float2bfloat16(wte[i4 + j]);
    } else {
#pragma unroll
        for (int j = 0; j < 4; j++) out[i4 + j] = __float2bfloat16(0.f);
    }
}

// ---------------- MFMA GEMM 128xBN, single-buffer (R7 config): C = A@Bt^T + epi ---
// EPI: 0 = +bias, 1 = +bias +f32 residual, 2 = +bias + tanh-GELU
template <int EPI, bool OUTBF, int BN>
__global__ __launch_bounds__(256) void mm_kernel(const hbf16* __restrict__ A,
                                                 const hbf16* __restrict__ Bt,
                                                 const float* __restrict__ bias,
                                                 const float* __restrict__ resid,
                                                 void* __restrict__ Cout,
                                                 int M, int N, int K) {
    constexpr int NF = BN / 32;  // n-frags per wave
    __shared__ __bf16 As[128 * 32];
    __shared__ __bf16 Bs[BN * 32];
    int tid = threadIdx.x;
    int l = tid & 63, w = tid >> 6;
    int wr = w >> 1, wc = w & 1;

    int gx = gridDim.x, gy = gridDim.y;
    int nwg = gx * gy;
    int hwlin = blockIdx.y * gx + blockIdx.x;
    int wk = (hwlin & 7) * (nwg >> 3) + (hwlin >> 3);
    int m0 = (wk % gy) * 128;
    int n0 = (wk / gy) * BN;

    int sr = tid >> 2, sc = tid & 3;
    int scs = (sc ^ (sr & 3)) * 8;
    const hbf16* pA0 = A + (size_t)(m0 + sr) * K + scs;
    const hbf16* pA1 = A + (size_t)(m0 + 64 + sr) * K + scs;
    const hbf16* pB0 = Bt + (size_t)(n0 + sr) * K + scs;
    const hbf16* pB1 = (BN == 128) ? Bt + (size_t)(n0 + 64 + sr) * K + scs : pB0;
    __bf16* lA0 = As + tid * 8;
    __bf16* lA1 = As + 2048 + tid * 8;
    __bf16* lB0 = Bs + tid * 8;
    __bf16* lB1 = Bs + 2048 + tid * 8;

    int lr = l & 15, lg = l >> 4;
    int ksl = (lg ^ (lr & 3)) * 8;
    int aoff[4], boff[NF];
#pragma unroll
    for (int m = 0; m < 4; m++) aoff[m] = (wr * 64 + m * 16 + lr) * 32 + ksl;
#pragma unroll
    for (int n = 0; n < NF; n++) boff[n] = (wc * (BN / 2) + n * 16 + lr) * 32 + ksl;

    f32x4 acc[4][NF] = {};

    for (int k0 = 0; k0 < K; k0 += 32) {
        GLD16(pA0, lA0);
        GLD16(pA1, lA1);
        GLD16(pB0, lB0);
        if constexpr (BN == 128) GLD16(pB1, lB1);
        pA0 += 32; pA1 += 32; pB0 += 32;
        if constexpr (BN == 128) pB1 += 32;
        __syncthreads();
        bf16x8 af[4], bfr[NF];
#pragma unroll
        for (int m = 0; m < 4; m++) af[m] = *(const bf16x8*)&As[aoff[m]];
#pragma unroll
        for (int n = 0; n < NF; n++) bfr[n] = *(const bf16x8*)&Bs[boff[n]];
#pragma unroll
        for (int m = 0; m < 4; m++)
#pragma unroll
            for (int n = 0; n < NF; n++)
                acc[m][n] = __builtin_amdgcn_mfma_f32_16x16x32_bf16(af[m], bfr[n], acc[m][n], 0, 0, 0);
        __syncthreads();
    }

#pragma unroll
    for (int n = 0; n < NF; n++) {
        int col = n0 + wc * (BN / 2) + n * 16 + lr;
        bool cok = col < N;
        float bv = (bias && cok) ? bias[col] : 0.f;
#pragma unroll
        for (int m = 0; m < 4; m++) {
#pragma unroll
            for (int r = 0; r < 4; r++) {
                int row = m0 + wr * 64 + m * 16 + lg * 4 + r;
                if (!cok) continue;
                float v = acc[m][n][r] + bv;
                if (EPI == 1) v += resid[(size_t)row * N + col];
                if (EPI == 2) {
                    float x3 = v * v * v;
                    v = 0.5f * v * (1.f + tanhf(0.7978845608028654f * (v + 0.044715f * x3)));
                }
                if (OUTBF)
                    ((hbf16*)Cout)[(size_t)row * N + col] = __float2bfloat16(v);
                else
                    ((float*)Cout)[(size_t)row * N + col] = v;
            }
        }
    }
}

// ---------------- MFMA GEMM 256x128, 512 threads, 2-phase dbuf (lm_head) ----------
__global__ __launch_bounds__(512) void mm2_kernel(const hbf16* __restrict__ A,
                                                  const hbf16* __restrict__ Bt,
                                                  float* __restrict__ Cout,
                                                  int M, int N, int K) {
    __shared__ __bf16 As[2][256 * 32];  // 2 x 16 KB
    __shared__ __bf16 Bs[2][128 * 32];  // 2 x 8 KB
    int tid = threadIdx.x;
    int l = tid & 63, w = tid >> 6;
    int wr = w >> 1, wc = w & 1;

    int gx = gridDim.x, gy = gridDim.y;  // gy = 8
    int nwg = gx * gy;
    int hwlin = blockIdx.y * gx + blockIdx.x;
    int wk = (hwlin & 7) * (nwg >> 3) + (hwlin >> 3);
    int m0 = (wk & 7) * 256;
    int n0 = (wk >> 3) * 128;

    int sr = tid >> 2, sc = tid & 3;
    int scs = (sc ^ (sr & 3)) * 8;
    const hbf16* gA0 = A + (size_t)(m0 + sr) * K + scs;
    const hbf16* gA1 = A + (size_t)(m0 + 128 + sr) * K + scs;
    const hbf16* gB = Bt + (size_t)(n0 + sr) * K + scs;

    auto stage = [&](int bi, int ko) {
        GLD16(gA0 + ko, &As[bi][tid * 8]);
        GLD16(gA1 + ko, &As[bi][4096 + tid * 8]);
        GLD16(gB + ko, &Bs[bi][tid * 8]);
    };

    int lr = l & 15, lg = l >> 4;
    int ksl = (lg ^ (lr & 3)) * 8;
    int aoff[4], boff[4];
#pragma unroll
    for (int m = 0; m < 4; m++) aoff[m] = (wr * 64 + m * 16 + lr) * 32 + ksl;
#pragma unroll
    for (int n = 0; n < 4; n++) boff[n] = (wc * 64 + n * 16 + lr) * 32 + ksl;

    f32x4 acc[4][4] = {};
    int nk = K / 32;

    stage(0, 0);
    __syncthreads();
    for (int t = 0; t < nk; ++t) {
        int cur = t & 1;
        if (t + 1 < nk) stage(cur ^ 1, (t + 1) * 32);
        bf16x8 af[4], bfr[4];
#pragma unroll
        for (int m = 0; m < 4; m++) af[m] = *(const bf16x8*)&As[cur][aoff[m]];
#pragma unroll
        for (int n = 0; n < 4; n++) bfr[n] = *(const bf16x8*)&Bs[cur][boff[n]];
#pragma unroll
        for (int m = 0; m < 4; m++)
#pragma unroll
            for (int n = 0; n < 4; n++)
                acc[m][n] = __builtin_amdgcn_mfma_f32_16x16x32_bf16(af[m], bfr[n], acc[m][n], 0, 0, 0);
        __syncthreads();
    }

#pragma unroll
    for (int n = 0; n < 4; n++) {
        int col = n0 + wc * 64 + n * 16 + lr;
        if (col >= N) continue;
#pragma unroll
        for (int m = 0; m < 4; m++) {
#pragma unroll
            for (int r = 0; r < 4; r++) {
                int row = m0 + wr * 64 + m * 16 + lg * 4 + r;
                Cout[(size_t)row * N + col] = acc[m][n][r];
            }
        }
    }
}

// ---------------- MFMA flash attention, pipelined + swapped QK^T ----------------
// QK^T computed as mfma(K, Q): lane li owns q-row w*16+li's scores (16 regs).
// Softmax: in-lane reduce + 2 shuffles (vs 32). m/l are scalars. PV unchanged.
__global__ __launch_bounds__(256) void fattn_kernel(const hbf16* __restrict__ qkv,
                                                    hbf16* __restrict__ y) {
    int qt = gridDim.x - 1 - blockIdx.x;  // heavy tiles first
    int h = blockIdx.y, b = blockIdx.z;
    int q0 = qt * 64;
    int tid = threadIdx.x;
    int l = tid & 63, w = tid >> 6;
    int li = l & 15, lg = l >> 4;
    constexpr int RS = 3 * Dc;
    constexpr int PST = 72;
    constexpr int VST = 72;
    constexpr float SCL = 0.125f * 1.44269504f;  // 1/sqrt(64) * log2(e)
    constexpr float THR = 11.5f;                 // defer-max threshold (log2 domain)

    __shared__ __bf16 K_lds[2][64 * 64];   // 2 x 8 KB, swizzled 16B slots
    __shared__ __bf16 Vt[2][64 * VST];     // 2 x 9 KB
    __shared__ __bf16 P_lds[4][16 * PST];  // 9 KB  (layout [q_local][j])

    bf16x8 qf[2];
    {
        const hbf16* qp = qkv + (size_t)(b * Tc + q0 + w * 16 + li) * RS + h * HDc + lg * 8;
        qf[0] = *(const bf16x8*)qp;
        qf[1] = *(const bf16x8*)(qp + 32);
    }

    // K staging: 2 issues; row = id>>3, slot s = id&7; global col = (s^(row&7))*8
    int krow0 = tid >> 3, krow1 = 32 + (tid >> 3);
    int ks8 = tid & 7;
    int kc0 = (ks8 ^ (krow0 & 7)) * 8;
    int kc1 = (ks8 ^ (krow1 & 7)) * 8;
    const hbf16* kbase = qkv + (size_t)(b * Tc) * RS + Dc + h * HDc;

    // V prefetch mapping: thread handles rows (jp, jp+1), d-chunk db..db+7
    int jp = (tid >> 3) * 2;
    int db = (tid & 7) * 8;
    const hbf16* vbase = qkv + (size_t)(b * Tc) * RS + 2 * Dc + h * HDc;

    // K frag read offsets (A-operand): K[n*16+li][(ks*4+lg)*8..+8], slot^(li&7)
    int koff[2][4];
#pragma unroll
    for (int ks = 0; ks < 2; ks++)
#pragma unroll
        for (int n = 0; n < 4; n++)
            koff[ks][n] = (n * 16 + li) * 64 + (((ks * 4 + lg) ^ (li & 7)) * 8);

    f32x4 acc_o[4] = {};
    float m_run = -1e30f, l_run = 0.f;  // scalar: lane owns q = w*16+li

    // ---- prologue: load V(0) regs (oldest), issue K(0) GLD, write V(0) -> Vt[0] ----
    bf16x8 vr0, vr1;
    {
        const hbf16* vp = vbase + (size_t)jp * RS + db;
        vr0 = *(const bf16x8*)vp;
        vr1 = *(const bf16x8*)(vp + RS);
        GLD16(kbase + (size_t)krow0 * RS + kc0, &K_lds[0][tid * 8]);
        GLD16(kbase + (size_t)krow1 * RS + kc1, &K_lds[0][2048 + tid * 8]);
    }
#pragma unroll
    for (int i = 0; i < 8; i++) {  // vmcnt wait for vr only (K keeps flying)
        __bf16 a0 = vr0[i], a1 = vr1[i];
        unsigned u = (unsigned)*(unsigned short*)&a0 | ((unsigned)*(unsigned short*)&a1 << 16);
        *(unsigned*)&Vt[0][(db + i) * VST + jp] = u;
    }

    int cur = 0;
    for (int jt = 0; jt <= qt; jt++) {
        int jn0 = (jt < qt) ? (jt + 1) * 64 : 0;  // dummy wrap keeps vmcnt invariant

        asm volatile("s_waitcnt lgkmcnt(0)" ::: "memory");
        __builtin_amdgcn_s_barrier();

        // issue next-tile V regs (older) then K GLD (younger)
        {
            const hbf16* vp = vbase + (size_t)(jn0 + jp) * RS + db;
            vr0 = *(const bf16x8*)vp;
            vr1 = *(const bf16x8*)(vp + RS);
            GLD16(kbase + (size_t)(jn0 + krow0) * RS + kc0, &K_lds[cur ^ 1][tid * 8]);
            GLD16(kbase + (size_t)(jn0 + krow1) * RS + kc1, &K_lds[cur ^ 1][2048 + tid * 8]);
        }

        asm volatile("s_waitcnt vmcnt(4)" ::: "memory");
        __builtin_amdgcn_sched_barrier(0);

        // ---- S = K Q^T (swapped): s[n][r] = S[j=n*16+lg*4+r][q=li] ----
        f32x4 s[4] = {};
#pragma unroll
        for (int ks = 0; ks < 2; ks++)
#pragma unroll
            for (int n = 0; n < 4; n++) {
                bf16x8 kf = *(const bf16x8*)&K_lds[cur][koff[ks][n]];
                s[n] = __builtin_amdgcn_mfma_f32_16x16x32_bf16(kf, qf[ks], s[n], 0, 0, 0);
            }
#pragma unroll
        for (int n = 0; n < 4; n++)
#pragma unroll
            for (int r = 0; r < 4; r++) s[n][r] *= SCL;

        if (jt == qt) {  // diagonal: mask j > q (block-local, shared origin)
            int qloc = w * 16 + li;
#pragma unroll
            for (int n = 0; n < 4; n++)
#pragma unroll
                for (int r = 0; r < 4; r++)
                    if (n * 16 + lg * 4 + r > qloc) s[n][r] = -1e30f;
        }

        // ---- online softmax: all 16 values belong to q = w*16+li ----
        float mx = -1e30f;
#pragma unroll
        for (int n = 0; n < 4; n++)
#pragma unroll
            for (int r = 0; r < 4; r++) mx = fmaxf(mx, s[n][r]);
        mx = fmaxf(mx, __shfl_xor(mx, 16, 64));
        mx = fmaxf(mx, __shfl_xor(mx, 32, 64));

        bool dfr = __all(mx - m_run <= THR);
        float sclq = 1.f;
        if (!dfr) {
            float mnew = fmaxf(m_run, mx);
            sclq = exp2f(m_run - mnew);
            m_run = mnew;
        }
        float rs = 0.f;
#pragma unroll
        for (int n = 0; n < 4; n++)
#pragma unroll
            for (int r = 0; r < 4; r++) {
                float pv = exp2f(s[n][r] - m_run);
                s[n][r] = pv;
                rs += pv;
            }
        rs += __shfl_xor(rs, 16, 64);
        rs += __shfl_xor(rs, 32, 64);
        l_run = (dfr ? l_run : l_run * sclq) + rs;

        // ---- P -> LDS [q=li][j], packed pairs (j contiguous in-lane) ----
#pragma unroll
        for (int n = 0; n < 4; n++)
#pragma unroll
            for (int r = 0; r < 4; r += 2) {
                __bf16 b0 = (__bf16)s[n][r], b1 = (__bf16)s[n][r + 1];
                unsigned u = (unsigned)*(unsigned short*)&b0 |
                             ((unsigned)*(unsigned short*)&b1 << 16);
                *(unsigned*)&P_lds[w][li * PST + n * 16 + lg * 4 + r] = u;
            }
        bf16x8 pa0 = *(const bf16x8*)&P_lds[w][li * PST + lg * 8];
        bf16x8 pa1 = *(const bf16x8*)&P_lds[w][li * PST + 32 + lg * 8];

        if (!dfr) {  // rescale O: factor lives at lane li == lg*4+r
#pragma unroll
            for (int r = 0; r < 4; r++) {
                float sr_ = __shfl(sclq, (l & 48) | (lg * 4 + r), 64);
#pragma unroll
                for (int n2 = 0; n2 < 4; n2++) acc_o[n2][r] *= sr_;
            }
        }

        // ---- PV from Vt[cur] ----
#pragma unroll
        for (int n2 = 0; n2 < 4; n2++) {
            bf16x8 vf0 = *(const bf16x8*)&Vt[cur][(n2 * 16 + li) * VST + lg * 8];
            bf16x8 vf1 = *(const bf16x8*)&Vt[cur][(n2 * 16 + li) * VST + 32 + lg * 8];
            acc_o[n2] = __builtin_amdgcn_mfma_f32_16x16x32_bf16(pa0, vf0, acc_o[n2], 0, 0, 0);
            acc_o[n2] = __builtin_amdgcn_mfma_f32_16x16x32_bf16(pa1, vf1, acc_o[n2], 0, 0, 0);
        }

        // ---- write V(jt+1) regs -> Vt[cur^1] ----
#pragma unroll
        for (int i = 0; i < 8; i++) {
            __bf16 a0 = vr0[i], a1 = vr1[i];
            unsigned u = (unsigned)*(unsigned short*)&a0 | ((unsigned)*(unsigned short*)&a1 << 16);
            *(unsigned*)&Vt[cur ^ 1][(db + i) * VST + jp] = u;
        }
        cur ^= 1;
    }

#pragma unroll
    for (int r = 0; r < 4; r++) {
        float lv = __shfl(l_run, (l & 48) | (lg * 4 + r), 64);
        float rcp = 1.f / lv;
        int row = q0 + w * 16 + lg * 4 + r;
#pragma unroll
        for (int n2 = 0; n2 < 4; n2++)
            y[(size_t)(b * Tc + row) * Dc + h * HDc + n2 * 16 + li] =
                __float2bfloat16(acc_o[n2][r] * rcp);
    }
}

extern "C" void kernel_launch(void* const* d_in, const int* in_sizes, int n_in,
                              void* d_out, int out_size, void* d_ws, size_t ws_size,
                              hipStream_t stream) {
    const int* x = (const int*)d_in[0];
    const float* wte = (const float*)d_in[1];
    const float* wpe = (const float*)d_in[2];
    const float* ln1w = (const float*)d_in[3];
    const float* ln1b = (const float*)d_in[4];
    const float* qkvw = (const float*)d_in[5];
    const float* qkvb = (const float*)d_in[6];
    const float* projw = (const float*)d_in[7];
    const float* projb = (const float*)d_in[8];
    const float* ln2w = (const float*)d_in[9];
    const float* ln2b = (const float*)d_in[10];
    const float* fcw = (const float*)d_in[11];
    const float* fcb = (const float*)d_in[12];
    const float* fcpw = (const float*)d_in[13];
    const float* fcpb = (const float*)d_in[14];
    const float* lnfw = (const float*)d_in[15];
    const float* lnfb = (const float*)d_in[16];

    char* p = (char*)d_ws;
    float* h = (float*)p;     p += (size_t)Mc * Dc * 4;      // f32 [M][D]
    hbf16* qkv = (hbf16*)p;   p += (size_t)Mc * 3 * Dc * 2;  // bf16 [M][3D]
    hbf16* a = (hbf16*)p;     p += (size_t)Mc * Dc * 2;      // bf16 [M][D]
    hbf16* y = (hbf16*)p;     p += (size_t)Mc * Dc * 2;      // bf16 [M][D]
    hbf16* mlp = (hbf16*)p;   p += (size_t)Mc * 4 * Dc * 2;  // bf16 [M][4D]
    hbf16* wte_b = (hbf16*)p; p += (size_t)Vpad * Dc * 2;    // [50304][768]
    hbf16* wtr = (hbf16*)p;                                  // transposed weights
    size_t used = (size_t)((char*)wtr - (char*)d_ws);
    bool all_mode = (ws_size - used) >= (size_t)Lc * SZL * 2;

    embed_kernel<<<(Mc * Dc + 255) / 256, 256, 0, stream>>>(x, wte, wpe, h);
    convert_wte<<<((size_t)Vpad * Dc / 4 + 255) / 256, 256, 0, stream>>>(wte, wte_b);

    if (all_mode) {
        transpose4_kernel<<<dim3(6912, Lc), 256, 0, stream>>>(
            qkvw, projw, fcw, fcpw,
            wtr, wtr + SZ_Q, wtr + SZ_Q + SZ_P, wtr + SZ_Q + SZ_P + SZ_F);
    }

    for (int l = 0; l < Lc; l++) {
        hbf16* base = wtr + (all_mode ? (size_t)l * SZL : 0);
        hbf16* wq_t = base;
        hbf16* wp_t = base + SZ_Q;
        hbf16* wf_t = base + SZ_Q + SZ_P;
        hbf16* wfp_t = base + SZ_Q + SZ_P + SZ_F;
        if (!all_mode) {
            transpose4_kernel<<<dim3(6912, 1), 256, 0, stream>>>(
                qkvw + (size_t)l * SZ_Q, projw + (size_t)l * SZ_P,
                fcw + (size_t)l * SZ_F, fcpw + (size_t)l * SZ_FP,
                wq_t, wp_t, wf_t, wfp_t);
        }

        ln_kernel<<<Mc / 4, 256, 0, stream>>>(h, ln1w + (size_t)l * Dc, ln1b + (size_t)l * Dc, a);
        mm_kernel<0, true, 128><<<dim3(3 * Dc / 128, Mc / 128), 256, 0, stream>>>(
            a, wq_t, qkvb + (size_t)l * 3 * Dc, nullptr, qkv, Mc, 3 * Dc, Dc);
        fattn_kernel<<<dim3(Tc / 64, Hc, Bc), 256, 0, stream>>>(qkv, y);
        mm_kernel<1, false, 64><<<dim3(Dc / 64, Mc / 128), 256, 0, stream>>>(
            y, wp_t, projb + (size_t)l * Dc, h, h, Mc, Dc, Dc);
        ln_kernel<<<Mc / 4, 256, 0, stream>>>(h, ln2w + (size_t)l * Dc, ln2b + (size_t)l * Dc, a);
        mm_kernel<2, true, 128><<<dim3(4 * Dc / 128, Mc / 128), 256, 0, stream>>>(
            a, wf_t, fcb + (size_t)l * 4 * Dc, nullptr, mlp, Mc, 4 * Dc, Dc);
        mm_kernel<1, false, 64><<<dim3(Dc / 64, Mc / 128), 256, 0, stream>>>(
            mlp, wfp_t, fcpb + (size_t)l * Dc, h, h, Mc, Dc, 4 * Dc);
    }

    ln_kernel<<<Mc / 4, 256, 0, stream>>>(h, lnfw, lnfb, a);
    mm2_kernel<<<dim3(Vpad / 128, Mc / 256), 512, 0, stream>>>(
        a, wte_b, (float*)d_out, Mc, Vc, Dc);
}

// Round 13
// 2391.154 us; speedup vs baseline: 1.1776x; 1.0785x over previous
//
#include <hip/hip_runtime.h>
#include <hip/hip_bf16.h>

typedef __hip_bfloat16 hbf16;
using bf16x8 = __attribute__((ext_vector_type(8))) __bf16;
using f32x4 = __attribute__((ext_vector_type(4))) float;

// GPT-2 small: L=12 H=12 D=768 V=50257 T=1024 B=2, HD=64
constexpr int Lc = 12, Hc = 12, Dc = 768, Vc = 50257, Tc = 1024, Bc = 2, HDc = 64;
constexpr int Mc = Bc * Tc;  // 2048 rows
constexpr int Vpad = 50304;  // 393*128, zero-padded vocab

// transposed-weight slot sizes (elements)
constexpr size_t SZ_Q = (size_t)3 * Dc * Dc;   // [2304][768]
constexpr size_t SZ_P = (size_t)Dc * Dc;       // [768][768]
constexpr size_t SZ_F = (size_t)4 * Dc * Dc;   // [3072][768]
constexpr size_t SZ_FP = (size_t)4 * Dc * Dc;  // [768][3072]
constexpr size_t SZL = SZ_Q + SZ_P + SZ_F + SZ_FP;

#define GLD16(gp, lp)                                               \
    __builtin_amdgcn_global_load_lds(                               \
        (__attribute__((address_space(1))) void*)(void*)(gp),       \
        (__attribute__((address_space(3))) void*)(void*)(lp), 16, 0, 0)

// ---------------- embedding: h = wte[x] + wpe[t] (f32) ----------------
__global__ void embed_kernel(const int* __restrict__ x, const float* __restrict__ wte,
                             const float* __restrict__ wpe, float* __restrict__ h) {
    int i = blockIdx.x * blockDim.x + threadIdx.x;
    if (i >= Mc * Dc) return;
    int m = i / Dc, d = i - m * Dc;
    int t = m % Tc;
    int tok = x[m];
    h[i] = wte[(size_t)tok * Dc + d] + wpe[(size_t)t * Dc + d];
}

// ---------------- layernorm: one wave per row, shuffle reduce, f32 in -> bf16 out --
__global__ __launch_bounds__(256) void ln_kernel(const float* __restrict__ x,
                                                 const float* __restrict__ w,
                                                 const float* __restrict__ b,
                                                 hbf16* __restrict__ out) {
    int wv = threadIdx.x >> 6, lane = threadIdx.x & 63;
    int row = blockIdx.x * 4 + wv;
    const float4* xr = (const float4*)(x + (size_t)row * Dc);
    float4 v[3];
    float s = 0.f, sq = 0.f;
#pragma unroll
    for (int i = 0; i < 3; i++) {
        v[i] = xr[i * 64 + lane];
        s += v[i].x + v[i].y + v[i].z + v[i].w;
        sq += v[i].x * v[i].x + v[i].y * v[i].y + v[i].z * v[i].z + v[i].w * v[i].w;
    }
#pragma unroll
    for (int o = 32; o > 0; o >>= 1) {
        s += __shfl_xor(s, o, 64);
        sq += __shfl_xor(sq, o, 64);
    }
    float mean = s * (1.f / Dc);
    float var = sq * (1.f / Dc) - mean * mean;
    float rstd = rsqrtf(var + 1e-5f);
#pragma unroll
    for (int i = 0; i < 3; i++) {
        int c = (i * 64 + lane) * 4;
        float4 wv4 = *(const float4*)(w + c);
        float4 bv4 = *(const float4*)(b + c);
        float r0 = (v[i].x - mean) * rstd * wv4.x + bv4.x;
        float r1 = (v[i].y - mean) * rstd * wv4.y + bv4.y;
        float r2 = (v[i].z - mean) * rstd * wv4.z + bv4.z;
        float r3 = (v[i].w - mean) * rstd * wv4.w + bv4.w;
        __bf16 q0 = (__bf16)r0, q1 = (__bf16)r1, q2 = (__bf16)r2, q3 = (__bf16)r3;
        ushort4 u;
        u.x = *(unsigned short*)&q0; u.y = *(unsigned short*)&q1;
        u.z = *(unsigned short*)&q2; u.w = *(unsigned short*)&q3;
        *(ushort4*)(out + (size_t)row * Dc + c) = u;
    }
}

// ---------------- weight transpose, grid (6912, nlayers) ----------------
__global__ __launch_bounds__(256) void transpose4_kernel(
    const float* __restrict__ s0, const float* __restrict__ s1,
    const float* __restrict__ s2, const float* __restrict__ s3,
    hbf16* __restrict__ d0, hbf16* __restrict__ d1,
    hbf16* __restrict__ d2, hbf16* __restrict__ d3) {
    int id = blockIdx.x;
    size_t lz = blockIdx.y;
    int bx, by, K, N;
    const float* W;
    hbf16* Wt;
    if (id < 1728)      { int t = id;        bx = t % 72; by = t / 72; K = 768;  N = 2304; W = s0 + lz * SZ_Q;  Wt = d0 + lz * SZL; }
    else if (id < 2304) { int t = id - 1728; bx = t % 24; by = t / 24; K = 768;  N = 768;  W = s1 + lz * SZ_P;  Wt = d1 + lz * SZL; }
    else if (id < 4608) { int t = id - 2304; bx = t % 96; by = t / 96; K = 768;  N = 3072; W = s2 + lz * SZ_F;  Wt = d2 + lz * SZL; }
    else                { int t = id - 4608; bx = t % 24; by = t / 24; K = 3072; N = 768;  W = s3 + lz * SZ_FP; Wt = d3 + lz * SZL; }

    __shared__ float tile[32][33];
    int n0 = bx * 32, k0 = by * 32;
    int tx = threadIdx.x & 31, ty = threadIdx.x >> 5;  // 32x8
#pragma unroll
    for (int i = 0; i < 4; i++) {
        int r = ty + i * 8;
        tile[r][tx] = W[(size_t)(k0 + r) * N + n0 + tx];
    }
    __syncthreads();
#pragma unroll
    for (int i = 0; i < 4; i++) {
        int r = ty + i * 8;
        Wt[(size_t)(n0 + r) * K + k0 + tx] = __float2bfloat16(tile[tx][r]);
    }
}

// ---------------- wte f32 [V][D] -> bf16 [Vpad][D] (zero pad) ----------------
__global__ void convert_wte(const float* __restrict__ wte, hbf16* __restrict__ out) {
    size_t i4 = ((size_t)blockIdx.x * 256 + threadIdx.x) * 4;
    if (i4 >= (size_t)Vpad * Dc) return;
    if (i4 < (size_t)Vc * Dc) {
#pragma unroll
        for (int j = 0; j < 4; j++) out[i4 + j] = __float2bfloat16(wte[i4 + j]);
    } else {
#pragma unroll
        for (int j = 0; j < 4; j++) out[i4 + j] = __float2bfloat16(0.f);
    }
}

// ---------------- MFMA GEMM 128xBN, BK=64: C = A@Bt^T + epilogue ----------
// 32 MFMAs per barrier-pair (half the vmcnt(0) drains of BK=32).
// Row stride 128B = full bank cycle; slot^(row&7) XOR -> 2-way max on frag reads.
// EPI: 0 = +bias, 1 = +bias +f32 residual, 2 = +bias + tanh-GELU
template <int EPI, bool OUTBF, int BN>
__global__ __launch_bounds__(256) void mm_kernel(const hbf16* __restrict__ A,
                                                 const hbf16* __restrict__ Bt,
                                                 const float* __restrict__ bias,
                                                 const float* __restrict__ resid,
                                                 void* __restrict__ Cout,
                                                 int M, int N, int K) {
    constexpr int NF = BN / 32;   // n-frags per wave
    constexpr int NBI = BN / 32;  // B stage issues (32 rows each)
    __shared__ __bf16 As[128 * 64];  // 16 KB
    __shared__ __bf16 Bs[BN * 64];   // 16 KB (BN=128) / 8 KB (BN=64)
    int tid = threadIdx.x;
    int l = tid & 63, w = tid >> 6;
    int wr = w >> 1, wc = w & 1;

    // XCD swizzle: hw dispatch order is x-fastest; chunk per XCD, m fastest.
    int gx = gridDim.x, gy = gridDim.y;
    int nwg = gx * gy;
    int hwlin = blockIdx.y * gx + blockIdx.x;
    int wk = (hwlin & 7) * (nwg >> 3) + (hwlin >> 3);
    int m0 = (wk % gy) * 128;
    int n0 = (wk / gy) * BN;

    // staging: 32 rows/issue; row = j*32 + (tid>>3), 16B slot sc = tid&7
    // source col = (sc ^ (row&7))*8 so LDS[row][slot] = G[row][slot^(row&7)]
    int sr = tid >> 3, sc = tid & 7;
    int scs = (sc ^ (sr & 7)) * 8;
    const hbf16* pA[4];
    __bf16* lA[4];
#pragma unroll
    for (int j = 0; j < 4; j++) {
        pA[j] = A + (size_t)(m0 + j * 32 + sr) * K + scs;
        lA[j] = As + j * 2048 + tid * 8;
    }
    const hbf16* pB[NBI];
    __bf16* lB[NBI];
#pragma unroll
    for (int j = 0; j < NBI; j++) {
        pB[j] = Bt + (size_t)(n0 + j * 32 + sr) * K + scs;
        lB[j] = Bs + j * 2048 + tid * 8;
    }

    int lr = l & 15, lg = l >> 4;
    // frag reads: k-slot (kk*4+lg) XOR (row&7) = (lr&7)
    int aoff[2][4], boff[2][NF];
#pragma unroll
    for (int kk = 0; kk < 2; kk++) {
        int ks = ((kk * 4 + lg) ^ (lr & 7)) * 8;
#pragma unroll
        for (int m = 0; m < 4; m++) aoff[kk][m] = (wr * 64 + m * 16 + lr) * 64 + ks;
#pragma unroll
        for (int n = 0; n < NF; n++) boff[kk][n] = (wc * (BN / 2) + n * 16 + lr) * 64 + ks;
    }

    f32x4 acc[4][NF] = {};

    for (int k0 = 0; k0 < K; k0 += 64) {
#pragma unroll
        for (int j = 0; j < 4; j++) {
            GLD16(pA[j], lA[j]);
            pA[j] += 64;
        }
#pragma unroll
        for (int j = 0; j < NBI; j++) {
            GLD16(pB[j], lB[j]);
            pB[j] += 64;
        }
        __syncthreads();
#pragma unroll
        for (int kk = 0; kk < 2; kk++) {
            bf16x8 af[4], bfr[NF];
#pragma unroll
            for (int m = 0; m < 4; m++) af[m] = *(const bf16x8*)&As[aoff[kk][m]];
#pragma unroll
            for (int n = 0; n < NF; n++) bfr[n] = *(const bf16x8*)&Bs[boff[kk][n]];
#pragma unroll
            for (int m = 0; m < 4; m++)
#pragma unroll
                for (int n = 0; n < NF; n++)
                    acc[m][n] = __builtin_amdgcn_mfma_f32_16x16x32_bf16(af[m], bfr[n], acc[m][n], 0, 0, 0);
        }
        __syncthreads();
    }

#pragma unroll
    for (int n = 0; n < NF; n++) {
        int col = n0 + wc * (BN / 2) + n * 16 + lr;
        bool cok = col < N;
        float bv = (bias && cok) ? bias[col] : 0.f;
#pragma unroll
        for (int m = 0; m < 4; m++) {
#pragma unroll
            for (int r = 0; r < 4; r++) {
                int row = m0 + wr * 64 + m * 16 + lg * 4 + r;
                if (!cok) continue;
                float v = acc[m][n][r] + bv;
                if (EPI == 1) v += resid[(size_t)row * N + col];
                if (EPI == 2) {
                    float x3 = v * v * v;
                    v = 0.5f * v * (1.f + tanhf(0.7978845608028654f * (v + 0.044715f * x3)));
                }
                if (OUTBF)
                    ((hbf16*)Cout)[(size_t)row * N + col] = __float2bfloat16(v);
                else
                    ((float*)Cout)[(size_t)row * N + col] = v;
            }
        }
    }
}

// ---------------- MFMA GEMM 256x128, 512 threads, 2-phase dbuf (lm_head) ----------
__global__ __launch_bounds__(512) void mm2_kernel(const hbf16* __restrict__ A,
                                                  const hbf16* __restrict__ Bt,
                                                  float* __restrict__ Cout,
                                                  int M, int N, int K) {
    __shared__ __bf16 As[2][256 * 32];  // 2 x 16 KB
    __shared__ __bf16 Bs[2][128 * 32];  // 2 x 8 KB
    int tid = threadIdx.x;
    int l = tid & 63, w = tid >> 6;
    int wr = w >> 1, wc = w & 1;

    int gx = gridDim.x, gy = gridDim.y;  // gy = 8
    int nwg = gx * gy;
    int hwlin = blockIdx.y * gx + blockIdx.x;
    int wk = (hwlin & 7) * (nwg >> 3) + (hwlin >> 3);
    int m0 = (wk & 7) * 256;
    int n0 = (wk >> 3) * 128;

    int sr = tid >> 2, sc = tid & 3;
    int scs = (sc ^ (sr & 3)) * 8;
    const hbf16* gA0 = A + (size_t)(m0 + sr) * K + scs;
    const hbf16* gA1 = A + (size_t)(m0 + 128 + sr) * K + scs;
    const hbf16* gB = Bt + (size_t)(n0 + sr) * K + scs;

    auto stage = [&](int bi, int ko) {
        GLD16(gA0 + ko, &As[bi][tid * 8]);
        GLD16(gA1 + ko, &As[bi][4096 + tid * 8]);
        GLD16(gB + ko, &Bs[bi][tid * 8]);
    };

    int lr = l & 15, lg = l >> 4;
    int ksl = (lg ^ (lr & 3)) * 8;
    int aoff[4], boff[4];
#pragma unroll
    for (int m = 0; m < 4; m++) aoff[m] = (wr * 64 + m * 16 + lr) * 32 + ksl;
#pragma unroll
    for (int n = 0; n < 4; n++) boff[n] = (wc * 64 + n * 16 + lr) * 32 + ksl;

    f32x4 acc[4][4] = {};
    int nk = K / 32;

    stage(0, 0);
    __syncthreads();
    for (int t = 0; t < nk; ++t) {
        int cur = t & 1;
        if (t + 1 < nk) stage(cur ^ 1, (t + 1) * 32);
        bf16x8 af[4], bfr[4];
#pragma unroll
        for (int m = 0; m < 4; m++) af[m] = *(const bf16x8*)&As[cur][aoff[m]];
#pragma unroll
        for (int n = 0; n < 4; n++) bfr[n] = *(const bf16x8*)&Bs[cur][boff[n]];
#pragma unroll
        for (int m = 0; m < 4; m++)
#pragma unroll
            for (int n = 0; n < 4; n++)
                acc[m][n] = __builtin_amdgcn_mfma_f32_16x16x32_bf16(af[m], bfr[n], acc[m][n], 0, 0, 0);
        __syncthreads();
    }

#pragma unroll
    for (int n = 0; n < 4; n++) {
        int col = n0 + wc * 64 + n * 16 + lr;
        if (col >= N) continue;
#pragma unroll
        for (int m = 0; m < 4; m++) {
#pragma unroll
            for (int r = 0; r < 4; r++) {
                int row = m0 + wr * 64 + m * 16 + lg * 4 + r;
                Cout[(size_t)row * N + col] = acc[m][n][r];
            }
        }
    }
}

// ---------------- MFMA flash attention, pipelined + swapped QK^T ----------------
__global__ __launch_bounds__(256) void fattn_kernel(const hbf16* __restrict__ qkv,
                                                    hbf16* __restrict__ y) {
    int qt = gridDim.x - 1 - blockIdx.x;  // heavy tiles first
    int h = blockIdx.y, b = blockIdx.z;
    int q0 = qt * 64;
    int tid = threadIdx.x;
    int l = tid & 63, w = tid >> 6;
    int li = l & 15, lg = l >> 4;
    constexpr int RS = 3 * Dc;
    constexpr int PST = 72;
    constexpr int VST = 72;
    constexpr float SCL = 0.125f * 1.44269504f;  // 1/sqrt(64) * log2(e)
    constexpr float THR = 11.5f;                 // defer-max threshold (log2 domain)

    __shared__ __bf16 K_lds[2][64 * 64];   // 2 x 8 KB, swizzled 16B slots
    __shared__ __bf16 Vt[2][64 * VST];     // 2 x 9 KB
    __shared__ __bf16 P_lds[4][16 * PST];  // 9 KB  (layout [q_local][j])

    bf16x8 qf[2];
    {
        const hbf16* qp = qkv + (size_t)(b * Tc + q0 + w * 16 + li) * RS + h * HDc + lg * 8;
        qf[0] = *(const bf16x8*)qp;
        qf[1] = *(const bf16x8*)(qp + 32);
    }

    int krow0 = tid >> 3, krow1 = 32 + (tid >> 3);
    int ks8 = tid & 7;
    int kc0 = (ks8 ^ (krow0 & 7)) * 8;
    int kc1 = (ks8 ^ (krow1 & 7)) * 8;
    const hbf16* kbase = qkv + (size_t)(b * Tc) * RS + Dc + h * HDc;

    int jp = (tid >> 3) * 2;
    int db = (tid & 7) * 8;
    const hbf16* vbase = qkv + (size_t)(b * Tc) * RS + 2 * Dc + h * HDc;

    int koff[2][4];
#pragma unroll
    for (int ks = 0; ks < 2; ks++)
#pragma unroll
        for (int n = 0; n < 4; n++)
            koff[ks][n] = (n * 16 + li) * 64 + (((ks * 4 + lg) ^ (li & 7)) * 8);

    f32x4 acc_o[4] = {};
    float m_run = -1e30f, l_run = 0.f;  // scalar: lane owns q = w*16+li

    bf16x8 vr0, vr1;
    {
        const hbf16* vp = vbase + (size_t)jp * RS + db;
        vr0 = *(const bf16x8*)vp;
        vr1 = *(const bf16x8*)(vp + RS);
        GLD16(kbase + (size_t)krow0 * RS + kc0, &K_lds[0][tid * 8]);
        GLD16(kbase + (size_t)krow1 * RS + kc1, &K_lds[0][2048 + tid * 8]);
    }
#pragma unroll
    for (int i = 0; i < 8; i++) {
        __bf16 a0 = vr0[i], a1 = vr1[i];
        unsigned u = (unsigned)*(unsigned short*)&a0 | ((unsigned)*(unsigned short*)&a1 << 16);
        *(unsigned*)&Vt[0][(db + i) * VST + jp] = u;
    }

    int cur = 0;
    for (int jt = 0; jt <= qt; jt++) {
        int jn0 = (jt < qt) ? (jt + 1) * 64 : 0;  // dummy wrap keeps vmcnt invariant

        asm volatile("s_waitcnt lgkmcnt(0)" ::: "memory");
        __builtin_amdgcn_s_barrier();

        {
            const hbf16* vp = vbase + (size_t)(jn0 + jp) * RS + db;
            vr0 = *(const bf16x8*)vp;
            vr1 = *(const bf16x8*)(vp + RS);
            GLD16(kbase + (size_t)(jn0 + krow0) * RS + kc0, &K_lds[cur ^ 1][tid * 8]);
            GLD16(kbase + (size_t)(jn0 + krow1) * RS + kc1, &K_lds[cur ^ 1][2048 + tid * 8]);
        }

        asm volatile("s_waitcnt vmcnt(4)" ::: "memory");
        __builtin_amdgcn_sched_barrier(0);

        // ---- S = K Q^T (swapped): s[n][r] = S[j=n*16+lg*4+r][q=li] ----
        f32x4 s[4] = {};
#pragma unroll
        for (int ks = 0; ks < 2; ks++)
#pragma unroll
            for (int n = 0; n < 4; n++) {
                bf16x8 kf = *(const bf16x8*)&K_lds[cur][koff[ks][n]];
                s[n] = __builtin_amdgcn_mfma_f32_16x16x32_bf16(kf, qf[ks], s[n], 0, 0, 0);
            }
#pragma unroll
        for (int n = 0; n < 4; n++)
#pragma unroll
            for (int r = 0; r < 4; r++) s[n][r] *= SCL;

        if (jt == qt) {
            int qloc = w * 16 + li;
#pragma unroll
            for (int n = 0; n < 4; n++)
#pragma unroll
                for (int r = 0; r < 4; r++)
                    if (n * 16 + lg * 4 + r > qloc) s[n][r] = -1e30f;
        }

        // ---- online softmax: all 16 values belong to q = w*16+li ----
        float mx = -1e30f;
#pragma unroll
        for (int n = 0; n < 4; n++)
#pragma unroll
            for (int r = 0; r < 4; r++) mx = fmaxf(mx, s[n][r]);
        mx = fmaxf(mx, __shfl_xor(mx, 16, 64));
        mx = fmaxf(mx, __shfl_xor(mx, 32, 64));

        bool dfr = __all(mx - m_run <= THR);
        float sclq = 1.f;
        if (!dfr) {
            float mnew = fmaxf(m_run, mx);
            sclq = exp2f(m_run - mnew);
            m_run = mnew;
        }
        float rs = 0.f;
#pragma unroll
        for (int n = 0; n < 4; n++)
#pragma unroll
            for (int r = 0; r < 4; r++) {
                float pv = exp2f(s[n][r] - m_run);
                s[n][r] = pv;
                rs += pv;
            }
        rs += __shfl_xor(rs, 16, 64);
        rs += __shfl_xor(rs, 32, 64);
        l_run = (dfr ? l_run : l_run * sclq) + rs;

        // ---- P -> LDS [q=li][j], packed pairs ----
#pragma unroll
        for (int n = 0; n < 4; n++)
#pragma unroll
            for (int r = 0; r < 4; r += 2) {
                __bf16 b0 = (__bf16)s[n][r], b1 = (__bf16)s[n][r + 1];
                unsigned u = (unsigned)*(unsigned short*)&b0 |
                             ((unsigned)*(unsigned short*)&b1 << 16);
                *(unsigned*)&P_lds[w][li * PST + n * 16 + lg * 4 + r] = u;
            }
        bf16x8 pa0 = *(const bf16x8*)&P_lds[w][li * PST + lg * 8];
        bf16x8 pa1 = *(const bf16x8*)&P_lds[w][li * PST + 32 + lg * 8];

        if (!dfr) {
#pragma unroll
            for (int r = 0; r < 4; r++) {
                float sr_ = __shfl(sclq, (l & 48) | (lg * 4 + r), 64);
#pragma unroll
                for (int n2 = 0; n2 < 4; n2++) acc_o[n2][r] *= sr_;
            }
        }

        // ---- PV from Vt[cur] ----
#pragma unroll
        for (int n2 = 0; n2 < 4; n2++) {
            bf16x8 vf0 = *(const bf16x8*)&Vt[cur][(n2 * 16 + li) * VST + lg * 8];
            bf16x8 vf1 = *(const bf16x8*)&Vt[cur][(n2 * 16 + li) * VST + 32 + lg * 8];
            acc_o[n2] = __builtin_amdgcn_mfma_f32_16x16x32_bf16(pa0, vf0, acc_o[n2], 0, 0, 0);
            acc_o[n2] = __builtin_amdgcn_mfma_f32_16x16x32_bf16(pa1, vf1, acc_o[n2], 0, 0, 0);
        }

        // ---- write V(jt+1) regs -> Vt[cur^1] ----
#pragma unroll
        for (int i = 0; i < 8; i++) {
            __bf16 a0 = vr0[i], a1 = vr1[i];
            unsigned u = (unsigned)*(unsigned short*)&a0 | ((unsigned)*(unsigned short*)&a1 << 16);
            *(unsigned*)&Vt[cur ^ 1][(db + i) * VST + jp] = u;
        }
        cur ^= 1;
    }

#pragma unroll
    for (int r = 0; r < 4; r++) {
        float lv = __shfl(l_run, (l & 48) | (lg * 4 + r), 64);
        float rcp = 1.f / lv;
        int row = q0 + w * 16 + lg * 4 + r;
#pragma unroll
        for (int n2 = 0; n2 < 4; n2++)
            y[(size_t)(b * Tc + row) * Dc + h * HDc + n2 * 16 + li] =
                __float2bfloat16(acc_o[n2][r] * rcp);
    }
}

extern "C" void kernel_launch(void* const* d_in, const int* in_sizes, int n_in,
                              void* d_out, int out_size, void* d_ws, size_t ws_size,
                              hipStream_t stream) {
    const int* x = (const int*)d_in[0];
    const float* wte = (const float*)d_in[1];
    const float* wpe = (const float*)d_in[2];
    const float* ln1w = (const float*)d_in[3];
    const float* ln1b = (const float*)d_in[4];
    const float* qkvw = (const float*)d_in[5];
    const float* qkvb = (const float*)d_in[6];
    const float* projw = (const float*)d_in[7];
    const float* projb = (const float*)d_in[8];
    const float* ln2w = (const float*)d_in[9];
    const float* ln2b = (const float*)d_in[10];
    const float* fcw = (const float*)d_in[11];
    const float* fcb = (const float*)d_in[12];
    const float* fcpw = (const float*)d_in[13];
    const float* fcpb = (const float*)d_in[14];
    const float* lnfw = (const float*)d_in[15];
    const float* lnfb = (const float*)d_in[16];

    char* p = (char*)d_ws;
    float* h = (float*)p;     p += (size_t)Mc * Dc * 4;      // f32 [M][D]
    hbf16* qkv = (hbf16*)p;   p += (size_t)Mc * 3 * Dc * 2;  // bf16 [M][3D]
    hbf16* a = (hbf16*)p;     p += (size_t)Mc * Dc * 2;      // bf16 [M][D]
    hbf16* y = (hbf16*)p;     p += (size_t)Mc * Dc * 2;      // bf16 [M][D]
    hbf16* mlp = (hbf16*)p;   p += (size_t)Mc * 4 * Dc * 2;  // bf16 [M][4D]
    hbf16* wte_b = (hbf16*)p; p += (size_t)Vpad * Dc * 2;    // [50304][768]
    hbf16* wtr = (hbf16*)p;                                  // transposed weights
    size_t used = (size_t)((char*)wtr - (char*)d_ws);
    bool all_mode = (ws_size - used) >= (size_t)Lc * SZL * 2;

    embed_kernel<<<(Mc * Dc + 255) / 256, 256, 0, stream>>>(x, wte, wpe, h);
    convert_wte<<<((size_t)Vpad * Dc / 4 + 255) / 256, 256, 0, stream>>>(wte, wte_b);

    if (all_mode) {
        transpose4_kernel<<<dim3(6912, Lc), 256, 0, stream>>>(
            qkvw, projw, fcw, fcpw,
            wtr, wtr + SZ_Q, wtr + SZ_Q + SZ_P, wtr + SZ_Q + SZ_P + SZ_F);
    }

    for (int l = 0; l < Lc; l++) {
        hbf16* base = wtr + (all_mode ? (size_t)l * SZL : 0);
        hbf16* wq_t = base;
        hbf16* wp_t = base + SZ_Q;
        hbf16* wf_t = base + SZ_Q + SZ_P;
        hbf16* wfp_t = base + SZ_Q + SZ_P + SZ_F;
        if (!all_mode) {
            transpose4_kernel<<<dim3(6912, 1), 256, 0, stream>>>(
                qkvw + (size_t)l * SZ_Q, projw + (size_t)l * SZ_P,
                fcw + (size_t)l * SZ_F, fcpw + (size_t)l * SZ_FP,
                wq_t, wp_t, wf_t, wfp_t);
        }

        ln_kernel<<<Mc / 4, 256, 0, stream>>>(h, ln1w + (size_t)l * Dc, ln1b + (size_t)l * Dc, a);
        mm_kernel<0, true, 128><<<dim3(3 * Dc / 128, Mc / 128), 256, 0, stream>>>(
            a, wq_t, qkvb + (size_t)l * 3 * Dc, nullptr, qkv, Mc, 3 * Dc, Dc);
        fattn_kernel<<<dim3(Tc / 64, Hc, Bc), 256, 0, stream>>>(qkv, y);
        mm_kernel<1, false, 64><<<dim3(Dc / 64, Mc / 128), 256, 0, stream>>>(
            y, wp_t, projb + (size_t)l * Dc, h, h, Mc, Dc, Dc);
        ln_kernel<<<Mc / 4, 256, 0, stream>>>(h, ln2w + (size_t)l * Dc, ln2b + (size_t)l * Dc, a);
        mm_kernel<2, true, 128><<<dim3(4 * Dc / 128, Mc / 128), 256, 0, stream>>>(
            a, wf_t, fcb + (size_t)l * 4 * Dc, nullptr, mlp, Mc, 4 * Dc, Dc);
        mm_kernel<1, false, 64><<<dim3(Dc / 64, Mc / 128), 256, 0, stream>>>(
            mlp, wfp_t, fcpb + (size_t)l * Dc, h, h, Mc, Dc, 4 * Dc);
    }

    ln_kernel<<<Mc / 4, 256, 0, stream>>>(h, lnfw, lnfb, a);
    mm2_kernel<<<dim3(Vpad / 128, Mc / 256), 512, 0, stream>>>(
        a, wte_b, (float*)d_out, Mc, Vc, Dc);
}

// Round 14
// 2370.950 us; speedup vs baseline: 1.1877x; 1.0085x over previous
//
#include <hip/hip_runtime.h>
#include <hip/hip_bf16.h>

typedef __hip_bfloat16 hbf16;
using bf16x8 = __attribute__((ext_vector_type(8))) __bf16;
using f32x4 = __attribute__((ext_vector_type(4))) float;

// GPT-2 small: L=12 H=12 D=768 V=50257 T=1024 B=2, HD=64
constexpr int Lc = 12, Hc = 12, Dc = 768, Vc = 50257, Tc = 1024, Bc = 2, HDc = 64;
constexpr int Mc = Bc * Tc;  // 2048 rows
constexpr int Vpad = 50304;  // 393*128, zero-padded vocab

// transposed-weight slot sizes (elements)
constexpr size_t SZ_Q = (size_t)3 * Dc * Dc;   // [2304][768]
constexpr size_t SZ_P = (size_t)Dc * Dc;       // [768][768]
constexpr size_t SZ_F = (size_t)4 * Dc * Dc;   // [3072][768]
constexpr size_t SZ_FP = (size_t)4 * Dc * Dc;  // [768][3072]
constexpr size_t SZL = SZ_Q + SZ_P + SZ_F + SZ_FP;

#define GLD16(gp, lp)                                               \
    __builtin_amdgcn_global_load_lds(                               \
        (__attribute__((address_space(1))) void*)(void*)(gp),       \
        (__attribute__((address_space(3))) void*)(void*)(lp), 16, 0, 0)

// ---------------- embedding: h = wte[x] + wpe[t] (f32) ----------------
__global__ void embed_kernel(const int* __restrict__ x, const float* __restrict__ wte,
                             const float* __restrict__ wpe, float* __restrict__ h) {
    int i = blockIdx.x * blockDim.x + threadIdx.x;
    if (i >= Mc * Dc) return;
    int m = i / Dc, d = i - m * Dc;
    int t = m % Tc;
    int tok = x[m];
    h[i] = wte[(size_t)tok * Dc + d] + wpe[(size_t)t * Dc + d];
}

// ---------------- layernorm: one wave per row, shuffle reduce, f32 in -> bf16 out --
__global__ __launch_bounds__(256) void ln_kernel(const float* __restrict__ x,
                                                 const float* __restrict__ w,
                                                 const float* __restrict__ b,
                                                 hbf16* __restrict__ out) {
    int wv = threadIdx.x >> 6, lane = threadIdx.x & 63;
    int row = blockIdx.x * 4 + wv;
    const float4* xr = (const float4*)(x + (size_t)row * Dc);
    float4 v[3];
    float s = 0.f, sq = 0.f;
#pragma unroll
    for (int i = 0; i < 3; i++) {
        v[i] = xr[i * 64 + lane];
        s += v[i].x + v[i].y + v[i].z + v[i].w;
        sq += v[i].x * v[i].x + v[i].y * v[i].y + v[i].z * v[i].z + v[i].w * v[i].w;
    }
#pragma unroll
    for (int o = 32; o > 0; o >>= 1) {
        s += __shfl_xor(s, o, 64);
        sq += __shfl_xor(sq, o, 64);
    }
    float mean = s * (1.f / Dc);
    float var = sq * (1.f / Dc) - mean * mean;
    float rstd = rsqrtf(var + 1e-5f);
#pragma unroll
    for (int i = 0; i < 3; i++) {
        int c = (i * 64 + lane) * 4;
        float4 wv4 = *(const float4*)(w + c);
        float4 bv4 = *(const float4*)(b + c);
        float r0 = (v[i].x - mean) * rstd * wv4.x + bv4.x;
        float r1 = (v[i].y - mean) * rstd * wv4.y + bv4.y;
        float r2 = (v[i].z - mean) * rstd * wv4.z + bv4.z;
        float r3 = (v[i].w - mean) * rstd * wv4.w + bv4.w;
        __bf16 q0 = (__bf16)r0, q1 = (__bf16)r1, q2 = (__bf16)r2, q3 = (__bf16)r3;
        ushort4 u;
        u.x = *(unsigned short*)&q0; u.y = *(unsigned short*)&q1;
        u.z = *(unsigned short*)&q2; u.w = *(unsigned short*)&q3;
        *(ushort4*)(out + (size_t)row * Dc + c) = u;
    }
}

// ---------------- weight transpose, grid (6912, nlayers) ----------------
__global__ __launch_bounds__(256) void transpose4_kernel(
    const float* __restrict__ s0, const float* __restrict__ s1,
    const float* __restrict__ s2, const float* __restrict__ s3,
    hbf16* __restrict__ d0, hbf16* __restrict__ d1,
    hbf16* __restrict__ d2, hbf16* __restrict__ d3) {
    int id = blockIdx.x;
    size_t lz = blockIdx.y;
    int bx, by, K, N;
    const float* W;
    hbf16* Wt;
    if (id < 1728)      { int t = id;        bx = t % 72; by = t / 72; K = 768;  N = 2304; W = s0 + lz * SZ_Q;  Wt = d0 + lz * SZL; }
    else if (id < 2304) { int t = id - 1728; bx = t % 24; by = t / 24; K = 768;  N = 768;  W = s1 + lz * SZ_P;  Wt = d1 + lz * SZL; }
    else if (id < 4608) { int t = id - 2304; bx = t % 96; by = t / 96; K = 768;  N = 3072; W = s2 + lz * SZ_F;  Wt = d2 + lz * SZL; }
    else                { int t = id - 4608; bx = t % 24; by = t / 24; K = 3072; N = 768;  W = s3 + lz * SZ_FP; Wt = d3 + lz * SZL; }

    __shared__ float tile[32][33];
    int n0 = bx * 32, k0 = by * 32;
    int tx = threadIdx.x & 31, ty = threadIdx.x >> 5;  // 32x8
#pragma unroll
    for (int i = 0; i < 4; i++) {
        int r = ty + i * 8;
        tile[r][tx] = W[(size_t)(k0 + r) * N + n0 + tx];
    }
    __syncthreads();
#pragma unroll
    for (int i = 0; i < 4; i++) {
        int r = ty + i * 8;
        Wt[(size_t)(n0 + r) * K + k0 + tx] = __float2bfloat16(tile[tx][r]);
    }
}

// ---------------- wte f32 [V][D] -> bf16 [Vpad][D] (zero pad) ----------------
__global__ void convert_wte(const float* __restrict__ wte, hbf16* __restrict__ out) {
    size_t i4 = ((size_t)blockIdx.x * 256 + threadIdx.x) * 4;
    if (i4 >= (size_t)Vpad * Dc) return;
    if (i4 < (size_t)Vc * Dc) {
#pragma unroll
        for (int j = 0; j < 4; j++) out[i4 + j] = __float2bfloat16(wte[i4 + j]);
    } else {
#pragma unroll
        for (int j = 0; j < 4; j++) out[i4 + j] = __float2bfloat16(0.f);
    }
}

// ---------------- MFMA GEMM 128xBN, BK=64: C = A@Bt^T + epilogue ----------
// 32 MFMAs per barrier-pair; 128B row stride; slot^(row&7) XOR -> 2-way max reads.
// EPI: 0 = +bias, 1 = +bias +f32 residual, 2 = +bias + tanh-GELU
template <int EPI, bool OUTBF, int BN>
__global__ __launch_bounds__(256) void mm_kernel(const hbf16* __restrict__ A,
                                                 const hbf16* __restrict__ Bt,
                                                 const float* __restrict__ bias,
                                                 const float* __restrict__ resid,
                                                 void* __restrict__ Cout,
                                                 int M, int N, int K) {
    constexpr int NF = BN / 32;   // n-frags per wave
    constexpr int NBI = BN / 32;  // B stage issues (32 rows each)
    __shared__ __bf16 As[128 * 64];  // 16 KB
    __shared__ __bf16 Bs[BN * 64];   // 16 KB (BN=128) / 8 KB (BN=64)
    int tid = threadIdx.x;
    int l = tid & 63, w = tid >> 6;
    int wr = w >> 1, wc = w & 1;

    // XCD swizzle: hw dispatch order is x-fastest; chunk per XCD, m fastest.
    int gx = gridDim.x, gy = gridDim.y;
    int nwg = gx * gy;
    int hwlin = blockIdx.y * gx + blockIdx.x;
    int wk = (hwlin & 7) * (nwg >> 3) + (hwlin >> 3);
    int m0 = (wk % gy) * 128;
    int n0 = (wk / gy) * BN;

    // staging: 32 rows/issue; row = j*32 + (tid>>3), 16B slot sc = tid&7
    int sr = tid >> 3, sc = tid & 7;
    int scs = (sc ^ (sr & 7)) * 8;
    const hbf16* pA[4];
    __bf16* lA[4];
#pragma unroll
    for (int j = 0; j < 4; j++) {
        pA[j] = A + (size_t)(m0 + j * 32 + sr) * K + scs;
        lA[j] = As + j * 2048 + tid * 8;
    }
    const hbf16* pB[NBI];
    __bf16* lB[NBI];
#pragma unroll
    for (int j = 0; j < NBI; j++) {
        pB[j] = Bt + (size_t)(n0 + j * 32 + sr) * K + scs;
        lB[j] = Bs + j * 2048 + tid * 8;
    }

    int lr = l & 15, lg = l >> 4;
    int aoff[2][4], boff[2][NF];
#pragma unroll
    for (int kk = 0; kk < 2; kk++) {
        int ks = ((kk * 4 + lg) ^ (lr & 7)) * 8;
#pragma unroll
        for (int m = 0; m < 4; m++) aoff[kk][m] = (wr * 64 + m * 16 + lr) * 64 + ks;
#pragma unroll
        for (int n = 0; n < NF; n++) boff[kk][n] = (wc * (BN / 2) + n * 16 + lr) * 64 + ks;
    }

    f32x4 acc[4][NF] = {};

    for (int k0 = 0; k0 < K; k0 += 64) {
#pragma unroll
        for (int j = 0; j < 4; j++) {
            GLD16(pA[j], lA[j]);
            pA[j] += 64;
        }
#pragma unroll
        for (int j = 0; j < NBI; j++) {
            GLD16(pB[j], lB[j]);
            pB[j] += 64;
        }
        __syncthreads();
#pragma unroll
        for (int kk = 0; kk < 2; kk++) {
            bf16x8 af[4], bfr[NF];
#pragma unroll
            for (int m = 0; m < 4; m++) af[m] = *(const bf16x8*)&As[aoff[kk][m]];
#pragma unroll
            for (int n = 0; n < NF; n++) bfr[n] = *(const bf16x8*)&Bs[boff[kk][n]];
#pragma unroll
            for (int m = 0; m < 4; m++)
#pragma unroll
                for (int n = 0; n < NF; n++)
                    acc[m][n] = __builtin_amdgcn_mfma_f32_16x16x32_bf16(af[m], bfr[n], acc[m][n], 0, 0, 0);
        }
        __syncthreads();
    }

#pragma unroll
    for (int n = 0; n < NF; n++) {
        int col = n0 + wc * (BN / 2) + n * 16 + lr;
        bool cok = col < N;
        float bv = (bias && cok) ? bias[col] : 0.f;
#pragma unroll
        for (int m = 0; m < 4; m++) {
#pragma unroll
            for (int r = 0; r < 4; r++) {
                int row = m0 + wr * 64 + m * 16 + lg * 4 + r;
                if (!cok) continue;
                float v = acc[m][n][r] + bv;
                if (EPI == 1) v += resid[(size_t)row * N + col];
                if (EPI == 2) {
                    float x3 = v * v * v;
                    v = 0.5f * v * (1.f + tanhf(0.7978845608028654f * (v + 0.044715f * x3)));
                }
                if (OUTBF)
                    ((hbf16*)Cout)[(size_t)row * N + col] = __float2bfloat16(v);
                else
                    ((float*)Cout)[(size_t)row * N + col] = v;
            }
        }
    }
}

// ---------------- MFMA GEMM 256x128, 512 threads, BK=64 single-buffer (lm_head) ---
// 12 K-steps (half the drains of BK=32); slot^(row&7) kills the 4-way frag conflict.
__global__ __launch_bounds__(512) void mm2_kernel(const hbf16* __restrict__ A,
                                                  const hbf16* __restrict__ Bt,
                                                  float* __restrict__ Cout,
                                                  int M, int N, int K) {
    __shared__ __bf16 As[256 * 64];  // 32 KB
    __shared__ __bf16 Bs[128 * 64];  // 16 KB
    int tid = threadIdx.x;
    int l = tid & 63, w = tid >> 6;
    int wr = w >> 1, wc = w & 1;

    int gx = gridDim.x, gy = gridDim.y;  // gy = 8
    int nwg = gx * gy;
    int hwlin = blockIdx.y * gx + blockIdx.x;
    int wk = (hwlin & 7) * (nwg >> 3) + (hwlin >> 3);
    int m0 = (wk & 7) * 256;
    int n0 = (wk >> 3) * 128;

    // staging: 64 rows/issue (512 thr x 16B = 8KB); row = j*64 + (tid>>3)
    int sr = tid >> 3, sc = tid & 7;
    int scs = (sc ^ (sr & 7)) * 8;
    const hbf16* pA[4];
    __bf16* lA[4];
#pragma unroll
    for (int j = 0; j < 4; j++) {
        pA[j] = A + (size_t)(m0 + j * 64 + sr) * K + scs;
        lA[j] = As + j * 4096 + tid * 8;
    }
    const hbf16* pB[2];
    __bf16* lB[2];
#pragma unroll
    for (int j = 0; j < 2; j++) {
        pB[j] = Bt + (size_t)(n0 + j * 64 + sr) * K + scs;
        lB[j] = Bs + j * 4096 + tid * 8;
    }

    int lr = l & 15, lg = l >> 4;
    int aoff[2][4], boff[2][4];
#pragma unroll
    for (int kk = 0; kk < 2; kk++) {
        int ks = ((kk * 4 + lg) ^ (lr & 7)) * 8;
#pragma unroll
        for (int m = 0; m < 4; m++) aoff[kk][m] = (wr * 64 + m * 16 + lr) * 64 + ks;
#pragma unroll
        for (int n = 0; n < 4; n++) boff[kk][n] = (wc * 64 + n * 16 + lr) * 64 + ks;
    }

    f32x4 acc[4][4] = {};

    for (int k0 = 0; k0 < K; k0 += 64) {
#pragma unroll
        for (int j = 0; j < 4; j++) {
            GLD16(pA[j], lA[j]);
            pA[j] += 64;
        }
#pragma unroll
        for (int j = 0; j < 2; j++) {
            GLD16(pB[j], lB[j]);
            pB[j] += 64;
        }
        __syncthreads();
#pragma unroll
        for (int kk = 0; kk < 2; kk++) {
            bf16x8 af[4], bfr[4];
#pragma unroll
            for (int m = 0; m < 4; m++) af[m] = *(const bf16x8*)&As[aoff[kk][m]];
#pragma unroll
            for (int n = 0; n < 4; n++) bfr[n] = *(const bf16x8*)&Bs[boff[kk][n]];
#pragma unroll
            for (int m = 0; m < 4; m++)
#pragma unroll
                for (int n = 0; n < 4; n++)
                    acc[m][n] = __builtin_amdgcn_mfma_f32_16x16x32_bf16(af[m], bfr[n], acc[m][n], 0, 0, 0);
        }
        __syncthreads();
    }

#pragma unroll
    for (int n = 0; n < 4; n++) {
        int col = n0 + wc * 64 + n * 16 + lr;
        if (col >= N) continue;
#pragma unroll
        for (int m = 0; m < 4; m++) {
#pragma unroll
            for (int r = 0; r < 4; r++) {
                int row = m0 + wr * 64 + m * 16 + lg * 4 + r;
                Cout[(size_t)row * N + col] = acc[m][n][r];
            }
        }
    }
}

// ---------------- MFMA flash attention, pipelined + swapped QK^T ----------------
__global__ __launch_bounds__(256) void fattn_kernel(const hbf16* __restrict__ qkv,
                                                    hbf16* __restrict__ y) {
    int qt = gridDim.x - 1 - blockIdx.x;  // heavy tiles first
    int h = blockIdx.y, b = blockIdx.z;
    int q0 = qt * 64;
    int tid = threadIdx.x;
    int l = tid & 63, w = tid >> 6;
    int li = l & 15, lg = l >> 4;
    constexpr int RS = 3 * Dc;
    constexpr int PST = 72;
    constexpr int VST = 72;
    constexpr float SCL = 0.125f * 1.44269504f;  // 1/sqrt(64) * log2(e)
    constexpr float THR = 11.5f;                 // defer-max threshold (log2 domain)

    __shared__ __bf16 K_lds[2][64 * 64];   // 2 x 8 KB, swizzled 16B slots
    __shared__ __bf16 Vt[2][64 * VST];     // 2 x 9 KB
    __shared__ __bf16 P_lds[4][16 * PST];  // 9 KB  (layout [q_local][j])

    bf16x8 qf[2];
    {
        const hbf16* qp = qkv + (size_t)(b * Tc + q0 + w * 16 + li) * RS + h * HDc + lg * 8;
        qf[0] = *(const bf16x8*)qp;
        qf[1] = *(const bf16x8*)(qp + 32);
    }

    int krow0 = tid >> 3, krow1 = 32 + (tid >> 3);
    int ks8 = tid & 7;
    int kc0 = (ks8 ^ (krow0 & 7)) * 8;
    int kc1 = (ks8 ^ (krow1 & 7)) * 8;
    const hbf16* kbase = qkv + (size_t)(b * Tc) * RS + Dc + h * HDc;

    int jp = (tid >> 3) * 2;
    int db = (tid & 7) * 8;
    const hbf16* vbase = qkv + (size_t)(b * Tc) * RS + 2 * Dc + h * HDc;

    int koff[2][4];
#pragma unroll
    for (int ks = 0; ks < 2; ks++)
#pragma unroll
        for (int n = 0; n < 4; n++)
            koff[ks][n] = (n * 16 + li) * 64 + (((ks * 4 + lg) ^ (li & 7)) * 8);

    f32x4 acc_o[4] = {};
    float m_run = -1e30f, l_run = 0.f;  // scalar: lane owns q = w*16+li

    bf16x8 vr0, vr1;
    {
        const hbf16* vp = vbase + (size_t)jp * RS + db;
        vr0 = *(const bf16x8*)vp;
        vr1 = *(const bf16x8*)(vp + RS);
        GLD16(kbase + (size_t)krow0 * RS + kc0, &K_lds[0][tid * 8]);
        GLD16(kbase + (size_t)krow1 * RS + kc1, &K_lds[0][2048 + tid * 8]);
    }
#pragma unroll
    for (int i = 0; i < 8; i++) {
        __bf16 a0 = vr0[i], a1 = vr1[i];
        unsigned u = (unsigned)*(unsigned short*)&a0 | ((unsigned)*(unsigned short*)&a1 << 16);
        *(unsigned*)&Vt[0][(db + i) * VST + jp] = u;
    }

    int cur = 0;
    for (int jt = 0; jt <= qt; jt++) {
        int jn0 = (jt < qt) ? (jt + 1) * 64 : 0;  // dummy wrap keeps vmcnt invariant

        asm volatile("s_waitcnt lgkmcnt(0)" ::: "memory");
        __builtin_amdgcn_s_barrier();

        {
            const hbf16* vp = vbase + (size_t)(jn0 + jp) * RS + db;
            vr0 = *(const bf16x8*)vp;
            vr1 = *(const bf16x8*)(vp + RS);
            GLD16(kbase + (size_t)(jn0 + krow0) * RS + kc0, &K_lds[cur ^ 1][tid * 8]);
            GLD16(kbase + (size_t)(jn0 + krow1) * RS + kc1, &K_lds[cur ^ 1][2048 + tid * 8]);
        }

        asm volatile("s_waitcnt vmcnt(4)" ::: "memory");
        __builtin_amdgcn_sched_barrier(0);

        // ---- S = K Q^T (swapped): s[n][r] = S[j=n*16+lg*4+r][q=li] ----
        f32x4 s[4] = {};
#pragma unroll
        for (int ks = 0; ks < 2; ks++)
#pragma unroll
            for (int n = 0; n < 4; n++) {
                bf16x8 kf = *(const bf16x8*)&K_lds[cur][koff[ks][n]];
                s[n] = __builtin_amdgcn_mfma_f32_16x16x32_bf16(kf, qf[ks], s[n], 0, 0, 0);
            }
#pragma unroll
        for (int n = 0; n < 4; n++)
#pragma unroll
            for (int r = 0; r < 4; r++) s[n][r] *= SCL;

        if (jt == qt) {
            int qloc = w * 16 + li;
#pragma unroll
            for (int n = 0; n < 4; n++)
#pragma unroll
                for (int r = 0; r < 4; r++)
                    if (n * 16 + lg * 4 + r > qloc) s[n][r] = -1e30f;
        }

        // ---- online softmax: all 16 values belong to q = w*16+li ----
        float mx = -1e30f;
#pragma unroll
        for (int n = 0; n < 4; n++)
#pragma unroll
            for (int r = 0; r < 4; r++) mx = fmaxf(mx, s[n][r]);
        mx = fmaxf(mx, __shfl_xor(mx, 16, 64));
        mx = fmaxf(mx, __shfl_xor(mx, 32, 64));

        bool dfr = __all(mx - m_run <= THR);
        float sclq = 1.f;
        if (!dfr) {
            float mnew = fmaxf(m_run, mx);
            sclq = exp2f(m_run - mnew);
            m_run = mnew;
        }
        float rs = 0.f;
#pragma unroll
        for (int n = 0; n < 4; n++)
#pragma unroll
            for (int r = 0; r < 4; r++) {
                float pv = exp2f(s[n][r] - m_run);
                s[n][r] = pv;
                rs += pv;
            }
        rs += __shfl_xor(rs, 16, 64);
        rs += __shfl_xor(rs, 32, 64);
        l_run = (dfr ? l_run : l_run * sclq) + rs;

        // ---- P -> LDS [q=li][j], packed pairs ----
#pragma unroll
        for (int n = 0; n < 4; n++)
#pragma unroll
            for (int r = 0; r < 4; r += 2) {
                __bf16 b0 = (__bf16)s[n][r], b1 = (__bf16)s[n][r + 1];
                unsigned u = (unsigned)*(unsigned short*)&b0 |
                             ((unsigned)*(unsigned short*)&b1 << 16);
                *(unsigned*)&P_lds[w][li * PST + n * 16 + lg * 4 + r] = u;
            }
        bf16x8 pa0 = *(const bf16x8*)&P_lds[w][li * PST + lg * 8];
        bf16x8 pa1 = *(const bf16x8*)&P_lds[w][li * PST + 32 + lg * 8];

        if (!dfr) {
#pragma unroll
            for (int r = 0; r < 4; r++) {
                float sr_ = __shfl(sclq, (l & 48) | (lg * 4 + r), 64);
#pragma unroll
                for (int n2 = 0; n2 < 4; n2++) acc_o[n2][r] *= sr_;
            }
        }

        // ---- PV from Vt[cur] ----
#pragma unroll
        for (int n2 = 0; n2 < 4; n2++) {
            bf16x8 vf0 = *(const bf16x8*)&Vt[cur][(n2 * 16 + li) * VST + lg * 8];
            bf16x8 vf1 = *(const bf16x8*)&Vt[cur][(n2 * 16 + li) * VST + 32 + lg * 8];
            acc_o[n2] = __builtin_amdgcn_mfma_f32_16x16x32_bf16(pa0, vf0, acc_o[n2], 0, 0, 0);
            acc_o[n2] = __builtin_amdgcn_mfma_f32_16x16x32_bf16(pa1, vf1, acc_o[n2], 0, 0, 0);
        }

        // ---- write V(jt+1) regs -> Vt[cur^1] ----
#pragma unroll
        for (int i = 0; i < 8; i++) {
            __bf16 a0 = vr0[i], a1 = vr1[i];
            unsigned u = (unsigned)*(unsigned short*)&a0 | ((unsigned)*(unsigned short*)&a1 << 16);
            *(unsigned*)&Vt[cur ^ 1][(db + i) * VST + jp] = u;
        }
        cur ^= 1;
    }

#pragma unroll
    for (int r = 0; r < 4; r++) {
        float lv = __shfl(l_run, (l & 48) | (lg * 4 + r), 64);
        float rcp = 1.f / lv;
        int row = q0 + w * 16 + lg * 4 + r;
#pragma unroll
        for (int n2 = 0; n2 < 4; n2++)
            y[(size_t)(b * Tc + row) * Dc + h * HDc + n2 * 16 + li] =
                __float2bfloat16(acc_o[n2][r] * rcp);
    }
}

extern "C" void kernel_launch(void* const* d_in, const int* in_sizes, int n_in,
                              void* d_out, int out_size, void* d_ws, size_t ws_size,
                              hipStream_t stream) {
    const int* x = (const int*)d_in[0];
    const float* wte = (const float*)d_in[1];
    const float* wpe = (const float*)d_in[2];
    const float* ln1w = (const float*)d_in[3];
    const float* ln1b = (const float*)d_in[4];
    const float* qkvw = (const float*)d_in[5];
    const float* qkvb = (const float*)d_in[6];
    const float* projw = (const float*)d_in[7];
    const float* projb = (const float*)d_in[8];
    const float* ln2w = (const float*)d_in[9];
    const float* ln2b = (const float*)d_in[10];
    const float* fcw = (const float*)d_in[11];
    const float* fcb = (const float*)d_in[12];
    const float* fcpw = (const float*)d_in[13];
    const float* fcpb = (const float*)d_in[14];
    const float* lnfw = (const float*)d_in[15];
    const float* lnfb = (const float*)d_in[16];

    char* p = (char*)d_ws;
    float* h = (float*)p;     p += (size_t)Mc * Dc * 4;      // f32 [M][D]
    hbf16* qkv = (hbf16*)p;   p += (size_t)Mc * 3 * Dc * 2;  // bf16 [M][3D]
    hbf16* a = (hbf16*)p;     p += (size_t)Mc * Dc * 2;      // bf16 [M][D]
    hbf16* y = (hbf16*)p;     p += (size_t)Mc * Dc * 2;      // bf16 [M][D]
    hbf16* mlp = (hbf16*)p;   p += (size_t)Mc * 4 * Dc * 2;  // bf16 [M][4D]
    hbf16* wte_b = (hbf16*)p; p += (size_t)Vpad * Dc * 2;    // [50304][768]
    hbf16* wtr = (hbf16*)p;                                  // transposed weights
    size_t used = (size_t)((char*)wtr - (char*)d_ws);
    bool all_mode = (ws_size - used) >= (size_t)Lc * SZL * 2;

    embed_kernel<<<(Mc * Dc + 255) / 256, 256, 0, stream>>>(x, wte, wpe, h);
    convert_wte<<<((size_t)Vpad * Dc / 4 + 255) / 256, 256, 0, stream>>>(wte, wte_b);

    if (all_mode) {
        transpose4_kernel<<<dim3(6912, Lc), 256, 0, stream>>>(
            qkvw, projw, fcw, fcpw,
            wtr, wtr + SZ_Q, wtr + SZ_Q + SZ_P, wtr + SZ_Q + SZ_P + SZ_F);
    }

    for (int l = 0; l < Lc; l++) {
        hbf16* base = wtr + (all_mode ? (size_t)l * SZL : 0);
        hbf16* wq_t = base;
        hbf16* wp_t = base + SZ_Q;
        hbf16* wf_t = base + SZ_Q + SZ_P;
        hbf16* wfp_t = base + SZ_Q + SZ_P + SZ_F;
        if (!all_mode) {
            transpose4_kernel<<<dim3(6912, 1), 256, 0, stream>>>(
                qkvw + (size_t)l * SZ_Q, projw + (size_t)l * SZ_P,
                fcw + (size_t)l * SZ_F, fcpw + (size_t)l * SZ_FP,
                wq_t, wp_t, wf_t, wfp_t);
        }

        ln_kernel<<<Mc / 4, 256, 0, stream>>>(h, ln1w + (size_t)l * Dc, ln1b + (size_t)l * Dc, a);
        mm_kernel<0, true, 128><<<dim3(3 * Dc / 128, Mc / 128), 256, 0, stream>>>(
            a, wq_t, qkvb + (size_t)l * 3 * Dc, nullptr, qkv, Mc, 3 * Dc, Dc);
        fattn_kernel<<<dim3(Tc / 64, Hc, Bc), 256, 0, stream>>>(qkv, y);
        mm_kernel<1, false, 64><<<dim3(Dc / 64, Mc / 128), 256, 0, stream>>>(
            y, wp_t, projb + (size_t)l * Dc, h, h, Mc, Dc, Dc);
        ln_kernel<<<Mc / 4, 256, 0, stream>>>(h, ln2w + (size_t)l * Dc, ln2b + (size_t)l * Dc, a);
        mm_kernel<2, true, 128><<<dim3(4 * Dc / 128, Mc / 128), 256, 0, stream>>>(
            a, wf_t, fcb + (size_t)l * 4 * Dc, nullptr, mlp, Mc, 4 * Dc, Dc);
        mm_kernel<1, false, 64><<<dim3(Dc / 64, Mc / 128), 256, 0, stream>>>(
            mlp, wfp_t, fcpb + (size_t)l * Dc, h, h, Mc, Dc, 4 * Dc);
    }

    ln_kernel<<<Mc / 4, 256, 0, stream>>>(h, lnfw, lnfb, a);
    mm2_kernel<<<dim3(Vpad / 128, Mc / 256), 512, 0, stream>>>(
        a, wte_b, (float*)d_out, Mc, Vc, Dc);
}

// Round 15
// 2344.352 us; speedup vs baseline: 1.2011x; 1.0113x over previous
//
#include <hip/hip_runtime.h>
#include <hip/hip_bf16.h>

typedef __hip_bfloat16 hbf16;
using bf16x8 = __attribute__((ext_vector_type(8))) __bf16;
using f32x4 = __attribute__((ext_vector_type(4))) float;

// GPT-2 small: L=12 H=12 D=768 V=50257 T=1024 B=2, HD=64
constexpr int Lc = 12, Hc = 12, Dc = 768, Vc = 50257, Tc = 1024, Bc = 2, HDc = 64;
constexpr int Mc = Bc * Tc;  // 2048 rows
constexpr int Vpad = 50304;  // 393*128, zero-padded vocab

// transposed-weight slot sizes (elements)
constexpr size_t SZ_Q = (size_t)3 * Dc * Dc;   // [2304][768]
constexpr size_t SZ_P = (size_t)Dc * Dc;       // [768][768]
constexpr size_t SZ_F = (size_t)4 * Dc * Dc;   // [3072][768]
constexpr size_t SZ_FP = (size_t)4 * Dc * Dc;  // [768][3072]
constexpr size_t SZL = SZ_Q + SZ_P + SZ_F + SZ_FP;

#define GLD16(gp, lp)                                               \
    __builtin_amdgcn_global_load_lds(                               \
        (__attribute__((address_space(1))) void*)(void*)(gp),       \
        (__attribute__((address_space(3))) void*)(void*)(lp), 16, 0, 0)

// ---------------- embedding: h = wte[x] + wpe[t] (f32) ----------------
__global__ void embed_kernel(const int* __restrict__ x, const float* __restrict__ wte,
                             const float* __restrict__ wpe, float* __restrict__ h) {
    int i = blockIdx.x * blockDim.x + threadIdx.x;
    if (i >= Mc * Dc) return;
    int m = i / Dc, d = i - m * Dc;
    int t = m % Tc;
    int tok = x[m];
    h[i] = wte[(size_t)tok * Dc + d] + wpe[(size_t)t * Dc + d];
}

// ---------------- layernorm: one wave per row, shuffle reduce, f32 in -> bf16 out --
__global__ __launch_bounds__(256) void ln_kernel(const float* __restrict__ x,
                                                 const float* __restrict__ w,
                                                 const float* __restrict__ b,
                                                 hbf16* __restrict__ out) {
    int wv = threadIdx.x >> 6, lane = threadIdx.x & 63;
    int row = blockIdx.x * 4 + wv;
    const float4* xr = (const float4*)(x + (size_t)row * Dc);
    float4 v[3];
    float s = 0.f, sq = 0.f;
#pragma unroll
    for (int i = 0; i < 3; i++) {
        v[i] = xr[i * 64 + lane];
        s += v[i].x + v[i].y + v[i].z + v[i].w;
        sq += v[i].x * v[i].x + v[i].y * v[i].y + v[i].z * v[i].z + v[i].w * v[i].w;
    }
#pragma unroll
    for (int o = 32; o > 0; o >>= 1) {
        s += __shfl_xor(s, o, 64);
        sq += __shfl_xor(sq, o, 64);
    }
    float mean = s * (1.f / Dc);
    float var = sq * (1.f / Dc) - mean * mean;
    float rstd = rsqrtf(var + 1e-5f);
#pragma unroll
    for (int i = 0; i < 3; i++) {
        int c = (i * 64 + lane) * 4;
        float4 wv4 = *(const float4*)(w + c);
        float4 bv4 = *(const float4*)(b + c);
        float r0 = (v[i].x - mean) * rstd * wv4.x + bv4.x;
        float r1 = (v[i].y - mean) * rstd * wv4.y + bv4.y;
        float r2 = (v[i].z - mean) * rstd * wv4.z + bv4.z;
        float r3 = (v[i].w - mean) * rstd * wv4.w + bv4.w;
        __bf16 q0 = (__bf16)r0, q1 = (__bf16)r1, q2 = (__bf16)r2, q3 = (__bf16)r3;
        ushort4 u;
        u.x = *(unsigned short*)&q0; u.y = *(unsigned short*)&q1;
        u.z = *(unsigned short*)&q2; u.w = *(unsigned short*)&q3;
        *(ushort4*)(out + (size_t)row * Dc + c) = u;
    }
}

// ---------------- weight transpose, grid (6912, nlayers) ----------------
__global__ __launch_bounds__(256) void transpose4_kernel(
    const float* __restrict__ s0, const float* __restrict__ s1,
    const float* __restrict__ s2, const float* __restrict__ s3,
    hbf16* __restrict__ d0, hbf16* __restrict__ d1,
    hbf16* __restrict__ d2, hbf16* __restrict__ d3) {
    int id = blockIdx.x;
    size_t lz = blockIdx.y;
    int bx, by, K, N;
    const float* W;
    hbf16* Wt;
    if (id < 1728)      { int t = id;        bx = t % 72; by = t / 72; K = 768;  N = 2304; W = s0 + lz * SZ_Q;  Wt = d0 + lz * SZL; }
    else if (id < 2304) { int t = id - 1728; bx = t % 24; by = t / 24; K = 768;  N = 768;  W = s1 + lz * SZ_P;  Wt = d1 + lz * SZL; }
    else if (id < 4608) { int t = id - 2304; bx = t % 96; by = t / 96; K = 768;  N = 3072; W = s2 + lz * SZ_F;  Wt = d2 + lz * SZL; }
    else                { int t = id - 4608; bx = t % 24; by = t / 24; K = 3072; N = 768;  W = s3 + lz * SZ_FP; Wt = d3 + lz * SZL; }

    __shared__ float tile[32][33];
    int n0 = bx * 32, k0 = by * 32;
    int tx = threadIdx.x & 31, ty = threadIdx.x >> 5;  // 32x8
#pragma unroll
    for (int i = 0; i < 4; i++) {
        int r = ty + i * 8;
        tile[r][tx] = W[(size_t)(k0 + r) * N + n0 + tx];
    }
    __syncthreads();
#pragma unroll
    for (int i = 0; i < 4; i++) {
        int r = ty + i * 8;
        Wt[(size_t)(n0 + r) * K + k0 + tx] = __float2bfloat16(tile[tx][r]);
    }
}

// ---------------- wte f32 [V][D] -> bf16 [Vpad][D] (zero pad) ----------------
__global__ void convert_wte(const float* __restrict__ wte, hbf16* __restrict__ out) {
    size_t i4 = ((size_t)blockIdx.x * 256 + threadIdx.x) * 4;
    if (i4 >= (size_t)Vpad * Dc) return;
    if (i4 < (size_t)Vc * Dc) {
#pragma unroll
        for (int j = 0; j < 4; j++) out[i4 + j] = __float2bfloat16(wte[i4 + j]);
    } else {
#pragma unroll
        for (int j = 0; j < 4; j++) out[i4 + j] = __float2bfloat16(0.f);
    }
}

// ---------------- MFMA GEMM 128xBN, BK=64, dbuf + counted vmcnt ----------
// 2 raw barriers/iter, never vmcnt(0) mid-loop: next tile's loads stay in flight.
// EPI: 0 = +bias, 1 = +bias +f32 residual, 2 = +bias + tanh-GELU
template <int EPI, bool OUTBF, int BN>
__global__ __launch_bounds__(256) void mm_kernel(const hbf16* __restrict__ A,
                                                 const hbf16* __restrict__ Bt,
                                                 const float* __restrict__ bias,
                                                 const float* __restrict__ resid,
                                                 void* __restrict__ Cout,
                                                 int M, int N, int K) {
    constexpr int NF = BN / 32;   // n-frags per wave
    constexpr int NBI = BN / 32;  // B stage issues (32 rows each)
    __shared__ __bf16 As[2][128 * 64];  // 2 x 16 KB
    __shared__ __bf16 Bs[2][BN * 64];   // 2 x 16/8 KB
    int tid = threadIdx.x;
    int l = tid & 63, w = tid >> 6;
    int wr = w >> 1, wc = w & 1;

    // XCD swizzle: hw dispatch order is x-fastest; chunk per XCD, m fastest.
    int gx = gridDim.x, gy = gridDim.y;
    int nwg = gx * gy;
    int hwlin = blockIdx.y * gx + blockIdx.x;
    int wk = (hwlin & 7) * (nwg >> 3) + (hwlin >> 3);
    int m0 = (wk % gy) * 128;
    int n0 = (wk / gy) * BN;

    // staging: 32 rows/issue; row = j*32 + (tid>>3), 16B slot sc = tid&7
    int sr = tid >> 3, sc = tid & 7;
    int scs = (sc ^ (sr & 7)) * 8;
    const hbf16* pA[4];
#pragma unroll
    for (int j = 0; j < 4; j++) pA[j] = A + (size_t)(m0 + j * 32 + sr) * K + scs;
    const hbf16* pB[NBI];
#pragma unroll
    for (int j = 0; j < NBI; j++) pB[j] = Bt + (size_t)(n0 + j * 32 + sr) * K + scs;

    auto stage = [&](int bi, int ko) {
#pragma unroll
        for (int j = 0; j < 4; j++) GLD16(pA[j] + ko, &As[bi][j * 2048 + tid * 8]);
#pragma unroll
        for (int j = 0; j < NBI; j++) GLD16(pB[j] + ko, &Bs[bi][j * 2048 + tid * 8]);
    };

    int lr = l & 15, lg = l >> 4;
    int aoff[2][4], boff[2][NF];
#pragma unroll
    for (int kk = 0; kk < 2; kk++) {
        int ks = ((kk * 4 + lg) ^ (lr & 7)) * 8;
#pragma unroll
        for (int m = 0; m < 4; m++) aoff[kk][m] = (wr * 64 + m * 16 + lr) * 64 + ks;
#pragma unroll
        for (int n = 0; n < NF; n++) boff[kk][n] = (wc * (BN / 2) + n * 16 + lr) * 64 + ks;
    }

    f32x4 acc[4][NF] = {};
    int nk = K / 64;

    stage(0, 0);
    for (int t = 0; t < nk; ++t) {
        int cur = t & 1;
        if (t + 1 < nk) {
            stage(cur ^ 1, (t + 1) * 64);
            if constexpr (BN == 128)
                asm volatile("s_waitcnt vmcnt(8)" ::: "memory");
            else
                asm volatile("s_waitcnt vmcnt(6)" ::: "memory");
        } else {
            asm volatile("s_waitcnt vmcnt(0)" ::: "memory");
        }
        __builtin_amdgcn_sched_barrier(0);
        __builtin_amdgcn_s_barrier();
        __builtin_amdgcn_sched_barrier(0);
#pragma unroll
        for (int kk = 0; kk < 2; kk++) {
            bf16x8 af[4], bfr[NF];
#pragma unroll
            for (int m = 0; m < 4; m++) af[m] = *(const bf16x8*)&As[cur][aoff[kk][m]];
#pragma unroll
            for (int n = 0; n < NF; n++) bfr[n] = *(const bf16x8*)&Bs[cur][boff[kk][n]];
#pragma unroll
            for (int m = 0; m < 4; m++)
#pragma unroll
                for (int n = 0; n < NF; n++)
                    acc[m][n] = __builtin_amdgcn_mfma_f32_16x16x32_bf16(af[m], bfr[n], acc[m][n], 0, 0, 0);
        }
        __builtin_amdgcn_s_barrier();
    }

#pragma unroll
    for (int n = 0; n < NF; n++) {
        int col = n0 + wc * (BN / 2) + n * 16 + lr;
        bool cok = col < N;
        float bv = (bias && cok) ? bias[col] : 0.f;
#pragma unroll
        for (int m = 0; m < 4; m++) {
#pragma unroll
            for (int r = 0; r < 4; r++) {
                int row = m0 + wr * 64 + m * 16 + lg * 4 + r;
                if (!cok) continue;
                float v = acc[m][n][r] + bv;
                if (EPI == 1) v += resid[(size_t)row * N + col];
                if (EPI == 2) {
                    float x3 = v * v * v;
                    v = 0.5f * v * (1.f + tanhf(0.7978845608028654f * (v + 0.044715f * x3)));
                }
                if (OUTBF)
                    ((hbf16*)Cout)[(size_t)row * N + col] = __float2bfloat16(v);
                else
                    ((float*)Cout)[(size_t)row * N + col] = v;
            }
        }
    }
}

// ---------------- MFMA GEMM 256x128, 512 threads, BK=64 dbuf + counted vmcnt ------
__global__ __launch_bounds__(512) void mm2_kernel(const hbf16* __restrict__ A,
                                                  const hbf16* __restrict__ Bt,
                                                  float* __restrict__ Cout,
                                                  int M, int N, int K) {
    __shared__ __bf16 As[2][256 * 64];  // 2 x 32 KB
    __shared__ __bf16 Bs[2][128 * 64];  // 2 x 16 KB
    int tid = threadIdx.x;
    int l = tid & 63, w = tid >> 6;
    int wr = w >> 1, wc = w & 1;

    int gx = gridDim.x, gy = gridDim.y;  // gy = 8
    int nwg = gx * gy;
    int hwlin = blockIdx.y * gx + blockIdx.x;
    int wk = (hwlin & 7) * (nwg >> 3) + (hwlin >> 3);
    int m0 = (wk & 7) * 256;
    int n0 = (wk >> 3) * 128;

    // staging: 64 rows/issue (512 thr x 16B = 8KB); row = j*64 + (tid>>3)
    int sr = tid >> 3, sc = tid & 7;
    int scs = (sc ^ (sr & 7)) * 8;
    const hbf16* pA[4];
#pragma unroll
    for (int j = 0; j < 4; j++) pA[j] = A + (size_t)(m0 + j * 64 + sr) * K + scs;
    const hbf16* pB[2];
#pragma unroll
    for (int j = 0; j < 2; j++) pB[j] = Bt + (size_t)(n0 + j * 64 + sr) * K + scs;

    auto stage = [&](int bi, int ko) {
#pragma unroll
        for (int j = 0; j < 4; j++) GLD16(pA[j] + ko, &As[bi][j * 4096 + tid * 8]);
#pragma unroll
        for (int j = 0; j < 2; j++) GLD16(pB[j] + ko, &Bs[bi][j * 4096 + tid * 8]);
    };

    int lr = l & 15, lg = l >> 4;
    int aoff[2][4], boff[2][4];
#pragma unroll
    for (int kk = 0; kk < 2; kk++) {
        int ks = ((kk * 4 + lg) ^ (lr & 7)) * 8;
#pragma unroll
        for (int m = 0; m < 4; m++) aoff[kk][m] = (wr * 64 + m * 16 + lr) * 64 + ks;
#pragma unroll
        for (int n = 0; n < 4; n++) boff[kk][n] = (wc * 64 + n * 16 + lr) * 64 + ks;
    }

    f32x4 acc[4][4] = {};
    int nk = K / 64;

    stage(0, 0);
    for (int t = 0; t < nk; ++t) {
        int cur = t & 1;
        if (t + 1 < nk) {
            stage(cur ^ 1, (t + 1) * 64);
            asm volatile("s_waitcnt vmcnt(6)" ::: "memory");
        } else {
            asm volatile("s_waitcnt vmcnt(0)" ::: "memory");
        }
        __builtin_amdgcn_sched_barrier(0);
        __builtin_amdgcn_s_barrier();
        __builtin_amdgcn_sched_barrier(0);
#pragma unroll
        for (int kk = 0; kk < 2; kk++) {
            bf16x8 af[4], bfr[4];
#pragma unroll
            for (int m = 0; m < 4; m++) af[m] = *(const bf16x8*)&As[cur][aoff[kk][m]];
#pragma unroll
            for (int n = 0; n < 4; n++) bfr[n] = *(const bf16x8*)&Bs[cur][boff[kk][n]];
#pragma unroll
            for (int m = 0; m < 4; m++)
#pragma unroll
                for (int n = 0; n < 4; n++)
                    acc[m][n] = __builtin_amdgcn_mfma_f32_16x16x32_bf16(af[m], bfr[n], acc[m][n], 0, 0, 0);
        }
        __builtin_amdgcn_s_barrier();
    }

#pragma unroll
    for (int n = 0; n < 4; n++) {
        int col = n0 + wc * 64 + n * 16 + lr;
        if (col >= N) continue;
#pragma unroll
        for (int m = 0; m < 4; m++) {
#pragma unroll
            for (int r = 0; r < 4; r++) {
                int row = m0 + wr * 64 + m * 16 + lg * 4 + r;
                Cout[(size_t)row * N + col] = acc[m][n][r];
            }
        }
    }
}

// ---------------- MFMA flash attention, pipelined + swapped QK^T ----------------
__global__ __launch_bounds__(256) void fattn_kernel(const hbf16* __restrict__ qkv,
                                                    hbf16* __restrict__ y) {
    int qt = gridDim.x - 1 - blockIdx.x;  // heavy tiles first
    int h = blockIdx.y, b = blockIdx.z;
    int q0 = qt * 64;
    int tid = threadIdx.x;
    int l = tid & 63, w = tid >> 6;
    int li = l & 15, lg = l >> 4;
    constexpr int RS = 3 * Dc;
    constexpr int PST = 72;
    constexpr int VST = 72;
    constexpr float SCL = 0.125f * 1.44269504f;  // 1/sqrt(64) * log2(e)
    constexpr float THR = 11.5f;                 // defer-max threshold (log2 domain)

    __shared__ __bf16 K_lds[2][64 * 64];   // 2 x 8 KB, swizzled 16B slots
    __shared__ __bf16 Vt[2][64 * VST];     // 2 x 9 KB
    __shared__ __bf16 P_lds[4][16 * PST];  // 9 KB  (layout [q_local][j])

    bf16x8 qf[2];
    {
        const hbf16* qp = qkv + (size_t)(b * Tc + q0 + w * 16 + li) * RS + h * HDc + lg * 8;
        qf[0] = *(const bf16x8*)qp;
        qf[1] = *(const bf16x8*)(qp + 32);
    }

    int krow0 = tid >> 3, krow1 = 32 + (tid >> 3);
    int ks8 = tid & 7;
    int kc0 = (ks8 ^ (krow0 & 7)) * 8;
    int kc1 = (ks8 ^ (krow1 & 7)) * 8;
    const hbf16* kbase = qkv + (size_t)(b * Tc) * RS + Dc + h * HDc;

    int jp = (tid >> 3) * 2;
    int db = (tid & 7) * 8;
    const hbf16* vbase = qkv + (size_t)(b * Tc) * RS + 2 * Dc + h * HDc;

    int koff[2][4];
#pragma unroll
    for (int ks = 0; ks < 2; ks++)
#pragma unroll
        for (int n = 0; n < 4; n++)
            koff[ks][n] = (n * 16 + li) * 64 + (((ks * 4 + lg) ^ (li & 7)) * 8);

    f32x4 acc_o[4] = {};
    float m_run = -1e30f, l_run = 0.f;  // scalar: lane owns q = w*16+li

    bf16x8 vr0, vr1;
    {
        const hbf16* vp = vbase + (size_t)jp * RS + db;
        vr0 = *(const bf16x8*)vp;
        vr1 = *(const bf16x8*)(vp + RS);
        GLD16(kbase + (size_t)krow0 * RS + kc0, &K_lds[0][tid * 8]);
        GLD16(kbase + (size_t)krow1 * RS + kc1, &K_lds[0][2048 + tid * 8]);
    }
#pragma unroll
    for (int i = 0; i < 8; i++) {
        __bf16 a0 = vr0[i], a1 = vr1[i];
        unsigned u = (unsigned)*(unsigned short*)&a0 | ((unsigned)*(unsigned short*)&a1 << 16);
        *(unsigned*)&Vt[0][(db + i) * VST + jp] = u;
    }

    int cur = 0;
    for (int jt = 0; jt <= qt; jt++) {
        int jn0 = (jt < qt) ? (jt + 1) * 64 : 0;  // dummy wrap keeps vmcnt invariant

        asm volatile("s_waitcnt lgkmcnt(0)" ::: "memory");
        __builtin_amdgcn_s_barrier();

        {
            const hbf16* vp = vbase + (size_t)(jn0 + jp) * RS + db;
            vr0 = *(const bf16x8*)vp;
            vr1 = *(const bf16x8*)(vp + RS);
            GLD16(kbase + (size_t)(jn0 + krow0) * RS + kc0, &K_lds[cur ^ 1][tid * 8]);
            GLD16(kbase + (size_t)(jn0 + krow1) * RS + kc1, &K_lds[cur ^ 1][2048 + tid * 8]);
        }

        asm volatile("s_waitcnt vmcnt(4)" ::: "memory");
        __builtin_amdgcn_sched_barrier(0);

        // ---- S = K Q^T (swapped): s[n][r] = S[j=n*16+lg*4+r][q=li] ----
        f32x4 s[4] = {};
#pragma unroll
        for (int ks = 0; ks < 2; ks++)
#pragma unroll
            for (int n = 0; n < 4; n++) {
                bf16x8 kf = *(const bf16x8*)&K_lds[cur][koff[ks][n]];
                s[n] = __builtin_amdgcn_mfma_f32_16x16x32_bf16(kf, qf[ks], s[n], 0, 0, 0);
            }
#pragma unroll
        for (int n = 0; n < 4; n++)
#pragma unroll
            for (int r = 0; r < 4; r++) s[n][r] *= SCL;

        if (jt == qt) {
            int qloc = w * 16 + li;
#pragma unroll
            for (int n = 0; n < 4; n++)
#pragma unroll
                for (int r = 0; r < 4; r++)
                    if (n * 16 + lg * 4 + r > qloc) s[n][r] = -1e30f;
        }

        // ---- online softmax: all 16 values belong to q = w*16+li ----
        float mx = -1e30f;
#pragma unroll
        for (int n = 0; n < 4; n++)
#pragma unroll
            for (int r = 0; r < 4; r++) mx = fmaxf(mx, s[n][r]);
        mx = fmaxf(mx, __shfl_xor(mx, 16, 64));
        mx = fmaxf(mx, __shfl_xor(mx, 32, 64));

        bool dfr = __all(mx - m_run <= THR);
        float sclq = 1.f;
        if (!dfr) {
            float mnew = fmaxf(m_run, mx);
            sclq = exp2f(m_run - mnew);
            m_run = mnew;
        }
        float rs = 0.f;
#pragma unroll
        for (int n = 0; n < 4; n++)
#pragma unroll
            for (int r = 0; r < 4; r++) {
                float pv = exp2f(s[n][r] - m_run);
                s[n][r] = pv;
                rs += pv;
            }
        rs += __shfl_xor(rs, 16, 64);
        rs += __shfl_xor(rs, 32, 64);
        l_run = (dfr ? l_run : l_run * sclq) + rs;

        // ---- P -> LDS [q=li][j], packed pairs ----
#pragma unroll
        for (int n = 0; n < 4; n++)
#pragma unroll
            for (int r = 0; r < 4; r += 2) {
                __bf16 b0 = (__bf16)s[n][r], b1 = (__bf16)s[n][r + 1];
                unsigned u = (unsigned)*(unsigned short*)&b0 |
                             ((unsigned)*(unsigned short*)&b1 << 16);
                *(unsigned*)&P_lds[w][li * PST + n * 16 + lg * 4 + r] = u;
            }
        bf16x8 pa0 = *(const bf16x8*)&P_lds[w][li * PST + lg * 8];
        bf16x8 pa1 = *(const bf16x8*)&P_lds[w][li * PST + 32 + lg * 8];

        if (!dfr) {
#pragma unroll
            for (int r = 0; r < 4; r++) {
                float sr_ = __shfl(sclq, (l & 48) | (lg * 4 + r), 64);
#pragma unroll
                for (int n2 = 0; n2 < 4; n2++) acc_o[n2][r] *= sr_;
            }
        }

        // ---- PV from Vt[cur] ----
#pragma unroll
        for (int n2 = 0; n2 < 4; n2++) {
            bf16x8 vf0 = *(const bf16x8*)&Vt[cur][(n2 * 16 + li) * VST + lg * 8];
            bf16x8 vf1 = *(const bf16x8*)&Vt[cur][(n2 * 16 + li) * VST + 32 + lg * 8];
            acc_o[n2] = __builtin_amdgcn_mfma_f32_16x16x32_bf16(pa0, vf0, acc_o[n2], 0, 0, 0);
            acc_o[n2] = __builtin_amdgcn_mfma_f32_16x16x32_bf16(pa1, vf1, acc_o[n2], 0, 0, 0);
        }

        // ---- write V(jt+1) regs -> Vt[cur^1] ----
#pragma unroll
        for (int i = 0; i < 8; i++) {
            __bf16 a0 = vr0[i], a1 = vr1[i];
            unsigned u = (unsigned)*(unsigned short*)&a0 | ((unsigned)*(unsigned short*)&a1 << 16);
            *(unsigned*)&Vt[cur ^ 1][(db + i) * VST + jp] = u;
        }
        cur ^= 1;
    }

#pragma unroll
    for (int r = 0; r < 4; r++) {
        float lv = __shfl(l_run, (l & 48) | (lg * 4 + r), 64);
        float rcp = 1.f / lv;
        int row = q0 + w * 16 + lg * 4 + r;
#pragma unroll
        for (int n2 = 0; n2 < 4; n2++)
            y[(size_t)(b * Tc + row) * Dc + h * HDc + n2 * 16 + li] =
                __float2bfloat16(acc_o[n2][r] * rcp);
    }
}

extern "C" void kernel_launch(void* const* d_in, const int* in_sizes, int n_in,
                              void* d_out, int out_size, void* d_ws, size_t ws_size,
                              hipStream_t stream) {
    const int* x = (const int*)d_in[0];
    const float* wte = (const float*)d_in[1];
    const float* wpe = (const float*)d_in[2];
    const float* ln1w = (const float*)d_in[3];
    const float* ln1b = (const float*)d_in[4];
    const float* qkvw = (const float*)d_in[5];
    const float* qkvb = (const float*)d_in[6];
    const float* projw = (const float*)d_in[7];
    const float* projb = (const float*)d_in[8];
    const float* ln2w = (const float*)d_in[9];
    const float* ln2b = (const float*)d_in[10];
    const float* fcw = (const float*)d_in[11];
    const float* fcb = (const float*)d_in[12];
    const float* fcpw = (const float*)d_in[13];
    const float* fcpb = (const float*)d_in[14];
    const float* lnfw = (const float*)d_in[15];
    const float* lnfb = (const float*)d_in[16];

    char* p = (char*)d_ws;
    float* h = (float*)p;     p += (size_t)Mc * Dc * 4;      // f32 [M][D]
    hbf16* qkv = (hbf16*)p;   p += (size_t)Mc * 3 * Dc * 2;  // bf16 [M][3D]
    hbf16* a = (hbf16*)p;     p += (size_t)Mc * Dc * 2;      // bf16 [M][D]
    hbf16* y = (hbf16*)p;     p += (size_t)Mc * Dc * 2;      // bf16 [M][D]
    hbf16* mlp = (hbf16*)p;   p += (size_t)Mc * 4 * Dc * 2;  // bf16 [M][4D]
    hbf16* wte_b = (hbf16*)p; p += (size_t)Vpad * Dc * 2;    // [50304][768]
    hbf16* wtr = (hbf16*)p;                                  // transposed weights
    size_t used = (size_t)((char*)wtr - (char*)d_ws);
    bool all_mode = (ws_size - used) >= (size_t)Lc * SZL * 2;

    embed_kernel<<<(Mc * Dc + 255) / 256, 256, 0, stream>>>(x, wte, wpe, h);
    convert_wte<<<((size_t)Vpad * Dc / 4 + 255) / 256, 256, 0, stream>>>(wte, wte_b);

    if (all_mode) {
        transpose4_kernel<<<dim3(6912, Lc), 256, 0, stream>>>(
            qkvw, projw, fcw, fcpw,
            wtr, wtr + SZ_Q, wtr + SZ_Q + SZ_P, wtr + SZ_Q + SZ_P + SZ_F);
    }

    for (int l = 0; l < Lc; l++) {
        hbf16* base = wtr + (all_mode ? (size_t)l * SZL : 0);
        hbf16* wq_t = base;
        hbf16* wp_t = base + SZ_Q;
        hbf16* wf_t = base + SZ_Q + SZ_P;
        hbf16* wfp_t = base + SZ_Q + SZ_P + SZ_F;
        if (!all_mode) {
            transpose4_kernel<<<dim3(6912, 1), 256, 0, stream>>>(
                qkvw + (size_t)l * SZ_Q, projw + (size_t)l * SZ_P,
                fcw + (size_t)l * SZ_F, fcpw + (size_t)l * SZ_FP,
                wq_t, wp_t, wf_t, wfp_t);
        }

        ln_kernel<<<Mc / 4, 256, 0, stream>>>(h, ln1w + (size_t)l * Dc, ln1b + (size_t)l * Dc, a);
        mm_kernel<0, true, 128><<<dim3(3 * Dc / 128, Mc / 128), 256, 0, stream>>>(
            a, wq_t, qkvb + (size_t)l * 3 * Dc, nullptr, qkv, Mc, 3 * Dc, Dc);
        fattn_kernel<<<dim3(Tc / 64, Hc, Bc), 256, 0, stream>>>(qkv, y);
        mm_kernel<1, false, 64><<<dim3(Dc / 64, Mc / 128), 256, 0, stream>>>(
            y, wp_t, projb + (size_t)l * Dc, h, h, Mc, Dc, Dc);
        ln_kernel<<<Mc / 4, 256, 0, stream>>>(h, ln2w + (size_t)l * Dc, ln2b + (size_t)l * Dc, a);
        mm_kernel<2, true, 128><<<dim3(4 * Dc / 128, Mc / 128), 256, 0, stream>>>(
            a, wf_t, fcb + (size_t)l * 4 * Dc, nullptr, mlp, Mc, 4 * Dc, Dc);
        mm_kernel<1, false, 64><<<dim3(Dc / 64, Mc / 128), 256, 0, stream>>>(
            mlp, wfp_t, fcpb + (size_t)l * Dc, h, h, Mc, Dc, 4 * Dc);
    }

    ln_kernel<<<Mc / 4, 256, 0, stream>>>(h, lnfw, lnfb, a);
    mm2_kernel<<<dim3(Vpad / 128, Mc / 256), 512, 0, stream>>>(
        a, wte_b, (float*)d_out, Mc, Vc, Dc);
}

// Round 16
// 2254.561 us; speedup vs baseline: 1.2490x; 1.0398x over previous
//
#include <hip/hip_runtime.h>
#include <hip/hip_bf16.h>

typedef __hip_bfloat16 hbf16;
using bf16x8 = __attribute__((ext_vector_type(8))) __bf16;
using f32x4 = __attribute__((ext_vector_type(4))) float;

// GPT-2 small: L=12 H=12 D=768 V=50257 T=1024 B=2, HD=64
constexpr int Lc = 12, Hc = 12, Dc = 768, Vc = 50257, Tc = 1024, Bc = 2, HDc = 64;
constexpr int Mc = Bc * Tc;  // 2048 rows
constexpr int Vpad = 50304;  // 393*128, zero-padded vocab

// transposed-weight slot sizes (elements)
constexpr size_t SZ_Q = (size_t)3 * Dc * Dc;   // [2304][768]
constexpr size_t SZ_P = (size_t)Dc * Dc;       // [768][768]
constexpr size_t SZ_F = (size_t)4 * Dc * Dc;   // [3072][768]
constexpr size_t SZ_FP = (size_t)4 * Dc * Dc;  // [768][3072]
constexpr size_t SZL = SZ_Q + SZ_P + SZ_F + SZ_FP;

#define GLD16(gp, lp)                                               \
    __builtin_amdgcn_global_load_lds(                               \
        (__attribute__((address_space(1))) void*)(void*)(gp),       \
        (__attribute__((address_space(3))) void*)(void*)(lp), 16, 0, 0)

// ---------------- embedding: h = wte[x] + wpe[t] (f32) ----------------
__global__ void embed_kernel(const int* __restrict__ x, const float* __restrict__ wte,
                             const float* __restrict__ wpe, float* __restrict__ h) {
    int i = blockIdx.x * blockDim.x + threadIdx.x;
    if (i >= Mc * Dc) return;
    int m = i / Dc, d = i - m * Dc;
    int t = m % Tc;
    int tok = x[m];
    h[i] = wte[(size_t)tok * Dc + d] + wpe[(size_t)t * Dc + d];
}

// ---------------- layernorm: one wave per row, shuffle reduce, f32 in -> bf16 out --
__global__ __launch_bounds__(256) void ln_kernel(const float* __restrict__ x,
                                                 const float* __restrict__ w,
                                                 const float* __restrict__ b,
                                                 hbf16* __restrict__ out) {
    int wv = threadIdx.x >> 6, lane = threadIdx.x & 63;
    int row = blockIdx.x * 4 + wv;
    const float4* xr = (const float4*)(x + (size_t)row * Dc);
    float4 v[3];
    float s = 0.f, sq = 0.f;
#pragma unroll
    for (int i = 0; i < 3; i++) {
        v[i] = xr[i * 64 + lane];
        s += v[i].x + v[i].y + v[i].z + v[i].w;
        sq += v[i].x * v[i].x + v[i].y * v[i].y + v[i].z * v[i].z + v[i].w * v[i].w;
    }
#pragma unroll
    for (int o = 32; o > 0; o >>= 1) {
        s += __shfl_xor(s, o, 64);
        sq += __shfl_xor(sq, o, 64);
    }
    float mean = s * (1.f / Dc);
    float var = sq * (1.f / Dc) - mean * mean;
    float rstd = rsqrtf(var + 1e-5f);
#pragma unroll
    for (int i = 0; i < 3; i++) {
        int c = (i * 64 + lane) * 4;
        float4 wv4 = *(const float4*)(w + c);
        float4 bv4 = *(const float4*)(b + c);
        float r0 = (v[i].x - mean) * rstd * wv4.x + bv4.x;
        float r1 = (v[i].y - mean) * rstd * wv4.y + bv4.y;
        float r2 = (v[i].z - mean) * rstd * wv4.z + bv4.z;
        float r3 = (v[i].w - mean) * rstd * wv4.w + bv4.w;
        __bf16 q0 = (__bf16)r0, q1 = (__bf16)r1, q2 = (__bf16)r2, q3 = (__bf16)r3;
        ushort4 u;
        u.x = *(unsigned short*)&q0; u.y = *(unsigned short*)&q1;
        u.z = *(unsigned short*)&q2; u.w = *(unsigned short*)&q3;
        *(ushort4*)(out + (size_t)row * Dc + c) = u;
    }
}

// ---------------- weight transpose, grid (6912, nlayers) ----------------
__global__ __launch_bounds__(256) void transpose4_kernel(
    const float* __restrict__ s0, const float* __restrict__ s1,
    const float* __restrict__ s2, const float* __restrict__ s3,
    hbf16* __restrict__ d0, hbf16* __restrict__ d1,
    hbf16* __restrict__ d2, hbf16* __restrict__ d3) {
    int id = blockIdx.x;
    size_t lz = blockIdx.y;
    int bx, by, K, N;
    const float* W;
    hbf16* Wt;
    if (id < 1728)      { int t = id;        bx = t % 72; by = t / 72; K = 768;  N = 2304; W = s0 + lz * SZ_Q;  Wt = d0 + lz * SZL; }
    else if (id < 2304) { int t = id - 1728; bx = t % 24; by = t / 24; K = 768;  N = 768;  W = s1 + lz * SZ_P;  Wt = d1 + lz * SZL; }
    else if (id < 4608) { int t = id - 2304; bx = t % 96; by = t / 96; K = 768;  N = 3072; W = s2 + lz * SZ_F;  Wt = d2 + lz * SZL; }
    else                { int t = id - 4608; bx = t % 24; by = t / 24; K = 3072; N = 768;  W = s3 + lz * SZ_FP; Wt = d3 + lz * SZL; }

    __shared__ float tile[32][33];
    int n0 = bx * 32, k0 = by * 32;
    int tx = threadIdx.x & 31, ty = threadIdx.x >> 5;  // 32x8
#pragma unroll
    for (int i = 0; i < 4; i++) {
        int r = ty + i * 8;
        tile[r][tx] = W[(size_t)(k0 + r) * N + n0 + tx];
    }
    __syncthreads();
#pragma unroll
    for (int i = 0; i < 4; i++) {
        int r = ty + i * 8;
        Wt[(size_t)(n0 + r) * K + k0 + tx] = __float2bfloat16(tile[tx][r]);
    }
}

// ---------------- wte f32 [V][D] -> bf16 [Vpad][D] (zero pad) ----------------
__global__ void convert_wte(const float* __restrict__ wte, hbf16* __restrict__ out) {
    size_t i4 = ((size_t)blockIdx.x * 256 + threadIdx.x) * 4;
    if (i4 >= (size_t)Vpad * Dc) return;
    if (i4 < (size_t)Vc * Dc) {
#pragma unroll
        for (int j = 0; j < 4; j++) out[i4 + j] = __float2bfloat16(wte[i4 + j]);
    } else {
#pragma unroll
        for (int j = 0; j < 4; j++) out[i4 + j] = __float2bfloat16(0.f);
    }
}

// ---------------- MFMA GEMM 128xBN, BK=64, dbuf + counted vmcnt (R15, kept) -------
// EPI: 0 = +bias, 1 = +bias +f32 residual, 2 = +bias + tanh-GELU
template <int EPI, bool OUTBF, int BN>
__global__ __launch_bounds__(256) void mm_kernel(const hbf16* __restrict__ A,
                                                 const hbf16* __restrict__ Bt,
                                                 const float* __restrict__ bias,
                                                 const float* __restrict__ resid,
                                                 void* __restrict__ Cout,
                                                 int M, int N, int K) {
    constexpr int NF = BN / 32;   // n-frags per wave
    constexpr int NBI = BN / 32;  // B stage issues (32 rows each)
    __shared__ __bf16 As[2][128 * 64];  // 2 x 16 KB
    __shared__ __bf16 Bs[2][BN * 64];   // 2 x 16/8 KB
    int tid = threadIdx.x;
    int l = tid & 63, w = tid >> 6;
    int wr = w >> 1, wc = w & 1;

    // XCD swizzle: hw dispatch order is x-fastest; chunk per XCD, m fastest.
    int gx = gridDim.x, gy = gridDim.y;
    int nwg = gx * gy;
    int hwlin = blockIdx.y * gx + blockIdx.x;
    int wk = (hwlin & 7) * (nwg >> 3) + (hwlin >> 3);
    int m0 = (wk % gy) * 128;
    int n0 = (wk / gy) * BN;

    // staging: 32 rows/issue; row = j*32 + (tid>>3), 16B slot sc = tid&7
    int sr = tid >> 3, sc = tid & 7;
    int scs = (sc ^ (sr & 7)) * 8;
    const hbf16* pA[4];
#pragma unroll
    for (int j = 0; j < 4; j++) pA[j] = A + (size_t)(m0 + j * 32 + sr) * K + scs;
    const hbf16* pB[NBI];
#pragma unroll
    for (int j = 0; j < NBI; j++) pB[j] = Bt + (size_t)(n0 + j * 32 + sr) * K + scs;

    auto stage = [&](int bi, int ko) {
#pragma unroll
        for (int j = 0; j < 4; j++) GLD16(pA[j] + ko, &As[bi][j * 2048 + tid * 8]);
#pragma unroll
        for (int j = 0; j < NBI; j++) GLD16(pB[j] + ko, &Bs[bi][j * 2048 + tid * 8]);
    };

    int lr = l & 15, lg = l >> 4;
    int aoff[2][4], boff[2][NF];
#pragma unroll
    for (int kk = 0; kk < 2; kk++) {
        int ks = ((kk * 4 + lg) ^ (lr & 7)) * 8;
#pragma unroll
        for (int m = 0; m < 4; m++) aoff[kk][m] = (wr * 64 + m * 16 + lr) * 64 + ks;
#pragma unroll
        for (int n = 0; n < NF; n++) boff[kk][n] = (wc * (BN / 2) + n * 16 + lr) * 64 + ks;
    }

    f32x4 acc[4][NF] = {};
    int nk = K / 64;

    stage(0, 0);
    for (int t = 0; t < nk; ++t) {
        int cur = t & 1;
        if (t + 1 < nk) {
            stage(cur ^ 1, (t + 1) * 64);
            if constexpr (BN == 128)
                asm volatile("s_waitcnt vmcnt(8)" ::: "memory");
            else
                asm volatile("s_waitcnt vmcnt(6)" ::: "memory");
        } else {
            asm volatile("s_waitcnt vmcnt(0)" ::: "memory");
        }
        __builtin_amdgcn_sched_barrier(0);
        __builtin_amdgcn_s_barrier();
        __builtin_amdgcn_sched_barrier(0);
#pragma unroll
        for (int kk = 0; kk < 2; kk++) {
            bf16x8 af[4], bfr[NF];
#pragma unroll
            for (int m = 0; m < 4; m++) af[m] = *(const bf16x8*)&As[cur][aoff[kk][m]];
#pragma unroll
            for (int n = 0; n < NF; n++) bfr[n] = *(const bf16x8*)&Bs[cur][boff[kk][n]];
#pragma unroll
            for (int m = 0; m < 4; m++)
#pragma unroll
                for (int n = 0; n < NF; n++)
                    acc[m][n] = __builtin_amdgcn_mfma_f32_16x16x32_bf16(af[m], bfr[n], acc[m][n], 0, 0, 0);
        }
        __builtin_amdgcn_s_barrier();
    }

#pragma unroll
    for (int n = 0; n < NF; n++) {
        int col = n0 + wc * (BN / 2) + n * 16 + lr;
        bool cok = col < N;
        float bv = (bias && cok) ? bias[col] : 0.f;
#pragma unroll
        for (int m = 0; m < 4; m++) {
#pragma unroll
            for (int r = 0; r < 4; r++) {
                int row = m0 + wr * 64 + m * 16 + lg * 4 + r;
                if (!cok) continue;
                float v = acc[m][n][r] + bv;
                if (EPI == 1) v += resid[(size_t)row * N + col];
                if (EPI == 2) {
                    float x3 = v * v * v;
                    v = 0.5f * v * (1.f + tanhf(0.7978845608028654f * (v + 0.044715f * x3)));
                }
                if (OUTBF)
                    ((hbf16*)Cout)[(size_t)row * N + col] = __float2bfloat16(v);
                else
                    ((float*)Cout)[(size_t)row * N + col] = v;
            }
        }
    }
}

// ---------------- MFMA GEMM 256x128, 512 threads, BK=64 single-buffer (R14) -------
// 48 KB LDS (2 blocks/CU); 12 K-steps; slot^(row&7) -> 0 bank conflicts.
__global__ __launch_bounds__(512) void mm2_kernel(const hbf16* __restrict__ A,
                                                  const hbf16* __restrict__ Bt,
                                                  float* __restrict__ Cout,
                                                  int M, int N, int K) {
    __shared__ __bf16 As[256 * 64];  // 32 KB
    __shared__ __bf16 Bs[128 * 64];  // 16 KB
    int tid = threadIdx.x;
    int l = tid & 63, w = tid >> 6;
    int wr = w >> 1, wc = w & 1;

    int gx = gridDim.x, gy = gridDim.y;  // gy = 8
    int nwg = gx * gy;
    int hwlin = blockIdx.y * gx + blockIdx.x;
    int wk = (hwlin & 7) * (nwg >> 3) + (hwlin >> 3);
    int m0 = (wk & 7) * 256;
    int n0 = (wk >> 3) * 128;

    // staging: 64 rows/issue (512 thr x 16B = 8KB); row = j*64 + (tid>>3)
    int sr = tid >> 3, sc = tid & 7;
    int scs = (sc ^ (sr & 7)) * 8;
    const hbf16* pA[4];
    __bf16* lA[4];
#pragma unroll
    for (int j = 0; j < 4; j++) {
        pA[j] = A + (size_t)(m0 + j * 64 + sr) * K + scs;
        lA[j] = As + j * 4096 + tid * 8;
    }
    const hbf16* pB[2];
    __bf16* lB[2];
#pragma unroll
    for (int j = 0; j < 2; j++) {
        pB[j] = Bt + (size_t)(n0 + j * 64 + sr) * K + scs;
        lB[j] = Bs + j * 4096 + tid * 8;
    }

    int lr = l & 15, lg = l >> 4;
    int aoff[2][4], boff[2][4];
#pragma unroll
    for (int kk = 0; kk < 2; kk++) {
        int ks = ((kk * 4 + lg) ^ (lr & 7)) * 8;
#pragma unroll
        for (int m = 0; m < 4; m++) aoff[kk][m] = (wr * 64 + m * 16 + lr) * 64 + ks;
#pragma unroll
        for (int n = 0; n < 4; n++) boff[kk][n] = (wc * 64 + n * 16 + lr) * 64 + ks;
    }

    f32x4 acc[4][4] = {};

    for (int k0 = 0; k0 < K; k0 += 64) {
#pragma unroll
        for (int j = 0; j < 4; j++) {
            GLD16(pA[j], lA[j]);
            pA[j] += 64;
        }
#pragma unroll
        for (int j = 0; j < 2; j++) {
            GLD16(pB[j], lB[j]);
            pB[j] += 64;
        }
        __syncthreads();
#pragma unroll
        for (int kk = 0; kk < 2; kk++) {
            bf16x8 af[4], bfr[4];
#pragma unroll
            for (int m = 0; m < 4; m++) af[m] = *(const bf16x8*)&As[aoff[kk][m]];
#pragma unroll
            for (int n = 0; n < 4; n++) bfr[n] = *(const bf16x8*)&Bs[boff[kk][n]];
#pragma unroll
            for (int m = 0; m < 4; m++)
#pragma unroll
                for (int n = 0; n < 4; n++)
                    acc[m][n] = __builtin_amdgcn_mfma_f32_16x16x32_bf16(af[m], bfr[n], acc[m][n], 0, 0, 0);
        }
        __syncthreads();
    }

#pragma unroll
    for (int n = 0; n < 4; n++) {
        int col = n0 + wc * 64 + n * 16 + lr;
        if (col >= N) continue;
#pragma unroll
        for (int m = 0; m < 4; m++) {
#pragma unroll
            for (int r = 0; r < 4; r++) {
                int row = m0 + wr * 64 + m * 16 + lg * 4 + r;
                Cout[(size_t)row * N + col] = acc[m][n][r];
            }
        }
    }
}

// ---------------- MFMA flash attention, pipelined + swapped QK^T ----------------
__global__ __launch_bounds__(256) void fattn_kernel(const hbf16* __restrict__ qkv,
                                                    hbf16* __restrict__ y) {
    int qt = gridDim.x - 1 - blockIdx.x;  // heavy tiles first
    int h = blockIdx.y, b = blockIdx.z;
    int q0 = qt * 64;
    int tid = threadIdx.x;
    int l = tid & 63, w = tid >> 6;
    int li = l & 15, lg = l >> 4;
    constexpr int RS = 3 * Dc;
    constexpr int PST = 72;
    constexpr int VST = 72;
    constexpr float SCL = 0.125f * 1.44269504f;  // 1/sqrt(64) * log2(e)
    constexpr float THR = 11.5f;                 // defer-max threshold (log2 domain)

    __shared__ __bf16 K_lds[2][64 * 64];   // 2 x 8 KB, swizzled 16B slots
    __shared__ __bf16 Vt[2][64 * VST];     // 2 x 9 KB
    __shared__ __bf16 P_lds[4][16 * PST];  // 9 KB  (layout [q_local][j])

    bf16x8 qf[2];
    {
        const hbf16* qp = qkv + (size_t)(b * Tc + q0 + w * 16 + li) * RS + h * HDc + lg * 8;
        qf[0] = *(const bf16x8*)qp;
        qf[1] = *(const bf16x8*)(qp + 32);
    }

    int krow0 = tid >> 3, krow1 = 32 + (tid >> 3);
    int ks8 = tid & 7;
    int kc0 = (ks8 ^ (krow0 & 7)) * 8;
    int kc1 = (ks8 ^ (krow1 & 7)) * 8;
    const hbf16* kbase = qkv + (size_t)(b * Tc) * RS + Dc + h * HDc;

    int jp = (tid >> 3) * 2;
    int db = (tid & 7) * 8;
    const hbf16* vbase = qkv + (size_t)(b * Tc) * RS + 2 * Dc + h * HDc;

    int koff[2][4];
#pragma unroll
    for (int ks = 0; ks < 2; ks++)
#pragma unroll
        for (int n = 0; n < 4; n++)
            koff[ks][n] = (n * 16 + li) * 64 + (((ks * 4 + lg) ^ (li & 7)) * 8);

    f32x4 acc_o[4] = {};
    float m_run = -1e30f, l_run = 0.f;  // scalar: lane owns q = w*16+li

    bf16x8 vr0, vr1;
    {
        const hbf16* vp = vbase + (size_t)jp * RS + db;
        vr0 = *(const bf16x8*)vp;
        vr1 = *(const bf16x8*)(vp + RS);
        GLD16(kbase + (size_t)krow0 * RS + kc0, &K_lds[0][tid * 8]);
        GLD16(kbase + (size_t)krow1 * RS + kc1, &K_lds[0][2048 + tid * 8]);
    }
#pragma unroll
    for (int i = 0; i < 8; i++) {
        __bf16 a0 = vr0[i], a1 = vr1[i];
        unsigned u = (unsigned)*(unsigned short*)&a0 | ((unsigned)*(unsigned short*)&a1 << 16);
        *(unsigned*)&Vt[0][(db + i) * VST + jp] = u;
    }

    int cur = 0;
    for (int jt = 0; jt <= qt; jt++) {
        int jn0 = (jt < qt) ? (jt + 1) * 64 : 0;  // dummy wrap keeps vmcnt invariant

        asm volatile("s_waitcnt lgkmcnt(0)" ::: "memory");
        __builtin_amdgcn_s_barrier();

        {
            const hbf16* vp = vbase + (size_t)(jn0 + jp) * RS + db;
            vr0 = *(const bf16x8*)vp;
            vr1 = *(const bf16x8*)(vp + RS);
            GLD16(kbase + (size_t)(jn0 + krow0) * RS + kc0, &K_lds[cur ^ 1][tid * 8]);
            GLD16(kbase + (size_t)(jn0 + krow1) * RS + kc1, &K_lds[cur ^ 1][2048 + tid * 8]);
        }

        asm volatile("s_waitcnt vmcnt(4)" ::: "memory");
        __builtin_amdgcn_sched_barrier(0);

        // ---- S = K Q^T (swapped): s[n][r] = S[j=n*16+lg*4+r][q=li] ----
        f32x4 s[4] = {};
#pragma unroll
        for (int ks = 0; ks < 2; ks++)
#pragma unroll
            for (int n = 0; n < 4; n++) {
                bf16x8 kf = *(const bf16x8*)&K_lds[cur][koff[ks][n]];
                s[n] = __builtin_amdgcn_mfma_f32_16x16x32_bf16(kf, qf[ks], s[n], 0, 0, 0);
            }
#pragma unroll
        for (int n = 0; n < 4; n++)
#pragma unroll
            for (int r = 0; r < 4; r++) s[n][r] *= SCL;

        if (jt == qt) {
            int qloc = w * 16 + li;
#pragma unroll
            for (int n = 0; n < 4; n++)
#pragma unroll
                for (int r = 0; r < 4; r++)
                    if (n * 16 + lg * 4 + r > qloc) s[n][r] = -1e30f;
        }

        // ---- online softmax: all 16 values belong to q = w*16+li ----
        float mx = -1e30f;
#pragma unroll
        for (int n = 0; n < 4; n++)
#pragma unroll
            for (int r = 0; r < 4; r++) mx = fmaxf(mx, s[n][r]);
        mx = fmaxf(mx, __shfl_xor(mx, 16, 64));
        mx = fmaxf(mx, __shfl_xor(mx, 32, 64));

        bool dfr = __all(mx - m_run <= THR);
        float sclq = 1.f;
        if (!dfr) {
            float mnew = fmaxf(m_run, mx);
            sclq = exp2f(m_run - mnew);
            m_run = mnew;
        }
        float rs = 0.f;
#pragma unroll
        for (int n = 0; n < 4; n++)
#pragma unroll
            for (int r = 0; r < 4; r++) {
                float pv = exp2f(s[n][r] - m_run);
                s[n][r] = pv;
                rs += pv;
            }
        rs += __shfl_xor(rs, 16, 64);
        rs += __shfl_xor(rs, 32, 64);
        l_run = (dfr ? l_run : l_run * sclq) + rs;

        // ---- P -> LDS [q=li][j], packed pairs ----
#pragma unroll
        for (int n = 0; n < 4; n++)
#pragma unroll
            for (int r = 0; r < 4; r += 2) {
                __bf16 b0 = (__bf16)s[n][r], b1 = (__bf16)s[n][r + 1];
                unsigned u = (unsigned)*(unsigned short*)&b0 |
                             ((unsigned)*(unsigned short*)&b1 << 16);
                *(unsigned*)&P_lds[w][li * PST + n * 16 + lg * 4 + r] = u;
            }
        bf16x8 pa0 = *(const bf16x8*)&P_lds[w][li * PST + lg * 8];
        bf16x8 pa1 = *(const bf16x8*)&P_lds[w][li * PST + 32 + lg * 8];

        if (!dfr) {
#pragma unroll
            for (int r = 0; r < 4; r++) {
                float sr_ = __shfl(sclq, (l & 48) | (lg * 4 + r), 64);
#pragma unroll
                for (int n2 = 0; n2 < 4; n2++) acc_o[n2][r] *= sr_;
            }
        }

        // ---- PV from Vt[cur] ----
#pragma unroll
        for (int n2 = 0; n2 < 4; n2++) {
            bf16x8 vf0 = *(const bf16x8*)&Vt[cur][(n2 * 16 + li) * VST + lg * 8];
            bf16x8 vf1 = *(const bf16x8*)&Vt[cur][(n2 * 16 + li) * VST + 32 + lg * 8];
            acc_o[n2] = __builtin_amdgcn_mfma_f32_16x16x32_bf16(pa0, vf0, acc_o[n2], 0, 0, 0);
            acc_o[n2] = __builtin_amdgcn_mfma_f32_16x16x32_bf16(pa1, vf1, acc_o[n2], 0, 0, 0);
        }

        // ---- write V(jt+1) regs -> Vt[cur^1] ----
#pragma unroll
        for (int i = 0; i < 8; i++) {
            __bf16 a0 = vr0[i], a1 = vr1[i];
            unsigned u = (unsigned)*(unsigned short*)&a0 | ((unsigned)*(unsigned short*)&a1 << 16);
            *(unsigned*)&Vt[cur ^ 1][(db + i) * VST + jp] = u;
        }
        cur ^= 1;
    }

#pragma unroll
    for (int r = 0; r < 4; r++) {
        float lv = __shfl(l_run, (l & 48) | (lg * 4 + r), 64);
        float rcp = 1.f / lv;
        int row = q0 + w * 16 + lg * 4 + r;
#pragma unroll
        for (int n2 = 0; n2 < 4; n2++)
            y[(size_t)(b * Tc + row) * Dc + h * HDc + n2 * 16 + li] =
                __float2bfloat16(acc_o[n2][r] * rcp);
    }
}

extern "C" void kernel_launch(void* const* d_in, const int* in_sizes, int n_in,
                              void* d_out, int out_size, void* d_ws, size_t ws_size,
                              hipStream_t stream) {
    const int* x = (const int*)d_in[0];
    const float* wte = (const float*)d_in[1];
    const float* wpe = (const float*)d_in[2];
    const float* ln1w = (const float*)d_in[3];
    const float* ln1b = (const float*)d_in[4];
    const float* qkvw = (const float*)d_in[5];
    const float* qkvb = (const float*)d_in[6];
    const float* projw = (const float*)d_in[7];
    const float* projb = (const float*)d_in[8];
    const float* ln2w = (const float*)d_in[9];
    const float* ln2b = (const float*)d_in[10];
    const float* fcw = (const float*)d_in[11];
    const float* fcb = (const float*)d_in[12];
    const float* fcpw = (const float*)d_in[13];
    const float* fcpb = (const float*)d_in[14];
    const float* lnfw = (const float*)d_in[15];
    const float* lnfb = (const float*)d_in[16];

    char* p = (char*)d_ws;
    float* h = (float*)p;     p += (size_t)Mc * Dc * 4;      // f32 [M][D]
    hbf16* qkv = (hbf16*)p;   p += (size_t)Mc * 3 * Dc * 2;  // bf16 [M][3D]
    hbf16* a = (hbf16*)p;     p += (size_t)Mc * Dc * 2;      // bf16 [M][D]
    hbf16* y = (hbf16*)p;     p += (size_t)Mc * Dc * 2;      // bf16 [M][D]
    hbf16* mlp = (hbf16*)p;   p += (size_t)Mc * 4 * Dc * 2;  // bf16 [M][4D]
    hbf16* wte_b = (hbf16*)p; p += (size_t)Vpad * Dc * 2;    // [50304][768]
    hbf16* wtr = (hbf16*)p;                                  // transposed weights
    size_t used = (size_t)((char*)wtr - (char*)d_ws);
    bool all_mode = (ws_size - used) >= (size_t)Lc * SZL * 2;

    embed_kernel<<<(Mc * Dc + 255) / 256, 256, 0, stream>>>(x, wte, wpe, h);
    convert_wte<<<((size_t)Vpad * Dc / 4 + 255) / 256, 256, 0, stream>>>(wte, wte_b);

    if (all_mode) {
        transpose4_kernel<<<dim3(6912, Lc), 256, 0, stream>>>(
            qkvw, projw, fcw, fcpw,
            wtr, wtr + SZ_Q, wtr + SZ_Q + SZ_P, wtr + SZ_Q + SZ_P + SZ_F);
    }

    for (int l = 0; l < Lc; l++) {
        hbf16* base = wtr + (all_mode ? (size_t)l * SZL : 0);
        hbf16* wq_t = base;
        hbf16* wp_t = base + SZ_Q;
        hbf16* wf_t = base + SZ_Q + SZ_P;
        hbf16* wfp_t = base + SZ_Q + SZ_P + SZ_F;
        if (!all_mode) {
            transpose4_kernel<<<dim3(6912, 1), 256, 0, stream>>>(
                qkvw + (size_t)l * SZ_Q, projw + (size_t)l * SZ_P,
                fcw + (size_t)l * SZ_F, fcpw + (size_t)l * SZ_FP,
                wq_t, wp_t, wf_t, wfp_t);
        }

        ln_kernel<<<Mc / 4, 256, 0, stream>>>(h, ln1w + (size_t)l * Dc, ln1b + (size_t)l * Dc, a);
        mm_kernel<0, true, 128><<<dim3(3 * Dc / 128, Mc / 128), 256, 0, stream>>>(
            a, wq_t, qkvb + (size_t)l * 3 * Dc, nullptr, qkv, Mc, 3 * Dc, Dc);
        fattn_kernel<<<dim3(Tc / 64, Hc, Bc), 256, 0, stream>>>(qkv, y);
        mm_kernel<1, false, 64><<<dim3(Dc / 64, Mc / 128), 256, 0, stream>>>(
            y, wp_t, projb + (size_t)l * Dc, h, h, Mc, Dc, Dc);
        ln_kernel<<<Mc / 4, 256, 0, stream>>>(h, ln2w + (size_t)l * Dc, ln2b + (size_t)l * Dc, a);
        mm_kernel<2, true, 128><<<dim3(4 * Dc / 128, Mc / 128), 256, 0, stream>>>(
            a, wf_t, fcb + (size_t)l * 4 * Dc, nullptr, mlp, Mc, 4 * Dc, Dc);
        mm_kernel<1, false, 64><<<dim3(Dc / 64, Mc / 128), 256, 0, stream>>>(
            mlp, wfp_t, fcpb + (size_t)l * Dc, h, h, Mc, Dc, 4 * Dc);
    }

    ln_kernel<<<Mc / 4, 256, 0, stream>>>(h, lnfw, lnfb, a);
    mm2_kernel<<<dim3(Vpad / 128, Mc / 256), 512, 0, stream>>>(
        a, wte_b, (float*)d_out, Mc, Vc, Dc);
}

// Round 17
// 2205.459 us; speedup vs baseline: 1.2768x; 1.0223x over previous
//
#include <hip/hip_runtime.h>
#include <hip/hip_bf16.h>

typedef __hip_bfloat16 hbf16;
using bf16x8 = __attribute__((ext_vector_type(8))) __bf16;
using f32x4 = __attribute__((ext_vector_type(4))) float;

// GPT-2 small: L=12 H=12 D=768 V=50257 T=1024 B=2, HD=64
constexpr int Lc = 12, Hc = 12, Dc = 768, Vc = 50257, Tc = 1024, Bc = 2, HDc = 64;
constexpr int Mc = Bc * Tc;  // 2048 rows
constexpr int Vpad = 50304;  // 393*128, zero-padded vocab

// transposed-weight slot sizes (elements)
constexpr size_t SZ_Q = (size_t)3 * Dc * Dc;   // [2304][768]
constexpr size_t SZ_P = (size_t)Dc * Dc;       // [768][768]
constexpr size_t SZ_F = (size_t)4 * Dc * Dc;   // [3072][768]
constexpr size_t SZ_FP = (size_t)4 * Dc * Dc;  // [768][3072]
constexpr size_t SZL = SZ_Q + SZ_P + SZ_F + SZ_FP;
constexpr int NPART = Bc * Hc * 8 * 2;  // 384 split partials

#define GLD16(gp, lp)                                               \
    __builtin_amdgcn_global_load_lds(                               \
        (__attribute__((address_space(1))) void*)(void*)(gp),       \
        (__attribute__((address_space(3))) void*)(void*)(lp), 16, 0, 0)

// ---------------- embedding: h = wte[x] + wpe[t] (f32) ----------------
__global__ void embed_kernel(const int* __restrict__ x, const float* __restrict__ wte,
                             const float* __restrict__ wpe, float* __restrict__ h) {
    int i = blockIdx.x * blockDim.x + threadIdx.x;
    if (i >= Mc * Dc) return;
    int m = i / Dc, d = i - m * Dc;
    int t = m % Tc;
    int tok = x[m];
    h[i] = wte[(size_t)tok * Dc + d] + wpe[(size_t)t * Dc + d];
}

// ---------------- layernorm: one wave per row, shuffle reduce, f32 in -> bf16 out --
__global__ __launch_bounds__(256) void ln_kernel(const float* __restrict__ x,
                                                 const float* __restrict__ w,
                                                 const float* __restrict__ b,
                                                 hbf16* __restrict__ out) {
    int wv = threadIdx.x >> 6, lane = threadIdx.x & 63;
    int row = blockIdx.x * 4 + wv;
    const float4* xr = (const float4*)(x + (size_t)row * Dc);
    float4 v[3];
    float s = 0.f, sq = 0.f;
#pragma unroll
    for (int i = 0; i < 3; i++) {
        v[i] = xr[i * 64 + lane];
        s += v[i].x + v[i].y + v[i].z + v[i].w;
        sq += v[i].x * v[i].x + v[i].y * v[i].y + v[i].z * v[i].z + v[i].w * v[i].w;
    }
#pragma unroll
    for (int o = 32; o > 0; o >>= 1) {
        s += __shfl_xor(s, o, 64);
        sq += __shfl_xor(sq, o, 64);
    }
    float mean = s * (1.f / Dc);
    float var = sq * (1.f / Dc) - mean * mean;
    float rstd = rsqrtf(var + 1e-5f);
#pragma unroll
    for (int i = 0; i < 3; i++) {
        int c = (i * 64 + lane) * 4;
        float4 wv4 = *(const float4*)(w + c);
        float4 bv4 = *(const float4*)(b + c);
        float r0 = (v[i].x - mean) * rstd * wv4.x + bv4.x;
        float r1 = (v[i].y - mean) * rstd * wv4.y + bv4.y;
        float r2 = (v[i].z - mean) * rstd * wv4.z + bv4.z;
        float r3 = (v[i].w - mean) * rstd * wv4.w + bv4.w;
        __bf16 q0 = (__bf16)r0, q1 = (__bf16)r1, q2 = (__bf16)r2, q3 = (__bf16)r3;
        ushort4 u;
        u.x = *(unsigned short*)&q0; u.y = *(unsigned short*)&q1;
        u.z = *(unsigned short*)&q2; u.w = *(unsigned short*)&q3;
        *(ushort4*)(out + (size_t)row * Dc + c) = u;
    }
}

// ---------------- weight transpose, grid (6912, nlayers) ----------------
__global__ __launch_bounds__(256) void transpose4_kernel(
    const float* __restrict__ s0, const float* __restrict__ s1,
    const float* __restrict__ s2, const float* __restrict__ s3,
    hbf16* __restrict__ d0, hbf16* __restrict__ d1,
    hbf16* __restrict__ d2, hbf16* __restrict__ d3) {
    int id = blockIdx.x;
    size_t lz = blockIdx.y;
    int bx, by, K, N;
    const float* W;
    hbf16* Wt;
    if (id < 1728)      { int t = id;        bx = t % 72; by = t / 72; K = 768;  N = 2304; W = s0 + lz * SZ_Q;  Wt = d0 + lz * SZL; }
    else if (id < 2304) { int t = id - 1728; bx = t % 24; by = t / 24; K = 768;  N = 768;  W = s1 + lz * SZ_P;  Wt = d1 + lz * SZL; }
    else if (id < 4608) { int t = id - 2304; bx = t % 96; by = t / 96; K = 768;  N = 3072; W = s2 + lz * SZ_F;  Wt = d2 + lz * SZL; }
    else                { int t = id - 4608; bx = t % 24; by = t / 24; K = 3072; N = 768;  W = s3 + lz * SZ_FP; Wt = d3 + lz * SZL; }

    __shared__ float tile[32][33];
    int n0 = bx * 32, k0 = by * 32;
    int tx = threadIdx.x & 31, ty = threadIdx.x >> 5;  // 32x8
#pragma unroll
    for (int i = 0; i < 4; i++) {
        int r = ty + i * 8;
        tile[r][tx] = W[(size_t)(k0 + r) * N + n0 + tx];
    }
    __syncthreads();
#pragma unroll
    for (int i = 0; i < 4; i++) {
        int r = ty + i * 8;
        Wt[(size_t)(n0 + r) * K + k0 + tx] = __float2bfloat16(tile[tx][r]);
    }
}

// ---------------- wte f32 [V][D] -> bf16 [Vpad][D] (zero pad) ----------------
__global__ void convert_wte(const float* __restrict__ wte, hbf16* __restrict__ out) {
    size_t i4 = ((size_t)blockIdx.x * 256 + threadIdx.x) * 4;
    if (i4 >= (size_t)Vpad * Dc) return;
    if (i4 < (size_t)Vc * Dc) {
#pragma unroll
        for (int j = 0; j < 4; j++) out[i4 + j] = __float2bfloat16(wte[i4 + j]);
    } else {
#pragma unroll
        for (int j = 0; j < 4; j++) out[i4 + j] = __float2bfloat16(0.f);
    }
}

// ---------------- MFMA GEMM 128xBN, BK=64, dbuf + counted vmcnt (R15) ----------
// EPI: 0 = +bias, 1 = +bias +f32 residual, 2 = +bias + tanh-GELU
template <int EPI, bool OUTBF, int BN>
__global__ __launch_bounds__(256) void mm_kernel(const hbf16* __restrict__ A,
                                                 const hbf16* __restrict__ Bt,
                                                 const float* __restrict__ bias,
                                                 const float* __restrict__ resid,
                                                 void* __restrict__ Cout,
                                                 int M, int N, int K) {
    constexpr int NF = BN / 32;
    constexpr int NBI = BN / 32;
    __shared__ __bf16 As[2][128 * 64];
    __shared__ __bf16 Bs[2][BN * 64];
    int tid = threadIdx.x;
    int l = tid & 63, w = tid >> 6;
    int wr = w >> 1, wc = w & 1;

    int gx = gridDim.x, gy = gridDim.y;
    int nwg = gx * gy;
    int hwlin = blockIdx.y * gx + blockIdx.x;
    int wk = (hwlin & 7) * (nwg >> 3) + (hwlin >> 3);
    int m0 = (wk % gy) * 128;
    int n0 = (wk / gy) * BN;

    int sr = tid >> 3, sc = tid & 7;
    int scs = (sc ^ (sr & 7)) * 8;
    const hbf16* pA[4];
#pragma unroll
    for (int j = 0; j < 4; j++) pA[j] = A + (size_t)(m0 + j * 32 + sr) * K + scs;
    const hbf16* pB[NBI];
#pragma unroll
    for (int j = 0; j < NBI; j++) pB[j] = Bt + (size_t)(n0 + j * 32 + sr) * K + scs;

    auto stage = [&](int bi, int ko) {
#pragma unroll
        for (int j = 0; j < 4; j++) GLD16(pA[j] + ko, &As[bi][j * 2048 + tid * 8]);
#pragma unroll
        for (int j = 0; j < NBI; j++) GLD16(pB[j] + ko, &Bs[bi][j * 2048 + tid * 8]);
    };

    int lr = l & 15, lg = l >> 4;
    int aoff[2][4], boff[2][NF];
#pragma unroll
    for (int kk = 0; kk < 2; kk++) {
        int ks = ((kk * 4 + lg) ^ (lr & 7)) * 8;
#pragma unroll
        for (int m = 0; m < 4; m++) aoff[kk][m] = (wr * 64 + m * 16 + lr) * 64 + ks;
#pragma unroll
        for (int n = 0; n < NF; n++) boff[kk][n] = (wc * (BN / 2) + n * 16 + lr) * 64 + ks;
    }

    f32x4 acc[4][NF] = {};
    int nk = K / 64;

    stage(0, 0);
    for (int t = 0; t < nk; ++t) {
        int cur = t & 1;
        if (t + 1 < nk) {
            stage(cur ^ 1, (t + 1) * 64);
            if constexpr (BN == 128)
                asm volatile("s_waitcnt vmcnt(8)" ::: "memory");
            else
                asm volatile("s_waitcnt vmcnt(6)" ::: "memory");
        } else {
            asm volatile("s_waitcnt vmcnt(0)" ::: "memory");
        }
        __builtin_amdgcn_sched_barrier(0);
        __builtin_amdgcn_s_barrier();
        __builtin_amdgcn_sched_barrier(0);
#pragma unroll
        for (int kk = 0; kk < 2; kk++) {
            bf16x8 af[4], bfr[NF];
#pragma unroll
            for (int m = 0; m < 4; m++) af[m] = *(const bf16x8*)&As[cur][aoff[kk][m]];
#pragma unroll
            for (int n = 0; n < NF; n++) bfr[n] = *(const bf16x8*)&Bs[cur][boff[kk][n]];
#pragma unroll
            for (int m = 0; m < 4; m++)
#pragma unroll
                for (int n = 0; n < NF; n++)
                    acc[m][n] = __builtin_amdgcn_mfma_f32_16x16x32_bf16(af[m], bfr[n], acc[m][n], 0, 0, 0);
        }
        __builtin_amdgcn_s_barrier();
    }

#pragma unroll
    for (int n = 0; n < NF; n++) {
        int col = n0 + wc * (BN / 2) + n * 16 + lr;
        bool cok = col < N;
        float bv = (bias && cok) ? bias[col] : 0.f;
#pragma unroll
        for (int m = 0; m < 4; m++) {
#pragma unroll
            for (int r = 0; r < 4; r++) {
                int row = m0 + wr * 64 + m * 16 + lg * 4 + r;
                if (!cok) continue;
                float v = acc[m][n][r] + bv;
                if (EPI == 1) v += resid[(size_t)row * N + col];
                if (EPI == 2) {
                    float x3 = v * v * v;
                    v = 0.5f * v * (1.f + tanhf(0.7978845608028654f * (v + 0.044715f * x3)));
                }
                if (OUTBF)
                    ((hbf16*)Cout)[(size_t)row * N + col] = __float2bfloat16(v);
                else
                    ((float*)Cout)[(size_t)row * N + col] = v;
            }
        }
    }
}

// ---------------- MFMA GEMM 256x128, 512 threads, BK=64 single-buffer (R14) -------
__global__ __launch_bounds__(512) void mm2_kernel(const hbf16* __restrict__ A,
                                                  const hbf16* __restrict__ Bt,
                                                  float* __restrict__ Cout,
                                                  int M, int N, int K) {
    __shared__ __bf16 As[256 * 64];  // 32 KB
    __shared__ __bf16 Bs[128 * 64];  // 16 KB
    int tid = threadIdx.x;
    int l = tid & 63, w = tid >> 6;
    int wr = w >> 1, wc = w & 1;

    int gx = gridDim.x, gy = gridDim.y;  // gy = 8
    int nwg = gx * gy;
    int hwlin = blockIdx.y * gx + blockIdx.x;
    int wk = (hwlin & 7) * (nwg >> 3) + (hwlin >> 3);
    int m0 = (wk & 7) * 256;
    int n0 = (wk >> 3) * 128;

    int sr = tid >> 3, sc = tid & 7;
    int scs = (sc ^ (sr & 7)) * 8;
    const hbf16* pA[4];
    __bf16* lA[4];
#pragma unroll
    for (int j = 0; j < 4; j++) {
        pA[j] = A + (size_t)(m0 + j * 64 + sr) * K + scs;
        lA[j] = As + j * 4096 + tid * 8;
    }
    const hbf16* pB[2];
    __bf16* lB[2];
#pragma unroll
    for (int j = 0; j < 2; j++) {
        pB[j] = Bt + (size_t)(n0 + j * 64 + sr) * K + scs;
        lB[j] = Bs + j * 4096 + tid * 8;
    }

    int lr = l & 15, lg = l >> 4;
    int aoff[2][4], boff[2][4];
#pragma unroll
    for (int kk = 0; kk < 2; kk++) {
        int ks = ((kk * 4 + lg) ^ (lr & 7)) * 8;
#pragma unroll
        for (int m = 0; m < 4; m++) aoff[kk][m] = (wr * 64 + m * 16 + lr) * 64 + ks;
#pragma unroll
        for (int n = 0; n < 4; n++) boff[kk][n] = (wc * 64 + n * 16 + lr) * 64 + ks;
    }

    f32x4 acc[4][4] = {};

    for (int k0 = 0; k0 < K; k0 += 64) {
#pragma unroll
        for (int j = 0; j < 4; j++) {
            GLD16(pA[j], lA[j]);
            pA[j] += 64;
        }
#pragma unroll
        for (int j = 0; j < 2; j++) {
            GLD16(pB[j], lB[j]);
            pB[j] += 64;
        }
        __syncthreads();
#pragma unroll
        for (int kk = 0; kk < 2; kk++) {
            bf16x8 af[4], bfr[4];
#pragma unroll
            for (int m = 0; m < 4; m++) af[m] = *(const bf16x8*)&As[aoff[kk][m]];
#pragma unroll
            for (int n = 0; n < 4; n++) bfr[n] = *(const bf16x8*)&Bs[boff[kk][n]];
#pragma unroll
            for (int m = 0; m < 4; m++)
#pragma unroll
                for (int n = 0; n < 4; n++)
                    acc[m][n] = __builtin_amdgcn_mfma_f32_16x16x32_bf16(af[m], bfr[n], acc[m][n], 0, 0, 0);
        }
        __syncthreads();
    }

#pragma unroll
    for (int n = 0; n < 4; n++) {
        int col = n0 + wc * 64 + n * 16 + lr;
        if (col >= N) continue;
#pragma unroll
        for (int m = 0; m < 4; m++) {
#pragma unroll
            for (int r = 0; r < 4; r++) {
                int row = m0 + wr * 64 + m * 16 + lg * 4 + r;
                Cout[(size_t)row * N + col] = acc[m][n][r];
            }
        }
    }
}

// ---------------- MFMA flash attention, pipelined + swapped QK^T + split-K --------
// grid (24, H, B). s<16: heavy split blocks (qt=8+(s>>1), half=s&1, <=8 tiles each,
// write unnormalized partials). s>=16: light blocks (qt=s-16, 1..8 tiles, write y).
__global__ __launch_bounds__(256) void fattn_kernel(const hbf16* __restrict__ qkv,
                                                    hbf16* __restrict__ y,
                                                    float* __restrict__ part_O,
                                                    float* __restrict__ part_m,
                                                    float* __restrict__ part_l) {
    int s = blockIdx.x;
    int h = blockIdx.y, b = blockIdx.z;
    int qt, jlo, jhi, half = 0;
    bool partial;
    if (s < 16) {
        qt = 8 + (s >> 1);
        half = s & 1;
        int mid = (qt + 1) >> 1;
        jlo = half ? mid : 0;
        jhi = half ? qt : mid - 1;
        partial = true;
    } else {
        qt = s - 16;
        jlo = 0;
        jhi = qt;
        partial = false;
    }
    int q0 = qt * 64;
    int tid = threadIdx.x;
    int l = tid & 63, w = tid >> 6;
    int li = l & 15, lg = l >> 4;
    constexpr int RS = 3 * Dc;
    constexpr int PST = 72;
    constexpr int VST = 72;
    constexpr float SCL = 0.125f * 1.44269504f;  // 1/sqrt(64) * log2(e)
    constexpr float THR = 11.5f;                 // defer-max threshold (log2 domain)

    __shared__ __bf16 K_lds[2][64 * 64];   // 2 x 8 KB, swizzled 16B slots
    __shared__ __bf16 Vt[2][64 * VST];     // 2 x 9 KB
    __shared__ __bf16 P_lds[4][16 * PST];  // 9 KB  (layout [q_local][j])

    bf16x8 qf[2];
    {
        const hbf16* qp = qkv + (size_t)(b * Tc + q0 + w * 16 + li) * RS + h * HDc + lg * 8;
        qf[0] = *(const bf16x8*)qp;
        qf[1] = *(const bf16x8*)(qp + 32);
    }

    int krow0 = tid >> 3, krow1 = 32 + (tid >> 3);
    int ks8 = tid & 7;
    int kc0 = (ks8 ^ (krow0 & 7)) * 8;
    int kc1 = (ks8 ^ (krow1 & 7)) * 8;
    const hbf16* kbase = qkv + (size_t)(b * Tc) * RS + Dc + h * HDc;

    int jp = (tid >> 3) * 2;
    int db = (tid & 7) * 8;
    const hbf16* vbase = qkv + (size_t)(b * Tc) * RS + 2 * Dc + h * HDc;

    int koff[2][4];
#pragma unroll
    for (int ks = 0; ks < 2; ks++)
#pragma unroll
        for (int n = 0; n < 4; n++)
            koff[ks][n] = (n * 16 + li) * 64 + (((ks * 4 + lg) ^ (li & 7)) * 8);

    f32x4 acc_o[4] = {};
    float m_run = -1e30f, l_run = 0.f;  // scalar: lane owns q = w*16+li

    int j0p = jlo * 64;
    bf16x8 vr0, vr1;
    {
        const hbf16* vp = vbase + (size_t)(j0p + jp) * RS + db;
        vr0 = *(const bf16x8*)vp;
        vr1 = *(const bf16x8*)(vp + RS);
        GLD16(kbase + (size_t)(j0p + krow0) * RS + kc0, &K_lds[0][tid * 8]);
        GLD16(kbase + (size_t)(j0p + krow1) * RS + kc1, &K_lds[0][2048 + tid * 8]);
    }
#pragma unroll
    for (int i = 0; i < 8; i++) {
        __bf16 a0 = vr0[i], a1 = vr1[i];
        unsigned u = (unsigned)*(unsigned short*)&a0 | ((unsigned)*(unsigned short*)&a1 << 16);
        *(unsigned*)&Vt[0][(db + i) * VST + jp] = u;
    }

    int cur = 0;
    for (int jt = jlo; jt <= jhi; jt++) {
        int jn0 = (jt < jhi) ? (jt + 1) * 64 : j0p;  // dummy wrap keeps vmcnt invariant

        asm volatile("s_waitcnt lgkmcnt(0)" ::: "memory");
        __builtin_amdgcn_s_barrier();

        {
            const hbf16* vp = vbase + (size_t)(jn0 + jp) * RS + db;
            vr0 = *(const bf16x8*)vp;
            vr1 = *(const bf16x8*)(vp + RS);
            GLD16(kbase + (size_t)(jn0 + krow0) * RS + kc0, &K_lds[cur ^ 1][tid * 8]);
            GLD16(kbase + (size_t)(jn0 + krow1) * RS + kc1, &K_lds[cur ^ 1][2048 + tid * 8]);
        }

        asm volatile("s_waitcnt vmcnt(4)" ::: "memory");
        __builtin_amdgcn_sched_barrier(0);

        // ---- S = K Q^T (swapped): s[n][r] = S[j=n*16+lg*4+r][q=li] ----
        f32x4 sv[4] = {};
#pragma unroll
        for (int ks = 0; ks < 2; ks++)
#pragma unroll
            for (int n = 0; n < 4; n++) {
                bf16x8 kf = *(const bf16x8*)&K_lds[cur][koff[ks][n]];
                sv[n] = __builtin_amdgcn_mfma_f32_16x16x32_bf16(kf, qf[ks], sv[n], 0, 0, 0);
            }
#pragma unroll
        for (int n = 0; n < 4; n++)
#pragma unroll
            for (int r = 0; r < 4; r++) sv[n][r] *= SCL;

        if (jt == qt) {
            int qloc = w * 16 + li;
#pragma unroll
            for (int n = 0; n < 4; n++)
#pragma unroll
                for (int r = 0; r < 4; r++)
                    if (n * 16 + lg * 4 + r > qloc) sv[n][r] = -1e30f;
        }

        // ---- online softmax: all 16 values belong to q = w*16+li ----
        float mx = -1e30f;
#pragma unroll
        for (int n = 0; n < 4; n++)
#pragma unroll
            for (int r = 0; r < 4; r++) mx = fmaxf(mx, sv[n][r]);
        mx = fmaxf(mx, __shfl_xor(mx, 16, 64));
        mx = fmaxf(mx, __shfl_xor(mx, 32, 64));

        bool dfr = __all(mx - m_run <= THR);
        float sclq = 1.f;
        if (!dfr) {
            float mnew = fmaxf(m_run, mx);
            sclq = exp2f(m_run - mnew);
            m_run = mnew;
        }
        float rs = 0.f;
#pragma unroll
        for (int n = 0; n < 4; n++)
#pragma unroll
            for (int r = 0; r < 4; r++) {
                float pv = exp2f(sv[n][r] - m_run);
                sv[n][r] = pv;
                rs += pv;
            }
        rs += __shfl_xor(rs, 16, 64);
        rs += __shfl_xor(rs, 32, 64);
        l_run = (dfr ? l_run : l_run * sclq) + rs;

        // ---- P -> LDS [q=li][j], packed pairs ----
#pragma unroll
        for (int n = 0; n < 4; n++)
#pragma unroll
            for (int r = 0; r < 4; r += 2) {
                __bf16 b0 = (__bf16)sv[n][r], b1 = (__bf16)sv[n][r + 1];
                unsigned u = (unsigned)*(unsigned short*)&b0 |
                             ((unsigned)*(unsigned short*)&b1 << 16);
                *(unsigned*)&P_lds[w][li * PST + n * 16 + lg * 4 + r] = u;
            }
        bf16x8 pa0 = *(const bf16x8*)&P_lds[w][li * PST + lg * 8];
        bf16x8 pa1 = *(const bf16x8*)&P_lds[w][li * PST + 32 + lg * 8];

        if (!dfr) {
#pragma unroll
            for (int r = 0; r < 4; r++) {
                float sr_ = __shfl(sclq, (l & 48) | (lg * 4 + r), 64);
#pragma unroll
                for (int n2 = 0; n2 < 4; n2++) acc_o[n2][r] *= sr_;
            }
        }

        // ---- PV from Vt[cur] ----
#pragma unroll
        for (int n2 = 0; n2 < 4; n2++) {
            bf16x8 vf0 = *(const bf16x8*)&Vt[cur][(n2 * 16 + li) * VST + lg * 8];
            bf16x8 vf1 = *(const bf16x8*)&Vt[cur][(n2 * 16 + li) * VST + 32 + lg * 8];
            acc_o[n2] = __builtin_amdgcn_mfma_f32_16x16x32_bf16(pa0, vf0, acc_o[n2], 0, 0, 0);
            acc_o[n2] = __builtin_amdgcn_mfma_f32_16x16x32_bf16(pa1, vf1, acc_o[n2], 0, 0, 0);
        }

        // ---- write V(jt+1) regs -> Vt[cur^1] ----
#pragma unroll
        for (int i = 0; i < 8; i++) {
            __bf16 a0 = vr0[i], a1 = vr1[i];
            unsigned u = (unsigned)*(unsigned short*)&a0 | ((unsigned)*(unsigned short*)&a1 << 16);
            *(unsigned*)&Vt[cur ^ 1][(db + i) * VST + jp] = u;
        }
        cur ^= 1;
    }

    if (partial) {
        int p = ((b * Hc + h) * 8 + (qt - 8)) * 2 + half;
#pragma unroll
        for (int r = 0; r < 4; r++) {
            int lrow = w * 16 + lg * 4 + r;
#pragma unroll
            for (int n2 = 0; n2 < 4; n2++)
                part_O[(size_t)p * 4096 + lrow * 64 + n2 * 16 + li] = acc_o[n2][r];
        }
        if (lg == 0) {
            part_m[p * 64 + w * 16 + li] = m_run;
            part_l[p * 64 + w * 16 + li] = l_run;
        }
    } else {
#pragma unroll
        for (int r = 0; r < 4; r++) {
            float lv = __shfl(l_run, (l & 48) | (lg * 4 + r), 64);
            float rcp = 1.f / lv;
            int row = q0 + w * 16 + lg * 4 + r;
#pragma unroll
            for (int n2 = 0; n2 < 4; n2++)
                y[(size_t)(b * Tc + row) * Dc + h * HDc + n2 * 16 + li] =
                    __float2bfloat16(acc_o[n2][r] * rcp);
        }
    }
}

// ---------------- merge split-K partials: one wave per q-row ----------------
__global__ __launch_bounds__(256) void fmerge_kernel(const float* __restrict__ part_O,
                                                     const float* __restrict__ part_m,
                                                     const float* __restrict__ part_l,
                                                     hbf16* __restrict__ y) {
    int gi = blockIdx.x * 4 + (threadIdx.x >> 6);
    int lane = threadIdx.x & 63;
    int row512 = gi & 511;
    int bh = gi >> 9;
    int b = bh / Hc, h = bh % Hc;
    int qt8 = row512 >> 6, lrow = row512 & 63;
    int p0 = (bh * 8 + qt8) * 2, p1 = p0 + 1;
    float m0 = part_m[p0 * 64 + lrow], m1 = part_m[p1 * 64 + lrow];
    float l0 = part_l[p0 * 64 + lrow], l1 = part_l[p1 * 64 + lrow];
    float m = fmaxf(m0, m1);
    float a0 = exp2f(m0 - m), a1 = exp2f(m1 - m);
    float lsum = l0 * a0 + l1 * a1;
    float o0 = part_O[(size_t)p0 * 4096 + lrow * 64 + lane];
    float o1 = part_O[(size_t)p1 * 4096 + lrow * 64 + lane];
    float o = (o0 * a0 + o1 * a1) / lsum;
    int q = (8 + qt8) * 64 + lrow;
    y[((size_t)b * Tc + q) * Dc + h * HDc + lane] = __float2bfloat16(o);
}

extern "C" void kernel_launch(void* const* d_in, const int* in_sizes, int n_in,
                              void* d_out, int out_size, void* d_ws, size_t ws_size,
                              hipStream_t stream) {
    const int* x = (const int*)d_in[0];
    const float* wte = (const float*)d_in[1];
    const float* wpe = (const float*)d_in[2];
    const float* ln1w = (const float*)d_in[3];
    const float* ln1b = (const float*)d_in[4];
    const float* qkvw = (const float*)d_in[5];
    const float* qkvb = (const float*)d_in[6];
    const float* projw = (const float*)d_in[7];
    const float* projb = (const float*)d_in[8];
    const float* ln2w = (const float*)d_in[9];
    const float* ln2b = (const float*)d_in[10];
    const float* fcw = (const float*)d_in[11];
    const float* fcb = (const float*)d_in[12];
    const float* fcpw = (const float*)d_in[13];
    const float* fcpb = (const float*)d_in[14];
    const float* lnfw = (const float*)d_in[15];
    const float* lnfb = (const float*)d_in[16];

    char* p = (char*)d_ws;
    float* h = (float*)p;      p += (size_t)Mc * Dc * 4;      // f32 [M][D]
    hbf16* qkv = (hbf16*)p;    p += (size_t)Mc * 3 * Dc * 2;  // bf16 [M][3D]
    hbf16* a = (hbf16*)p;      p += (size_t)Mc * Dc * 2;      // bf16 [M][D]
    hbf16* y = (hbf16*)p;      p += (size_t)Mc * Dc * 2;      // bf16 [M][D]
    hbf16* mlp = (hbf16*)p;    p += (size_t)Mc * 4 * Dc * 2;  // bf16 [M][4D]
    hbf16* wte_b = (hbf16*)p;  p += (size_t)Vpad * Dc * 2;    // [50304][768]
    float* part_O = (float*)p; p += (size_t)NPART * 4096 * 4; // 6.3 MB
    float* part_m = (float*)p; p += (size_t)NPART * 64 * 4;
    float* part_l = (float*)p; p += (size_t)NPART * 64 * 4;
    hbf16* wtr = (hbf16*)p;                                   // transposed weights
    size_t used = (size_t)((char*)wtr - (char*)d_ws);
    bool all_mode = (ws_size - used) >= (size_t)Lc * SZL * 2;

    embed_kernel<<<(Mc * Dc + 255) / 256, 256, 0, stream>>>(x, wte, wpe, h);
    convert_wte<<<((size_t)Vpad * Dc / 4 + 255) / 256, 256, 0, stream>>>(wte, wte_b);

    if (all_mode) {
        transpose4_kernel<<<dim3(6912, Lc), 256, 0, stream>>>(
            qkvw, projw, fcw, fcpw,
            wtr, wtr + SZ_Q, wtr + SZ_Q + SZ_P, wtr + SZ_Q + SZ_P + SZ_F);
    }

    for (int l = 0; l < Lc; l++) {
        hbf16* base = wtr + (all_mode ? (size_t)l * SZL : 0);
        hbf16* wq_t = base;
        hbf16* wp_t = base + SZ_Q;
        hbf16* wf_t = base + SZ_Q + SZ_P;
        hbf16* wfp_t = base + SZ_Q + SZ_P + SZ_F;
        if (!all_mode) {
            transpose4_kernel<<<dim3(6912, 1), 256, 0, stream>>>(
                qkvw + (size_t)l * SZ_Q, projw + (size_t)l * SZ_P,
                fcw + (size_t)l * SZ_F, fcpw + (size_t)l * SZ_FP,
                wq_t, wp_t, wf_t, wfp_t);
        }

        ln_kernel<<<Mc / 4, 256, 0, stream>>>(h, ln1w + (size_t)l * Dc, ln1b + (size_t)l * Dc, a);
        mm_kernel<0, true, 128><<<dim3(3 * Dc / 128, Mc / 128), 256, 0, stream>>>(
            a, wq_t, qkvb + (size_t)l * 3 * Dc, nullptr, qkv, Mc, 3 * Dc, Dc);
        fattn_kernel<<<dim3(24, Hc, Bc), 256, 0, stream>>>(qkv, y, part_O, part_m, part_l);
        fmerge_kernel<<<Bc * Hc * 512 / 4, 256, 0, stream>>>(part_O, part_m, part_l, y);
        mm_kernel<1, false, 64><<<dim3(Dc / 64, Mc / 128), 256, 0, stream>>>(
            y, wp_t, projb + (size_t)l * Dc, h, h, Mc, Dc, Dc);
        ln_kernel<<<Mc / 4, 256, 0, stream>>>(h, ln2w + (size_t)l * Dc, ln2b + (size_t)l * Dc, a);
        mm_kernel<2, true, 128><<<dim3(4 * Dc / 128, Mc / 128), 256, 0, stream>>>(
            a, wf_t, fcb + (size_t)l * 4 * Dc, nullptr, mlp, Mc, 4 * Dc, Dc);
        mm_kernel<1, false, 64><<<dim3(Dc / 64, Mc / 128), 256, 0, stream>>>(
            mlp, wfp_t, fcpb + (size_t)l * Dc, h, h, Mc, Dc, 4 * Dc);
    }

    ln_kernel<<<Mc / 4, 256, 0, stream>>>(h, lnfw, lnfb, a);
    mm2_kernel<<<dim3(Vpad / 128, Mc / 256), 512, 0, stream>>>(
        a, wte_b, (float*)d_out, Mc, Vc, Dc);
}

// Round 18
// 2034.558 us; speedup vs baseline: 1.3840x; 1.0840x over previous
//
#include <hip/hip_runtime.h>
#include <hip/hip_bf16.h>

typedef __hip_bfloat16 hbf16;
using bf16x8 = __attribute__((ext_vector_type(8))) __bf16;
using f32x4 = __attribute__((ext_vector_type(4))) float;

// GPT-2 small: L=12 H=12 D=768 V=50257 T=1024 B=2, HD=64
constexpr int Lc = 12, Hc = 12, Dc = 768, Vc = 50257, Tc = 1024, Bc = 2, HDc = 64;
constexpr int Mc = Bc * Tc;  // 2048 rows
constexpr int Vpad = 50304;  // 393*128, zero-padded vocab

// transposed-weight slot sizes (elements)
constexpr size_t SZ_Q = (size_t)3 * Dc * Dc;   // [2304][768]
constexpr size_t SZ_P = (size_t)Dc * Dc;       // [768][768]
constexpr size_t SZ_F = (size_t)4 * Dc * Dc;   // [3072][768]
constexpr size_t SZ_FP = (size_t)4 * Dc * Dc;  // [768][3072]
constexpr size_t SZL = SZ_Q + SZ_P + SZ_F + SZ_FP;
constexpr int NPART = Bc * Hc * 8 * 2;  // 384 split partials

#define GLD16(gp, lp)                                               \
    __builtin_amdgcn_global_load_lds(                               \
        (__attribute__((address_space(1))) void*)(void*)(gp),       \
        (__attribute__((address_space(3))) void*)(void*)(lp), 16, 0, 0)

// ---------------- embedding: h = wte[x] + wpe[t] (f32) ----------------
__global__ void embed_kernel(const int* __restrict__ x, const float* __restrict__ wte,
                             const float* __restrict__ wpe, float* __restrict__ h) {
    int i = blockIdx.x * blockDim.x + threadIdx.x;
    if (i >= Mc * Dc) return;
    int m = i / Dc, d = i - m * Dc;
    int t = m % Tc;
    int tok = x[m];
    h[i] = wte[(size_t)tok * Dc + d] + wpe[(size_t)t * Dc + d];
}

// ---------------- layernorm: one wave per row, shuffle reduce, f32 in -> bf16 out --
__global__ __launch_bounds__(256) void ln_kernel(const float* __restrict__ x,
                                                 const float* __restrict__ w,
                                                 const float* __restrict__ b,
                                                 hbf16* __restrict__ out) {
    int wv = threadIdx.x >> 6, lane = threadIdx.x & 63;
    int row = blockIdx.x * 4 + wv;
    const float4* xr = (const float4*)(x + (size_t)row * Dc);
    float4 v[3];
    float s = 0.f, sq = 0.f;
#pragma unroll
    for (int i = 0; i < 3; i++) {
        v[i] = xr[i * 64 + lane];
        s += v[i].x + v[i].y + v[i].z + v[i].w;
        sq += v[i].x * v[i].x + v[i].y * v[i].y + v[i].z * v[i].z + v[i].w * v[i].w;
    }
#pragma unroll
    for (int o = 32; o > 0; o >>= 1) {
        s += __shfl_xor(s, o, 64);
        sq += __shfl_xor(sq, o, 64);
    }
    float mean = s * (1.f / Dc);
    float var = sq * (1.f / Dc) - mean * mean;
    float rstd = rsqrtf(var + 1e-5f);
#pragma unroll
    for (int i = 0; i < 3; i++) {
        int c = (i * 64 + lane) * 4;
        float4 wv4 = *(const float4*)(w + c);
        float4 bv4 = *(const float4*)(b + c);
        float r0 = (v[i].x - mean) * rstd * wv4.x + bv4.x;
        float r1 = (v[i].y - mean) * rstd * wv4.y + bv4.y;
        float r2 = (v[i].z - mean) * rstd * wv4.z + bv4.z;
        float r3 = (v[i].w - mean) * rstd * wv4.w + bv4.w;
        __bf16 q0 = (__bf16)r0, q1 = (__bf16)r1, q2 = (__bf16)r2, q3 = (__bf16)r3;
        ushort4 u;
        u.x = *(unsigned short*)&q0; u.y = *(unsigned short*)&q1;
        u.z = *(unsigned short*)&q2; u.w = *(unsigned short*)&q3;
        *(ushort4*)(out + (size_t)row * Dc + c) = u;
    }
}

// ---------------- weight transpose, grid (6912, nlayers) ----------------
__global__ __launch_bounds__(256) void transpose4_kernel(
    const float* __restrict__ s0, const float* __restrict__ s1,
    const float* __restrict__ s2, const float* __restrict__ s3,
    hbf16* __restrict__ d0, hbf16* __restrict__ d1,
    hbf16* __restrict__ d2, hbf16* __restrict__ d3) {
    int id = blockIdx.x;
    size_t lz = blockIdx.y;
    int bx, by, K, N;
    const float* W;
    hbf16* Wt;
    if (id < 1728)      { int t = id;        bx = t % 72; by = t / 72; K = 768;  N = 2304; W = s0 + lz * SZ_Q;  Wt = d0 + lz * SZL; }
    else if (id < 2304) { int t = id - 1728; bx = t % 24; by = t / 24; K = 768;  N = 768;  W = s1 + lz * SZ_P;  Wt = d1 + lz * SZL; }
    else if (id < 4608) { int t = id - 2304; bx = t % 96; by = t / 96; K = 768;  N = 3072; W = s2 + lz * SZ_F;  Wt = d2 + lz * SZL; }
    else                { int t = id - 4608; bx = t % 24; by = t / 24; K = 3072; N = 768;  W = s3 + lz * SZ_FP; Wt = d3 + lz * SZL; }

    __shared__ float tile[32][33];
    int n0 = bx * 32, k0 = by * 32;
    int tx = threadIdx.x & 31, ty = threadIdx.x >> 5;  // 32x8
#pragma unroll
    for (int i = 0; i < 4; i++) {
        int r = ty + i * 8;
        tile[r][tx] = W[(size_t)(k0 + r) * N + n0 + tx];
    }
    __syncthreads();
#pragma unroll
    for (int i = 0; i < 4; i++) {
        int r = ty + i * 8;
        Wt[(size_t)(n0 + r) * K + k0 + tx] = __float2bfloat16(tile[tx][r]);
    }
}

// ---------------- wte f32 [V][D] -> bf16 [Vpad][D] (zero pad) ----------------
__global__ void convert_wte(const float* __restrict__ wte, hbf16* __restrict__ out) {
    size_t i4 = ((size_t)blockIdx.x * 256 + threadIdx.x) * 4;
    if (i4 >= (size_t)Vpad * Dc) return;
    if (i4 < (size_t)Vc * Dc) {
#pragma unroll
        for (int j = 0; j < 4; j++) out[i4 + j] = __float2bfloat16(wte[i4 + j]);
    } else {
#pragma unroll
        for (int j = 0; j < 4; j++) out[i4 + j] = __float2bfloat16(0.f);
    }
}

// ---------------- MFMA GEMM 64xBN, BK=64, dbuf + counted vmcnt ----------
// BM=64: 2x grid vs BM=128 -> 3-5 blocks/CU (cross-block TLP hides waits).
// Wave (2x2): 32 rows x BN/2 cols, acc[2][NF].
// EPI: 0 = +bias, 1 = +bias +f32 residual, 2 = +bias + tanh-GELU
template <int EPI, bool OUTBF, int BN>
__global__ __launch_bounds__(256) void mm_kernel(const hbf16* __restrict__ A,
                                                 const hbf16* __restrict__ Bt,
                                                 const float* __restrict__ bias,
                                                 const float* __restrict__ resid,
                                                 void* __restrict__ Cout,
                                                 int M, int N, int K) {
    constexpr int NF = BN / 32;   // n-frags per wave
    constexpr int NBI = BN / 32;  // B stage issues (32 rows each)
    __shared__ __bf16 As[2][64 * 64];   // 2 x 8 KB
    __shared__ __bf16 Bs[2][BN * 64];   // 2 x 16/8 KB
    int tid = threadIdx.x;
    int l = tid & 63, w = tid >> 6;
    int wr = w >> 1, wc = w & 1;

    // XCD swizzle: hw dispatch order is x-fastest; chunk per XCD, m fastest.
    int gx = gridDim.x, gy = gridDim.y;
    int nwg = gx * gy;
    int hwlin = blockIdx.y * gx + blockIdx.x;
    int wk = (hwlin & 7) * (nwg >> 3) + (hwlin >> 3);
    int m0 = (wk % gy) * 64;
    int n0 = (wk / gy) * BN;

    // staging: 32 rows/issue; row = j*32 + (tid>>3), 16B slot sc = tid&7
    int sr = tid >> 3, sc = tid & 7;
    int scs = (sc ^ (sr & 7)) * 8;
    const hbf16* pA[2];
#pragma unroll
    for (int j = 0; j < 2; j++) pA[j] = A + (size_t)(m0 + j * 32 + sr) * K + scs;
    const hbf16* pB[NBI];
#pragma unroll
    for (int j = 0; j < NBI; j++) pB[j] = Bt + (size_t)(n0 + j * 32 + sr) * K + scs;

    auto stage = [&](int bi, int ko) {
#pragma unroll
        for (int j = 0; j < 2; j++) GLD16(pA[j] + ko, &As[bi][j * 2048 + tid * 8]);
#pragma unroll
        for (int j = 0; j < NBI; j++) GLD16(pB[j] + ko, &Bs[bi][j * 2048 + tid * 8]);
    };

    int lr = l & 15, lg = l >> 4;
    int aoff[2][2], boff[2][NF];
#pragma unroll
    for (int kk = 0; kk < 2; kk++) {
        int ks = ((kk * 4 + lg) ^ (lr & 7)) * 8;
#pragma unroll
        for (int m = 0; m < 2; m++) aoff[kk][m] = (wr * 32 + m * 16 + lr) * 64 + ks;
#pragma unroll
        for (int n = 0; n < NF; n++) boff[kk][n] = (wc * (BN / 2) + n * 16 + lr) * 64 + ks;
    }

    f32x4 acc[2][NF] = {};
    int nk = K / 64;

    stage(0, 0);
    for (int t = 0; t < nk; ++t) {
        int cur = t & 1;
        if (t + 1 < nk) {
            stage(cur ^ 1, (t + 1) * 64);
            if constexpr (BN == 128)
                asm volatile("s_waitcnt vmcnt(6)" ::: "memory");
            else
                asm volatile("s_waitcnt vmcnt(4)" ::: "memory");
        } else {
            asm volatile("s_waitcnt vmcnt(0)" ::: "memory");
        }
        __builtin_amdgcn_sched_barrier(0);
        __builtin_amdgcn_s_barrier();
        __builtin_amdgcn_sched_barrier(0);
#pragma unroll
        for (int kk = 0; kk < 2; kk++) {
            bf16x8 af[2], bfr[NF];
#pragma unroll
            for (int m = 0; m < 2; m++) af[m] = *(const bf16x8*)&As[cur][aoff[kk][m]];
#pragma unroll
            for (int n = 0; n < NF; n++) bfr[n] = *(const bf16x8*)&Bs[cur][boff[kk][n]];
#pragma unroll
            for (int m = 0; m < 2; m++)
#pragma unroll
                for (int n = 0; n < NF; n++)
                    acc[m][n] = __builtin_amdgcn_mfma_f32_16x16x32_bf16(af[m], bfr[n], acc[m][n], 0, 0, 0);
        }
        __builtin_amdgcn_s_barrier();
    }

#pragma unroll
    for (int n = 0; n < NF; n++) {
        int col = n0 + wc * (BN / 2) + n * 16 + lr;
        bool cok = col < N;
        float bv = (bias && cok) ? bias[col] : 0.f;
#pragma unroll
        for (int m = 0; m < 2; m++) {
#pragma unroll
            for (int r = 0; r < 4; r++) {
                int row = m0 + wr * 32 + m * 16 + lg * 4 + r;
                if (!cok) continue;
                float v = acc[m][n][r] + bv;
                if (EPI == 1) v += resid[(size_t)row * N + col];
                if (EPI == 2) {
                    float x3 = v * v * v;
                    v = 0.5f * v * (1.f + tanhf(0.7978845608028654f * (v + 0.044715f * x3)));
                }
                if (OUTBF)
                    ((hbf16*)Cout)[(size_t)row * N + col] = __float2bfloat16(v);
                else
                    ((float*)Cout)[(size_t)row * N + col] = v;
            }
        }
    }
}

// ---------------- MFMA GEMM 256x128, 512 threads, BK=64 single-buffer (R14) -------
__global__ __launch_bounds__(512) void mm2_kernel(const hbf16* __restrict__ A,
                                                  const hbf16* __restrict__ Bt,
                                                  float* __restrict__ Cout,
                                                  int M, int N, int K) {
    __shared__ __bf16 As[256 * 64];  // 32 KB
    __shared__ __bf16 Bs[128 * 64];  // 16 KB
    int tid = threadIdx.x;
    int l = tid & 63, w = tid >> 6;
    int wr = w >> 1, wc = w & 1;

    int gx = gridDim.x, gy = gridDim.y;  // gy = 8
    int nwg = gx * gy;
    int hwlin = blockIdx.y * gx + blockIdx.x;
    int wk = (hwlin & 7) * (nwg >> 3) + (hwlin >> 3);
    int m0 = (wk & 7) * 256;
    int n0 = (wk >> 3) * 128;

    int sr = tid >> 3, sc = tid & 7;
    int scs = (sc ^ (sr & 7)) * 8;
    const hbf16* pA[4];
    __bf16* lA[4];
#pragma unroll
    for (int j = 0; j < 4; j++) {
        pA[j] = A + (size_t)(m0 + j * 64 + sr) * K + scs;
        lA[j] = As + j * 4096 + tid * 8;
    }
    const hbf16* pB[2];
    __bf16* lB[2];
#pragma unroll
    for (int j = 0; j < 2; j++) {
        pB[j] = Bt + (size_t)(n0 + j * 64 + sr) * K + scs;
        lB[j] = Bs + j * 4096 + tid * 8;
    }

    int lr = l & 15, lg = l >> 4;
    int aoff[2][4], boff[2][4];
#pragma unroll
    for (int kk = 0; kk < 2; kk++) {
        int ks = ((kk * 4 + lg) ^ (lr & 7)) * 8;
#pragma unroll
        for (int m = 0; m < 4; m++) aoff[kk][m] = (wr * 64 + m * 16 + lr) * 64 + ks;
#pragma unroll
        for (int n = 0; n < 4; n++) boff[kk][n] = (wc * 64 + n * 16 + lr) * 64 + ks;
    }

    f32x4 acc[4][4] = {};

    for (int k0 = 0; k0 < K; k0 += 64) {
#pragma unroll
        for (int j = 0; j < 4; j++) {
            GLD16(pA[j], lA[j]);
            pA[j] += 64;
        }
#pragma unroll
        for (int j = 0; j < 2; j++) {
            GLD16(pB[j], lB[j]);
            pB[j] += 64;
        }
        __syncthreads();
#pragma unroll
        for (int kk = 0; kk < 2; kk++) {
            bf16x8 af[4], bfr[4];
#pragma unroll
            for (int m = 0; m < 4; m++) af[m] = *(const bf16x8*)&As[aoff[kk][m]];
#pragma unroll
            for (int n = 0; n < 4; n++) bfr[n] = *(const bf16x8*)&Bs[boff[kk][n]];
#pragma unroll
            for (int m = 0; m < 4; m++)
#pragma unroll
                for (int n = 0; n < 4; n++)
                    acc[m][n] = __builtin_amdgcn_mfma_f32_16x16x32_bf16(af[m], bfr[n], acc[m][n], 0, 0, 0);
        }
        __syncthreads();
    }

#pragma unroll
    for (int n = 0; n < 4; n++) {
        int col = n0 + wc * 64 + n * 16 + lr;
        if (col >= N) continue;
#pragma unroll
        for (int m = 0; m < 4; m++) {
#pragma unroll
            for (int r = 0; r < 4; r++) {
                int row = m0 + wr * 64 + m * 16 + lg * 4 + r;
                Cout[(size_t)row * N + col] = acc[m][n][r];
            }
        }
    }
}

// ---------------- MFMA flash attention, pipelined + swapped QK^T + split-K --------
__global__ __launch_bounds__(256) void fattn_kernel(const hbf16* __restrict__ qkv,
                                                    hbf16* __restrict__ y,
                                                    float* __restrict__ part_O,
                                                    float* __restrict__ part_m,
                                                    float* __restrict__ part_l) {
    int s = blockIdx.x;
    int h = blockIdx.y, b = blockIdx.z;
    int qt, jlo, jhi, half = 0;
    bool partial;
    if (s < 16) {
        qt = 8 + (s >> 1);
        half = s & 1;
        int mid = (qt + 1) >> 1;
        jlo = half ? mid : 0;
        jhi = half ? qt : mid - 1;
        partial = true;
    } else {
        qt = s - 16;
        jlo = 0;
        jhi = qt;
        partial = false;
    }
    int q0 = qt * 64;
    int tid = threadIdx.x;
    int l = tid & 63, w = tid >> 6;
    int li = l & 15, lg = l >> 4;
    constexpr int RS = 3 * Dc;
    constexpr int PST = 72;
    constexpr int VST = 72;
    constexpr float SCL = 0.125f * 1.44269504f;  // 1/sqrt(64) * log2(e)
    constexpr float THR = 11.5f;                 // defer-max threshold (log2 domain)

    __shared__ __bf16 K_lds[2][64 * 64];   // 2 x 8 KB, swizzled 16B slots
    __shared__ __bf16 Vt[2][64 * VST];     // 2 x 9 KB
    __shared__ __bf16 P_lds[4][16 * PST];  // 9 KB  (layout [q_local][j])

    bf16x8 qf[2];
    {
        const hbf16* qp = qkv + (size_t)(b * Tc + q0 + w * 16 + li) * RS + h * HDc + lg * 8;
        qf[0] = *(const bf16x8*)qp;
        qf[1] = *(const bf16x8*)(qp + 32);
    }

    int krow0 = tid >> 3, krow1 = 32 + (tid >> 3);
    int ks8 = tid & 7;
    int kc0 = (ks8 ^ (krow0 & 7)) * 8;
    int kc1 = (ks8 ^ (krow1 & 7)) * 8;
    const hbf16* kbase = qkv + (size_t)(b * Tc) * RS + Dc + h * HDc;

    int jp = (tid >> 3) * 2;
    int db = (tid & 7) * 8;
    const hbf16* vbase = qkv + (size_t)(b * Tc) * RS + 2 * Dc + h * HDc;

    int koff[2][4];
#pragma unroll
    for (int ks = 0; ks < 2; ks++)
#pragma unroll
        for (int n = 0; n < 4; n++)
            koff[ks][n] = (n * 16 + li) * 64 + (((ks * 4 + lg) ^ (li & 7)) * 8);

    f32x4 acc_o[4] = {};
    float m_run = -1e30f, l_run = 0.f;  // scalar: lane owns q = w*16+li

    int j0p = jlo * 64;
    bf16x8 vr0, vr1;
    {
        const hbf16* vp = vbase + (size_t)(j0p + jp) * RS + db;
        vr0 = *(const bf16x8*)vp;
        vr1 = *(const bf16x8*)(vp + RS);
        GLD16(kbase + (size_t)(j0p + krow0) * RS + kc0, &K_lds[0][tid * 8]);
        GLD16(kbase + (size_t)(j0p + krow1) * RS + kc1, &K_lds[0][2048 + tid * 8]);
    }
#pragma unroll
    for (int i = 0; i < 8; i++) {
        __bf16 a0 = vr0[i], a1 = vr1[i];
        unsigned u = (unsigned)*(unsigned short*)&a0 | ((unsigned)*(unsigned short*)&a1 << 16);
        *(unsigned*)&Vt[0][(db + i) * VST + jp] = u;
    }

    int cur = 0;
    for (int jt = jlo; jt <= jhi; jt++) {
        int jn0 = (jt < jhi) ? (jt + 1) * 64 : j0p;  // dummy wrap keeps vmcnt invariant

        asm volatile("s_waitcnt lgkmcnt(0)" ::: "memory");
        __builtin_amdgcn_s_barrier();

        {
            const hbf16* vp = vbase + (size_t)(jn0 + jp) * RS + db;
            vr0 = *(const bf16x8*)vp;
            vr1 = *(const bf16x8*)(vp + RS);
            GLD16(kbase + (size_t)(jn0 + krow0) * RS + kc0, &K_lds[cur ^ 1][tid * 8]);
            GLD16(kbase + (size_t)(jn0 + krow1) * RS + kc1, &K_lds[cur ^ 1][2048 + tid * 8]);
        }

        asm volatile("s_waitcnt vmcnt(4)" ::: "memory");
        __builtin_amdgcn_sched_barrier(0);

        // ---- S = K Q^T (swapped): s[n][r] = S[j=n*16+lg*4+r][q=li] ----
        f32x4 sv[4] = {};
#pragma unroll
        for (int ks = 0; ks < 2; ks++)
#pragma unroll
            for (int n = 0; n < 4; n++) {
                bf16x8 kf = *(const bf16x8*)&K_lds[cur][koff[ks][n]];
                sv[n] = __builtin_amdgcn_mfma_f32_16x16x32_bf16(kf, qf[ks], sv[n], 0, 0, 0);
            }
#pragma unroll
        for (int n = 0; n < 4; n++)
#pragma unroll
            for (int r = 0; r < 4; r++) sv[n][r] *= SCL;

        if (jt == qt) {
            int qloc = w * 16 + li;
#pragma unroll
            for (int n = 0; n < 4; n++)
#pragma unroll
                for (int r = 0; r < 4; r++)
                    if (n * 16 + lg * 4 + r > qloc) sv[n][r] = -1e30f;
        }

        // ---- online softmax: all 16 values belong to q = w*16+li ----
        float mx = -1e30f;
#pragma unroll
        for (int n = 0; n < 4; n++)
#pragma unroll
            for (int r = 0; r < 4; r++) mx = fmaxf(mx, sv[n][r]);
        mx = fmaxf(mx, __shfl_xor(mx, 16, 64));
        mx = fmaxf(mx, __shfl_xor(mx, 32, 64));

        bool dfr = __all(mx - m_run <= THR);
        float sclq = 1.f;
        if (!dfr) {
            float mnew = fmaxf(m_run, mx);
            sclq = exp2f(m_run - mnew);
            m_run = mnew;
        }
        float rs = 0.f;
#pragma unroll
        for (int n = 0; n < 4; n++)
#pragma unroll
            for (int r = 0; r < 4; r++) {
                float pv = exp2f(sv[n][r] - m_run);
                sv[n][r] = pv;
                rs += pv;
            }
        rs += __shfl_xor(rs, 16, 64);
        rs += __shfl_xor(rs, 32, 64);
        l_run = (dfr ? l_run : l_run * sclq) + rs;

        // ---- P -> LDS [q=li][j], packed pairs ----
#pragma unroll
        for (int n = 0; n < 4; n++)
#pragma unroll
            for (int r = 0; r < 4; r += 2) {
                __bf16 b0 = (__bf16)sv[n][r], b1 = (__bf16)sv[n][r + 1];
                unsigned u = (unsigned)*(unsigned short*)&b0 |
                             ((unsigned)*(unsigned short*)&b1 << 16);
                *(unsigned*)&P_lds[w][li * PST + n * 16 + lg * 4 + r] = u;
            }
        bf16x8 pa0 = *(const bf16x8*)&P_lds[w][li * PST + lg * 8];
        bf16x8 pa1 = *(const bf16x8*)&P_lds[w][li * PST + 32 + lg * 8];

        if (!dfr) {
#pragma unroll
            for (int r = 0; r < 4; r++) {
                float sr_ = __shfl(sclq, (l & 48) | (lg * 4 + r), 64);
#pragma unroll
                for (int n2 = 0; n2 < 4; n2++) acc_o[n2][r] *= sr_;
            }
        }

        // ---- PV from Vt[cur] ----
#pragma unroll
        for (int n2 = 0; n2 < 4; n2++) {
            bf16x8 vf0 = *(const bf16x8*)&Vt[cur][(n2 * 16 + li) * VST + lg * 8];
            bf16x8 vf1 = *(const bf16x8*)&Vt[cur][(n2 * 16 + li) * VST + 32 + lg * 8];
            acc_o[n2] = __builtin_amdgcn_mfma_f32_16x16x32_bf16(pa0, vf0, acc_o[n2], 0, 0, 0);
            acc_o[n2] = __builtin_amdgcn_mfma_f32_16x16x32_bf16(pa1, vf1, acc_o[n2], 0, 0, 0);
        }

        // ---- write V(jt+1) regs -> Vt[cur^1] ----
#pragma unroll
        for (int i = 0; i < 8; i++) {
            __bf16 a0 = vr0[i], a1 = vr1[i];
            unsigned u = (unsigned)*(unsigned short*)&a0 | ((unsigned)*(unsigned short*)&a1 << 16);
            *(unsigned*)&Vt[cur ^ 1][(db + i) * VST + jp] = u;
        }
        cur ^= 1;
    }

    if (partial) {
        int p = ((b * Hc + h) * 8 + (qt - 8)) * 2 + half;
#pragma unroll
        for (int r = 0; r < 4; r++) {
            int lrow = w * 16 + lg * 4 + r;
#pragma unroll
            for (int n2 = 0; n2 < 4; n2++)
                part_O[(size_t)p * 4096 + lrow * 64 + n2 * 16 + li] = acc_o[n2][r];
        }
        if (lg == 0) {
            part_m[p * 64 + w * 16 + li] = m_run;
            part_l[p * 64 + w * 16 + li] = l_run;
        }
    } else {
#pragma unroll
        for (int r = 0; r < 4; r++) {
            float lv = __shfl(l_run, (l & 48) | (lg * 4 + r), 64);
            float rcp = 1.f / lv;
            int row = q0 + w * 16 + lg * 4 + r;
#pragma unroll
            for (int n2 = 0; n2 < 4; n2++)
                y[(size_t)(b * Tc + row) * Dc + h * HDc + n2 * 16 + li] =
                    __float2bfloat16(acc_o[n2][r] * rcp);
        }
    }
}

// ---------------- merge split-K partials: one wave per q-row ----------------
__global__ __launch_bounds__(256) void fmerge_kernel(const float* __restrict__ part_O,
                                                     const float* __restrict__ part_m,
                                                     const float* __restrict__ part_l,
                                                     hbf16* __restrict__ y) {
    int gi = blockIdx.x * 4 + (threadIdx.x >> 6);
    int lane = threadIdx.x & 63;
    int row512 = gi & 511;
    int bh = gi >> 9;
    int b = bh / Hc, h = bh % Hc;
    int qt8 = row512 >> 6, lrow = row512 & 63;
    int p0 = (bh * 8 + qt8) * 2, p1 = p0 + 1;
    float m0 = part_m[p0 * 64 + lrow], m1 = part_m[p1 * 64 + lrow];
    float l0 = part_l[p0 * 64 + lrow], l1 = part_l[p1 * 64 + lrow];
    float m = fmaxf(m0, m1);
    float a0 = exp2f(m0 - m), a1 = exp2f(m1 - m);
    float lsum = l0 * a0 + l1 * a1;
    float o0 = part_O[(size_t)p0 * 4096 + lrow * 64 + lane];
    float o1 = part_O[(size_t)p1 * 4096 + lrow * 64 + lane];
    float o = (o0 * a0 + o1 * a1) / lsum;
    int q = (8 + qt8) * 64 + lrow;
    y[((size_t)b * Tc + q) * Dc + h * HDc + lane] = __float2bfloat16(o);
}

extern "C" void kernel_launch(void* const* d_in, const int* in_sizes, int n_in,
                              void* d_out, int out_size, void* d_ws, size_t ws_size,
                              hipStream_t stream) {
    const int* x = (const int*)d_in[0];
    const float* wte = (const float*)d_in[1];
    const float* wpe = (const float*)d_in[2];
    const float* ln1w = (const float*)d_in[3];
    const float* ln1b = (const float*)d_in[4];
    const float* qkvw = (const float*)d_in[5];
    const float* qkvb = (const float*)d_in[6];
    const float* projw = (const float*)d_in[7];
    const float* projb = (const float*)d_in[8];
    const float* ln2w = (const float*)d_in[9];
    const float* ln2b = (const float*)d_in[10];
    const float* fcw = (const float*)d_in[11];
    const float* fcb = (const float*)d_in[12];
    const float* fcpw = (const float*)d_in[13];
    const float* fcpb = (const float*)d_in[14];
    const float* lnfw = (const float*)d_in[15];
    const float* lnfb = (const float*)d_in[16];

    char* p = (char*)d_ws;
    float* h = (float*)p;      p += (size_t)Mc * Dc * 4;      // f32 [M][D]
    hbf16* qkv = (hbf16*)p;    p += (size_t)Mc * 3 * Dc * 2;  // bf16 [M][3D]
    hbf16* a = (hbf16*)p;      p += (size_t)Mc * Dc * 2;      // bf16 [M][D]
    hbf16* y = (hbf16*)p;      p += (size_t)Mc * Dc * 2;      // bf16 [M][D]
    hbf16* mlp = (hbf16*)p;    p += (size_t)Mc * 4 * Dc * 2;  // bf16 [M][4D]
    hbf16* wte_b = (hbf16*)p;  p += (size_t)Vpad * Dc * 2;    // [50304][768]
    float* part_O = (float*)p; p += (size_t)NPART * 4096 * 4; // 6.3 MB
    float* part_m = (float*)p; p += (size_t)NPART * 64 * 4;
    float* part_l = (float*)p; p += (size_t)NPART * 64 * 4;
    hbf16* wtr = (hbf16*)p;                                   // transposed weights
    size_t used = (size_t)((char*)wtr - (char*)d_ws);
    bool all_mode = (ws_size - used) >= (size_t)Lc * SZL * 2;

    embed_kernel<<<(Mc * Dc + 255) / 256, 256, 0, stream>>>(x, wte, wpe, h);
    convert_wte<<<((size_t)Vpad * Dc / 4 + 255) / 256, 256, 0, stream>>>(wte, wte_b);

    if (all_mode) {
        transpose4_kernel<<<dim3(6912, Lc), 256, 0, stream>>>(
            qkvw, projw, fcw, fcpw,
            wtr, wtr + SZ_Q, wtr + SZ_Q + SZ_P, wtr + SZ_Q + SZ_P + SZ_F);
    }

    for (int l = 0; l < Lc; l++) {
        hbf16* base = wtr + (all_mode ? (size_t)l * SZL : 0);
        hbf16* wq_t = base;
        hbf16* wp_t = base + SZ_Q;
        hbf16* wf_t = base + SZ_Q + SZ_P;
        hbf16* wfp_t = base + SZ_Q + SZ_P + SZ_F;
        if (!all_mode) {
            transpose4_kernel<<<dim3(6912, 1), 256, 0, stream>>>(
                qkvw + (size_t)l * SZ_Q, projw + (size_t)l * SZ_P,
                fcw + (size_t)l * SZ_F, fcpw + (size_t)l * SZ_FP,
                wq_t, wp_t, wf_t, wfp_t);
        }

        ln_kernel<<<Mc / 4, 256, 0, stream>>>(h, ln1w + (size_t)l * Dc, ln1b + (size_t)l * Dc, a);
        mm_kernel<0, true, 128><<<dim3(3 * Dc / 128, Mc / 64), 256, 0, stream>>>(
            a, wq_t, qkvb + (size_t)l * 3 * Dc, nullptr, qkv, Mc, 3 * Dc, Dc);
        fattn_kernel<<<dim3(24, Hc, Bc), 256, 0, stream>>>(qkv, y, part_O, part_m, part_l);
        fmerge_kernel<<<Bc * Hc * 512 / 4, 256, 0, stream>>>(part_O, part_m, part_l, y);
        mm_kernel<1, false, 64><<<dim3(Dc / 64, Mc / 64), 256, 0, stream>>>(
            y, wp_t, projb + (size_t)l * Dc, h, h, Mc, Dc, Dc);
        ln_kernel<<<Mc / 4, 256, 0, stream>>>(h, ln2w + (size_t)l * Dc, ln2b + (size_t)l * Dc, a);
        mm_kernel<2, true, 128><<<dim3(4 * Dc / 128, Mc / 64), 256, 0, stream>>>(
            a, wf_t, fcb + (size_t)l * 4 * Dc, nullptr, mlp, Mc, 4 * Dc, Dc);
        mm_kernel<1, false, 64><<<dim3(Dc / 64, Mc / 64), 256, 0, stream>>>(
            mlp, wfp_t, fcpb + (size_t)l * Dc, h, h, Mc, Dc, 4 * Dc);
    }

    ln_kernel<<<Mc / 4, 256, 0, stream>>>(h, lnfw, lnfb, a);
    mm2_kernel<<<dim3(Vpad / 128, Mc / 256), 512, 0, stream>>>(
        a, wte_b, (float*)d_out, Mc, Vc, Dc);
}